// Round 1
// baseline (2531.861 us; speedup 1.0000x reference)
//
#include <hip/hip_runtime.h>

#define NN 100000
#define NE 1600000
#define EPSV 1e-5f

// ---------------------------------------------------------------------------
// Generic skinny GEMM: Y[n,ko] = sum_d X[n,d]*W[ko,d] (+bias[ko]), K fixed 64.
// 1 wave per block, 64 nodes per block, lane = node. X rows staged in LDS with
// row stride 68 (conflict-free ds_read_b128). Weights are wave-uniform ->
// scalar loads feeding v_fmac (SGPR operand).
// ---------------------------------------------------------------------------
template<int KO>
__global__ __launch_bounds__(64) void gemm64(const float* __restrict__ X,
                                             const float* __restrict__ W,
                                             const float* __restrict__ bias,
                                             float* __restrict__ Y, int n) {
  __shared__ float xs[64 * 68];
  const int t = threadIdx.x;
  const long base = (long)blockIdx.x * 64;
  long rows_l = (long)n - base;
  const int rows = rows_l > 64 ? 64 : (int)rows_l;
  const float4* g = reinterpret_cast<const float4*>(X + base * 64);
  if (rows == 64) {
#pragma unroll
    for (int j = 0; j < 16; ++j) {
      int i4 = j * 64 + t;
      float4 v = g[i4];
      int row = i4 >> 4;
      int col = (i4 & 15) * 4;
      *reinterpret_cast<float4*>(&xs[row * 68 + col]) = v;
    }
  } else {
#pragma unroll
    for (int j = 0; j < 16; ++j) {
      int i4 = j * 64 + t;
      int row = i4 >> 4;
      int col = (i4 & 15) * 4;
      float4 v = make_float4(0.f, 0.f, 0.f, 0.f);
      if (row < rows) v = g[i4];
      *reinterpret_cast<float4*>(&xs[row * 68 + col]) = v;
    }
  }
  __syncthreads();
  float x[64];
#pragma unroll
  for (int i = 0; i < 16; ++i) {
    float4 v = *reinterpret_cast<const float4*>(&xs[t * 68 + 4 * i]);
    x[4 * i + 0] = v.x; x[4 * i + 1] = v.y;
    x[4 * i + 2] = v.z; x[4 * i + 3] = v.w;
  }
  const bool act = t < rows;
  constexpr int CH = (KO >= 32) ? 32 : KO;
  constexpr int NCH = KO / CH;
  float* yr = Y + (base + t) * KO;
  for (int kc = 0; kc < NCH; ++kc) {
    float acc[CH];
#pragma unroll
    for (int k = 0; k < CH; ++k) {
      const float* w = W + (kc * CH + k) * 64;
      float a = bias ? bias[kc * CH + k] : 0.f;
#pragma unroll
      for (int d = 0; d < 64; ++d) a += x[d] * w[d];
      acc[k] = a;
    }
    if (act) {
#pragma unroll
      for (int k = 0; k < CH; ++k) yr[kc * CH + k] = acc[k];
    }
  }
}

// per-column sum / sumsq for BatchNorm batch stats (C=64)
__global__ __launch_bounds__(256) void colsum(const float* __restrict__ X,
                                              float* __restrict__ acc, int n) {
  const int t = threadIdx.x;
  const int c = t & 63, w = t >> 6;
  float s = 0.f, ss = 0.f;
  for (int r = blockIdx.x * 4 + w; r < n; r += gridDim.x * 4) {
    float v = X[(long)r * 64 + c];
    s += v; ss += v * v;
  }
  __shared__ float sh[8][64];
  sh[w][c] = s; sh[4 + w][c] = ss;
  __syncthreads();
  if (t < 64) {
    float a = sh[0][t] + sh[1][t] + sh[2][t] + sh[3][t];
    float b = sh[4][t] + sh[5][t] + sh[6][t] + sh[7][t];
    atomicAdd(&acc[t], a);
    atomicAdd(&acc[64 + t], b);
  }
}

__global__ void bn_finalize(const float* __restrict__ acc, const float* __restrict__ gamma,
                            const float* __restrict__ beta, float* __restrict__ scsh,
                            float inv_n) {
  int t = threadIdx.x;  // 64 threads
  float mean = acc[t] * inv_n;
  float var = acc[64 + t] * inv_n - mean * mean;
  float sc = gamma[t] * rsqrtf(var + EPSV);
  scsh[t] = sc;
  scsh[64 + t] = beta[t] - mean * sc;
}

__global__ __launch_bounds__(256) void bn_apply(const float* __restrict__ X,
                                                float* __restrict__ Y,
                                                const float* __restrict__ scsh,
                                                long n4, int relu) {
  long i = (long)blockIdx.x * blockDim.x + threadIdx.x;
  long stride = (long)gridDim.x * blockDim.x;
  for (; i < n4; i += stride) {
    float4 v = reinterpret_cast<const float4*>(X)[i];
    int c = (int)((i * 4) & 63);
    v.x = v.x * scsh[c]     + scsh[64 + c];
    v.y = v.y * scsh[c + 1] + scsh[65 + c];
    v.z = v.z * scsh[c + 2] + scsh[66 + c];
    v.w = v.w * scsh[c + 3] + scsh[67 + c];
    if (relu) {
      v.x = fmaxf(v.x, 0.f); v.y = fmaxf(v.y, 0.f);
      v.z = fmaxf(v.z, 0.f); v.w = fmaxf(v.w, 0.f);
    }
    reinterpret_cast<float4*>(Y)[i] = v;
  }
}

// pack rel_weight[r][d][k] -> Wp[(r*64+k)*64 + d] so x3 is a plain gemm64<192>
__global__ void pack_relw(const float* __restrict__ rw, float* __restrict__ wp) {
  int i = blockIdx.x * blockDim.x + threadIdx.x;
  if (i >= 3 * 64 * 64) return;
  int o = i >> 6, d = i & 63;
  int r = o >> 6, k = o & 63;
  wp[i] = rw[r * 4096 + d * 64 + k];
}

// one wave per edge: coalesced 256B gather from x3, coalesced atomic row add
__global__ __launch_bounds__(256) void edge_scatter(const int* __restrict__ src,
                                                    const int* __restrict__ dst,
                                                    const int* __restrict__ rt,
                                                    const float* __restrict__ norm,
                                                    const float* __restrict__ x3,
                                                    float* __restrict__ swh) {
  const int lane = threadIdx.x & 63;
  int wid = blockIdx.x * 4 + (threadIdx.x >> 6);
  const int nw = gridDim.x * 4;
  for (int e = wid; e < NE; e += nw) {
    int s = src[e], dd = dst[e], r = rt[e];
    float nm = norm[e];
    float v = x3[(long)s * 192 + r * 64 + lane] * nm;
    atomicAdd(&swh[(long)dd * 64 + lane], v);
  }
}

// GRU gate combine (elementwise, in-place h update). use_h=0 => h==0, gh=bhh.
__global__ __launch_bounds__(256) void gru_combine(const float* __restrict__ G1,
                                                   const float* __restrict__ G2,
                                                   const float* __restrict__ bih,
                                                   const float* __restrict__ bhh,
                                                   float* __restrict__ h, int use_h) {
  long i = (long)blockIdx.x * blockDim.x + threadIdx.x;
  long stride = (long)gridDim.x * blockDim.x;
  const long tot = (long)NN * 64;
  for (; i < tot; i += stride) {
    long nrow = i >> 6;
    int c = (int)(i & 63);
    const float* g1 = G1 + nrow * 192;
    float ir = g1[c] + bih[c];
    float iz = g1[64 + c] + bih[64 + c];
    float in_ = g1[128 + c] + bih[128 + c];
    float hr = bhh[c], hz = bhh[64 + c], hn = bhh[128 + c], hv = 0.f;
    if (use_h) {
      const float* g2 = G2 + nrow * 192;
      hr += g2[c]; hz += g2[64 + c]; hn += g2[128 + c];
      hv = h[i];
    }
    float r = 1.f / (1.f + expf(-(ir + hr)));
    float z = 1.f / (1.f + expf(-(iz + hz)));
    float nn = tanhf(in_ + r * hn);
    h[i] = (1.f - z) * nn + z * hv;
  }
}

extern "C" void kernel_launch(void* const* d_in, const int* in_sizes, int n_in,
                              void* d_out, int out_size, void* d_ws, size_t ws_size,
                              hipStream_t stream) {
  const float* v     = (const float*)d_in[0];
  const int*   src   = (const int*)d_in[1];
  const int*   dst   = (const int*)d_in[2];
  const int*   rt    = (const int*)d_in[3];
  const float* norm  = (const float*)d_in[4];
  const float* emb_W = (const float*)d_in[5];
  // d_in[6] emb_b: cancels inside BatchNorm (mean-subtracted) -> unused
  const float* emb_g  = (const float*)d_in[7];
  const float* emb_be = (const float*)d_in[8];
  const float* rel_w  = (const float*)d_in[9];
  const float* Wih    = (const float*)d_in[10];
  const float* Whh    = (const float*)d_in[11];
  const float* bih    = (const float*)d_in[12];
  const float* bhh    = (const float*)d_in[13];
  const float* ker_g  = (const float*)d_in[14];
  const float* ker_be = (const float*)d_in[15];
  const float* aW1    = (const float*)d_in[16];
  // a_b1 cancels in BN -> unused
  const float* a_g  = (const float*)d_in[18];
  const float* a_be = (const float*)d_in[19];
  const float* aW2  = (const float*)d_in[20];
  const float* ab2  = (const float*)d_in[21];
  const float* bW1  = (const float*)d_in[22];
  // b_b1 cancels in BN -> unused
  const float* b_g  = (const float*)d_in[24];
  const float* b_be = (const float*)d_in[25];
  const float* bW2  = (const float*)d_in[26];
  const float* bb2  = (const float*)d_in[27];
  float* out = (float*)d_out;

  // workspace layout (floats): A,B,C are [N,64]; D,E are [N,192]
  float* A   = (float*)d_ws;          // h0, then head tmp T
  float* B   = A + 6400000;           // GRU state h (updated in place)
  float* C   = B + 6400000;           // swh, then HK
  float* D   = C + 6400000;           // x3 then G1 (per layer)
  float* E   = D + 19200000;          // G2 (layer 2 only)
  float* Wp  = E + 19200000;          // packed rel weights [192,64]
  float* ACC = Wp + 12288;            // 4 x 128 BN accumulators
  float* SC  = ACC + 512;             // 4 x 128 BN scale/shift

  const int GB = (NN + 63) / 64;  // 1563

  hipMemsetAsync(ACC, 0, 512 * sizeof(float), stream);
  pack_relw<<<48, 256, 0, stream>>>(rel_w, Wp);

  // embedding: h0 = relu(BN(v @ emb_W.T))
  gemm64<64><<<GB, 64, 0, stream>>>(v, emb_W, nullptr, A, NN);
  colsum<<<416, 256, 0, stream>>>(A, ACC + 0, NN);
  bn_finalize<<<1, 64, 0, stream>>>(ACC + 0, emb_g, emb_be, SC + 0, 1.f / NN);
  bn_apply<<<2048, 256, 0, stream>>>(A, A, SC + 0, (long)NN * 16, 1);

  // ---- layer 1 (h == 0: skip Whh gemm) ----
  gemm64<192><<<GB, 64, 0, stream>>>(A, Wp, nullptr, D, NN);       // x3
  hipMemsetAsync(C, 0, (size_t)6400000 * 4, stream);
  edge_scatter<<<2048, 256, 0, stream>>>(src, dst, rt, norm, D, C);
  gemm64<192><<<GB, 64, 0, stream>>>(C, Wih, nullptr, D, NN);      // G1
  gru_combine<<<2048, 256, 0, stream>>>(D, nullptr, bih, bhh, B, 0);

  // ---- layer 2 ----
  gemm64<192><<<GB, 64, 0, stream>>>(B, Wp, nullptr, D, NN);       // x3
  hipMemsetAsync(C, 0, (size_t)6400000 * 4, stream);
  edge_scatter<<<2048, 256, 0, stream>>>(src, dst, rt, norm, D, C);
  gemm64<192><<<GB, 64, 0, stream>>>(B, Whh, nullptr, E, NN);      // G2
  gemm64<192><<<GB, 64, 0, stream>>>(C, Wih, nullptr, D, NN);      // G1
  gru_combine<<<2048, 256, 0, stream>>>(D, E, bih, bhh, B, 1);

  // hk = BN(h) -> C
  colsum<<<416, 256, 0, stream>>>(B, ACC + 128, NN);
  bn_finalize<<<1, 64, 0, stream>>>(ACC + 128, ker_g, ker_be, SC + 128, 1.f / NN);
  bn_apply<<<2048, 256, 0, stream>>>(B, C, SC + 128, (long)NN * 16, 0);

  // head A: relu(BN(hk@aW1.T)) @ aW2.T + ab2
  gemm64<64><<<GB, 64, 0, stream>>>(C, aW1, nullptr, A, NN);
  colsum<<<416, 256, 0, stream>>>(A, ACC + 256, NN);
  bn_finalize<<<1, 64, 0, stream>>>(ACC + 256, a_g, a_be, SC + 256, 1.f / NN);
  bn_apply<<<2048, 256, 0, stream>>>(A, A, SC + 256, (long)NN * 16, 1);
  gemm64<2><<<GB, 64, 0, stream>>>(A, aW2, ab2, out, NN);

  // head B
  gemm64<64><<<GB, 64, 0, stream>>>(C, bW1, nullptr, A, NN);
  colsum<<<416, 256, 0, stream>>>(A, ACC + 384, NN);
  bn_finalize<<<1, 64, 0, stream>>>(ACC + 384, b_g, b_be, SC + 384, 1.f / NN);
  bn_apply<<<2048, 256, 0, stream>>>(A, A, SC + 384, (long)NN * 16, 1);
  gemm64<21><<<GB, 64, 0, stream>>>(A, bW2, bb2, out + (long)NN * 2, NN);
}

// Round 2
// 726.534 us; speedup vs baseline: 3.4848x; 3.4848x over previous
//
#include <hip/hip_runtime.h>

#define NN 100000
#define NE 1600000
#define NP 100096   // 782 * 128, padded row count for 128-row GEMM tiles
#define EPSV 1e-5f

typedef unsigned int u32;
typedef unsigned short u16;
typedef unsigned long long u64;
typedef __bf16 bf16x8 __attribute__((ext_vector_type(8)));
typedef float f32x4 __attribute__((ext_vector_type(4)));

__device__ __forceinline__ u16 f2bf(float f) {
  u32 x = __float_as_uint(f);
  return (u16)((x + 0x7FFFu + ((x >> 16) & 1u)) >> 16);  // RNE
}
__device__ __forceinline__ float bf2f(u16 h) { return __uint_as_float(((u32)h) << 16); }

// ---------------- fp32 -> bf16 bulk convert ----------------
__global__ __launch_bounds__(256) void cvt_f32_bf16(const float* __restrict__ X,
                                                    u16* __restrict__ Y) {
  long i = (long)blockIdx.x * 256 + threadIdx.x;  // one float4 per thread
  float4 v = reinterpret_cast<const float4*>(X)[i];
  reinterpret_cast<ushort4*>(Y)[i] = make_ushort4(f2bf(v.x), f2bf(v.y), f2bf(v.z), f2bf(v.w));
}

// ---------------- Wfused[kg][j] = sum_k relw[r,ds,k] * Wih[kg,k], j=(r*64+ds) ----
__global__ void wfuse(const float* __restrict__ relw, const float* __restrict__ Wih,
                      float* __restrict__ Wrow) {
  int t = blockIdx.x * 256 + threadIdx.x;
  if (t >= 192 * 192) return;
  int kg = t / 192, j = t % 192;
  const float* a = relw + (j >> 6) * 4096 + (j & 63) * 64;
  const float* b = Wih + kg * 64;
  float s = 0.f;
#pragma unroll
  for (int k = 0; k < 64; ++k) s += a[k] * b[k];
  Wrow[kg * 192 + j] = s;
}

// ---------------- pack W[KO,K] (row-major f32) into bf16 B-fragments ----------
// frag(ks,ot): lane l elem j holds B[k=ks*32+8*(l>>4)+j][n=ot*16+(l&15)] = W[n][k]
__global__ void pack_w(const float* __restrict__ W, u32* __restrict__ out, int K, int KOT) {
  int iu = blockIdx.x * 256 + threadIdx.x;
  int total = KOT * 16 * K / 2;
  if (iu >= total) return;
  int q = iu & 3, lane = (iu >> 2) & 63, f = iu >> 8;
  int ks = f / KOT, ot = f - ks * KOT;
  int o = ot * 16 + (lane & 15);
  int k = ks * 32 + (lane >> 4) * 8 + q * 2;
  out[iu] = (u32)f2bf(W[o * K + k]) | ((u32)f2bf(W[o * K + k + 1]) << 16);
}

// ---------------- MFMA GEMM: Y[m,o] = sum_k A[m,k]*W[o,k]; A bf16 [NP,K] -------
template<int K, int KO, int OUTBF>
__global__ __launch_bounds__(256, 2) void gemm_mfma(const u16* __restrict__ Abf,
                                                    const u32* __restrict__ Wpk,
                                                    void* __restrict__ Yv, int n) {
  constexpr int KOT = KO / 16, KS = K / 32;
  const int lane = threadIdx.x & 63, w = threadIdx.x >> 6;
  const int rr = lane & 15, kg = lane >> 4;
  const long mbase = (long)blockIdx.x * 128 + w * 32;
  f32x4 acc[2][KOT] = {};
  for (int ks = 0; ks < KS; ++ks) {
    bf16x8 af0 = *reinterpret_cast<const bf16x8*>(Abf + (mbase + rr) * K + ks * 32 + kg * 8);
    bf16x8 af1 = *reinterpret_cast<const bf16x8*>(Abf + (mbase + 16 + rr) * K + ks * 32 + kg * 8);
#pragma unroll
    for (int o = 0; o < KOT; ++o) {
      bf16x8 bfr = *reinterpret_cast<const bf16x8*>(Wpk + ((long)(ks * KOT + o) * 64 + lane) * 4);
      acc[0][o] = __builtin_amdgcn_mfma_f32_16x16x32_bf16(af0, bfr, acc[0][o], 0, 0, 0);
      acc[1][o] = __builtin_amdgcn_mfma_f32_16x16x32_bf16(af1, bfr, acc[1][o], 0, 0, 0);
    }
  }
#pragma unroll
  for (int tl = 0; tl < 2; ++tl)
#pragma unroll
    for (int o = 0; o < KOT; ++o)
#pragma unroll
      for (int q = 0; q < 4; ++q) {
        long row = mbase + tl * 16 + kg * 4 + q;
        if (row < n) {
          long off = row * KO + o * 16 + rr;
          if (OUTBF) ((u16*)Yv)[off] = f2bf(acc[tl][o][q]);
          else       ((float*)Yv)[off] = acc[tl][o][q];
        }
      }
}

// ---------------- BN batch stats ----------------
__global__ __launch_bounds__(256) void colsum(const float* __restrict__ X,
                                              float* __restrict__ acc, int n) {
  const int t = threadIdx.x;
  const int c = t & 63, w = t >> 6;
  float s = 0.f, ss = 0.f;
  for (int r = blockIdx.x * 4 + w; r < n; r += gridDim.x * 4) {
    float v = X[(long)r * 64 + c];
    s += v; ss += v * v;
  }
  __shared__ float sh[8][64];
  sh[w][c] = s; sh[4 + w][c] = ss;
  __syncthreads();
  if (t < 64) {
    float a = sh[0][t] + sh[1][t] + sh[2][t] + sh[3][t];
    float b = sh[4][t] + sh[5][t] + sh[6][t] + sh[7][t];
    atomicAdd(&acc[t], a);
    atomicAdd(&acc[64 + t], b);
  }
}

__global__ void bn_finalize(const float* __restrict__ acc, const float* __restrict__ gamma,
                            const float* __restrict__ beta, float* __restrict__ scsh,
                            float inv_n) {
  int t = threadIdx.x;  // 64 threads
  float mean = acc[t] * inv_n;
  float var = acc[64 + t] * inv_n - mean * mean;
  float sc = gamma[t] * rsqrtf(var + EPSV);
  scsh[t] = sc;
  scsh[64 + t] = beta[t] - mean * sc;
}

__global__ __launch_bounds__(256) void bn_apply_bf(const float* __restrict__ X,
                                                   u16* __restrict__ Y,
                                                   const float* __restrict__ scsh, int relu) {
  long i = (long)blockIdx.x * 256 + threadIdx.x;  // one float4 per thread, NN*16 total
  float4 v = reinterpret_cast<const float4*>(X)[i];
  int c = (int)((i * 4) & 63);
  v.x = v.x * scsh[c]     + scsh[64 + c];
  v.y = v.y * scsh[c + 1] + scsh[65 + c];
  v.z = v.z * scsh[c + 2] + scsh[66 + c];
  v.w = v.w * scsh[c + 3] + scsh[67 + c];
  if (relu) {
    v.x = fmaxf(v.x, 0.f); v.y = fmaxf(v.y, 0.f);
    v.z = fmaxf(v.z, 0.f); v.w = fmaxf(v.w, 0.f);
  }
  reinterpret_cast<ushort4*>(Y)[i] = make_ushort4(f2bf(v.x), f2bf(v.y), f2bf(v.z), f2bf(v.w));
}

// ---------------- edge buckets (built once per call, reused both layers) -------
__global__ __launch_bounds__(256) void bucket_scatter(const int* __restrict__ src,
                                                      const int* __restrict__ dst,
                                                      const int* __restrict__ rt,
                                                      const float* __restrict__ nrm,
                                                      int* __restrict__ cur,
                                                      u64* __restrict__ buck) {
  int e = blockIdx.x * 256 + threadIdx.x;
  if (e >= NE) return;
  int d = dst[e];
  int pos = atomicAdd(&cur[d], 1);
  if (pos < 64) {
    u32 srp = (u32)src[e] | ((u32)rt[e] << 20);
    buck[(long)d * 64 + pos] = (u64)srp | ((u64)__float_as_uint(nrm[e]) << 32);
  }
}

// one wave per node: acc[rel][d] = sum_{in-edges} norm * X[src, d]
__global__ __launch_bounds__(256) void bucket_gather(const int* __restrict__ cur,
                                                     const u64* __restrict__ buck,
                                                     const u16* __restrict__ Xbf,
                                                     u16* __restrict__ ACCbf) {
  int wv = blockIdx.x * 4 + (threadIdx.x >> 6);
  int lane = threadIdx.x & 63;
  if (wv >= NN) return;
  int deg = cur[wv]; deg = deg > 64 ? 64 : deg;
  u32 srp_v = 0, nm_v = 0;
  if (lane < deg) {
    u64 r = buck[(long)wv * 64 + lane];
    srp_v = (u32)r; nm_v = (u32)(r >> 32);
  }
  float a0 = 0.f, a1 = 0.f, a2 = 0.f;
  for (int j = 0; j < deg; ++j) {
    u32 srp = (u32)__shfl((int)srp_v, j);
    float nm = __uint_as_float((u32)__shfl((int)nm_v, j));
    int s = srp & 0xFFFFF;
    int r = srp >> 20;
    float xv = bf2f(Xbf[(long)s * 64 + lane]) * nm;
    a0 += (r == 0) ? xv : 0.f;
    a1 += (r == 1) ? xv : 0.f;
    a2 += (r == 2) ? xv : 0.f;
  }
  long o = (long)wv * 192 + lane;
  ACCbf[o]       = f2bf(a0);
  ACCbf[o + 64]  = f2bf(a1);
  ACCbf[o + 128] = f2bf(a2);
}

// ---------------- GRU gate combine; writes h (f32) and h (bf16) ----------------
__global__ __launch_bounds__(256) void gru_combine(const u16* __restrict__ G1,
                                                   const u16* __restrict__ G2,
                                                   const float* __restrict__ bih,
                                                   const float* __restrict__ bhh,
                                                   float* __restrict__ h,
                                                   u16* __restrict__ hbf, int use_h) {
  long t = (long)blockIdx.x * 256 + threadIdx.x;  // one node-quarter (4 feats), NN*16 total
  long node = t >> 4;
  int c0 = (int)(t & 15) * 4;
  const u16* g1 = G1 + node * 192;
  float hv[4] = {0.f, 0.f, 0.f, 0.f};
  if (use_h) {
    float4 t4 = reinterpret_cast<const float4*>(h)[t];
    hv[0] = t4.x; hv[1] = t4.y; hv[2] = t4.z; hv[3] = t4.w;
  }
  float ho[4];
#pragma unroll
  for (int k = 0; k < 4; ++k) {
    int c = c0 + k;
    float ir = bf2f(g1[c])       + bih[c];
    float iz = bf2f(g1[64 + c])  + bih[64 + c];
    float in_ = bf2f(g1[128 + c]) + bih[128 + c];
    float hr = bhh[c], hz = bhh[64 + c], hn = bhh[128 + c];
    if (use_h) {
      const u16* g2 = G2 + node * 192;
      hr += bf2f(g2[c]); hz += bf2f(g2[64 + c]); hn += bf2f(g2[128 + c]);
    }
    float r = 1.f / (1.f + __expf(-(ir + hr)));
    float z = 1.f / (1.f + __expf(-(iz + hz)));
    float nn = tanhf(in_ + r * hn);
    ho[k] = (1.f - z) * nn + z * hv[k];
  }
  reinterpret_cast<float4*>(h)[t] = make_float4(ho[0], ho[1], ho[2], ho[3]);
  reinterpret_cast<ushort4*>(hbf)[t] = make_ushort4(f2bf(ho[0]), f2bf(ho[1]), f2bf(ho[2]), f2bf(ho[3]));
}

// ---------------- tiny final head GEMM (VALU, W staged in LDS) -----------------
template<int KO>
__global__ __launch_bounds__(64) void headfin(const u16* __restrict__ Xbf,
                                              const float* __restrict__ W,
                                              const float* __restrict__ b2,
                                              float* __restrict__ out, int n) {
  __shared__ float ws[KO * 64];
  int lane = threadIdx.x;
  for (int i = lane; i < KO * 64; i += 64) ws[i] = W[i];
  __syncthreads();
  long node = (long)blockIdx.x * 64 + lane;
  const u16* xr = Xbf + node * 64;
  float x[64];
#pragma unroll
  for (int i = 0; i < 16; ++i) {
    ushort4 a4 = reinterpret_cast<const ushort4*>(xr)[i];
    x[4 * i]     = bf2f(a4.x);
    x[4 * i + 1] = bf2f(a4.y);
    x[4 * i + 2] = bf2f(a4.z);
    x[4 * i + 3] = bf2f(a4.w);
  }
#pragma unroll
  for (int o = 0; o < KO; ++o) {
    float a = b2[o];
#pragma unroll
    for (int d = 0; d < 64; ++d) a += x[d] * ws[o * 64 + d];
    if (node < n) out[node * KO + o] = a;
  }
}

extern "C" void kernel_launch(void* const* d_in, const int* in_sizes, int n_in,
                              void* d_out, int out_size, void* d_ws, size_t ws_size,
                              hipStream_t stream) {
  const float* v     = (const float*)d_in[0];
  const int*   src   = (const int*)d_in[1];
  const int*   dst   = (const int*)d_in[2];
  const int*   rt    = (const int*)d_in[3];
  const float* norm  = (const float*)d_in[4];
  const float* emb_W = (const float*)d_in[5];
  // emb_b (d_in[6]) cancels in BN
  const float* emb_g  = (const float*)d_in[7];
  const float* emb_be = (const float*)d_in[8];
  const float* rel_w  = (const float*)d_in[9];
  const float* Wih    = (const float*)d_in[10];
  const float* Whh    = (const float*)d_in[11];
  const float* bih    = (const float*)d_in[12];
  const float* bhh    = (const float*)d_in[13];
  const float* ker_g  = (const float*)d_in[14];
  const float* ker_be = (const float*)d_in[15];
  const float* aW1    = (const float*)d_in[16];
  // a_b1 cancels in BN
  const float* a_g  = (const float*)d_in[18];
  const float* a_be = (const float*)d_in[19];
  const float* aW2  = (const float*)d_in[20];
  const float* ab2  = (const float*)d_in[21];
  const float* bW1  = (const float*)d_in[22];
  // b_b1 cancels in BN
  const float* b_g  = (const float*)d_in[24];
  const float* b_be = (const float*)d_in[25];
  const float* bW2  = (const float*)d_in[26];
  const float* bb2  = (const float*)d_in[27];
  float* out = (float*)d_out;

  // ---- workspace carve-up (all 256B-aligned) ----
  char* p = (char*)d_ws;
  auto nxt = [&](size_t bytes) -> char* {
    char* r = p; p += (bytes + 255) & ~(size_t)255; return r;
  };
  float* Z    = (float*)nxt((size_t)NP * 64 * 4);   // pre-BN f32 scratch
  float* Bh   = (float*)nxt((size_t)NP * 64 * 4);   // GRU state h (f32)
  u16*   X1   = (u16*)nxt((size_t)NP * 64 * 2);     // bf16 [N,64] slot 1
  u16*   X2   = (u16*)nxt((size_t)NP * 64 * 2);     // bf16 [N,64] slot 2
  u16*   ACCB = (u16*)nxt((size_t)NP * 192 * 2);    // gather acc / G2 (aliased)
  u16*   G1B  = (u16*)nxt((size_t)NP * 192 * 2);    // fused gate pre-acts
  u64*   BUCK = (u64*)nxt((size_t)NN * 64 * 8);     // per-dst edge buckets
  int*   CUR  = (int*)nxt((size_t)NN * 4);
  u32*   PWf  = (u32*)nxt(18432 * 4);
  u32*   PWem = (u32*)nxt(2048 * 4);
  u32*   PWhh = (u32*)nxt(6144 * 4);
  u32*   PWa  = (u32*)nxt(2048 * 4);
  u32*   PWb  = (u32*)nxt(2048 * 4);
  float* WROW = (float*)nxt(147456);
  float* ACCs = (float*)nxt(512 * 4);
  float* SC   = (float*)nxt(512 * 4);

  hipMemsetAsync(CUR, 0, (size_t)NN * 4, stream);
  hipMemsetAsync(ACCs, 0, 512 * 4, stream);

  // ---- setup: converts, weight fuse + packs, edge buckets ----
  cvt_f32_bf16<<<6250, 256, 0, stream>>>(v, X1);
  wfuse<<<144, 256, 0, stream>>>(rel_w, Wih, WROW);
  pack_w<<<72, 256, 0, stream>>>(WROW, PWf, 192, 12);
  pack_w<<<8, 256, 0, stream>>>(emb_W, PWem, 64, 4);
  pack_w<<<24, 256, 0, stream>>>(Whh, PWhh, 64, 12);
  pack_w<<<8, 256, 0, stream>>>(aW1, PWa, 64, 4);
  pack_w<<<8, 256, 0, stream>>>(bW1, PWb, 64, 4);
  bucket_scatter<<<6250, 256, 0, stream>>>(src, dst, rt, norm, CUR, BUCK);

  // ---- embedding: h0 = relu(BN(v @ emb_W^T)) -> X2 (bf16) ----
  gemm_mfma<64, 64, 0><<<782, 256, 0, stream>>>(X1, PWem, Z, NN);
  colsum<<<416, 256, 0, stream>>>(Z, ACCs + 0, NN);
  bn_finalize<<<1, 64, 0, stream>>>(ACCs + 0, emb_g, emb_be, SC + 0, 1.f / NN);
  bn_apply_bf<<<6250, 256, 0, stream>>>(Z, X2, SC + 0, 1);

  // ---- layer 1 (h == 0) ----
  bucket_gather<<<25000, 256, 0, stream>>>(CUR, BUCK, X2, ACCB);
  gemm_mfma<192, 192, 1><<<782, 256, 0, stream>>>(ACCB, PWf, G1B, NN);
  gru_combine<<<6250, 256, 0, stream>>>(G1B, (const u16*)nullptr, bih, bhh, Bh, X1, 0);

  // ---- layer 2 ----
  bucket_gather<<<25000, 256, 0, stream>>>(CUR, BUCK, X1, ACCB);
  gemm_mfma<192, 192, 1><<<782, 256, 0, stream>>>(ACCB, PWf, G1B, NN);
  gemm_mfma<64, 192, 1><<<782, 256, 0, stream>>>(X1, PWhh, ACCB, NN);  // G2 = h @ Whh^T
  gru_combine<<<6250, 256, 0, stream>>>(G1B, ACCB, bih, bhh, Bh, X1, 1);

  // ---- hk = BN(h) -> X2 (bf16) ----
  colsum<<<416, 256, 0, stream>>>(Bh, ACCs + 128, NN);
  bn_finalize<<<1, 64, 0, stream>>>(ACCs + 128, ker_g, ker_be, SC + 128, 1.f / NN);
  bn_apply_bf<<<6250, 256, 0, stream>>>(Bh, X2, SC + 128, 0);

  // ---- head A ----
  gemm_mfma<64, 64, 0><<<782, 256, 0, stream>>>(X2, PWa, Z, NN);
  colsum<<<416, 256, 0, stream>>>(Z, ACCs + 256, NN);
  bn_finalize<<<1, 64, 0, stream>>>(ACCs + 256, a_g, a_be, SC + 256, 1.f / NN);
  bn_apply_bf<<<6250, 256, 0, stream>>>(Z, X1, SC + 256, 1);
  headfin<2><<<1563, 64, 0, stream>>>(X1, aW2, ab2, out, NN);

  // ---- head B ----
  gemm_mfma<64, 64, 0><<<782, 256, 0, stream>>>(X2, PWb, Z, NN);
  colsum<<<416, 256, 0, stream>>>(Z, ACCs + 384, NN);
  bn_finalize<<<1, 64, 0, stream>>>(ACCs + 384, b_g, b_be, SC + 384, 1.f / NN);
  bn_apply_bf<<<6250, 256, 0, stream>>>(Z, X1, SC + 384, 1);
  headfin<21><<<1563, 64, 0, stream>>>(X1, bW2, bb2, out + (long)NN * 2, NN);
}

// Round 3
// 571.904 us; speedup vs baseline: 4.4271x; 1.2704x over previous
//
#include <hip/hip_runtime.h>

#define NN 100000
#define NE 1600000
#define NP 100096   // 782 * 128 rows, GEMM tile padding
#define EPSV 1e-5f

typedef unsigned int u32;
typedef unsigned short u16;
typedef unsigned long long u64;
typedef __bf16 bf16x8 __attribute__((ext_vector_type(8)));
typedef float f32x4 __attribute__((ext_vector_type(4)));

__device__ __forceinline__ u16 f2bf(float f) {
  u32 x = __float_as_uint(f);
  return (u16)((x + 0x7FFFu + ((x >> 16) & 1u)) >> 16);  // RNE
}
__device__ __forceinline__ float bf2f(u16 h) { return __uint_as_float(((u32)h) << 16); }

// ---------------- Wfused[kg][j] = sum_k relw[r,ds,k] * Wih[kg,k], j=(r*64+ds) ----
__global__ void wfuse(const float* __restrict__ relw, const float* __restrict__ Wih,
                      float* __restrict__ Wrow) {
  int t = blockIdx.x * 256 + threadIdx.x;
  if (t >= 192 * 192) return;
  int kg = t / 192, j = t % 192;
  const float* a = relw + (j >> 6) * 4096 + (j & 63) * 64;
  const float* b = Wih + kg * 64;
  float s = 0.f;
#pragma unroll
  for (int k = 0; k < 64; ++k) s += a[k] * b[k];
  Wrow[kg * 192 + j] = s;
}

// ---------------- pack W[KO,K] (row-major f32) into bf16 B-fragments ----------
// frag(ks,ot): lane l elem j holds B[k=ks*32+8*(l>>4)+j][n=ot*16+(l&15)] = W[n][k]
__global__ void pack_w(const float* __restrict__ W, u32* __restrict__ out, int K, int KOT) {
  int iu = blockIdx.x * 256 + threadIdx.x;
  int total = KOT * 16 * K / 2;
  if (iu >= total) return;
  int q = iu & 3, lane = (iu >> 2) & 63, f = iu >> 8;
  int ks = f / KOT, ot = f - ks * KOT;
  int o = ot * 16 + (lane & 15);
  int k = ks * 32 + (lane >> 4) * 8 + q * 2;
  out[iu] = (u32)f2bf(W[o * K + k]) | ((u32)f2bf(W[o * K + k + 1]) << 16);
}

// pack head weights folded with ker-BN scale: P = pack(W[o,k] * sc[k]); K=64, KOT=4
__global__ void fold_pack(const float* __restrict__ Wa, const float* __restrict__ Wb,
                          const float* __restrict__ sc, u32* __restrict__ Pa,
                          u32* __restrict__ Pb) {
  int iu = blockIdx.x * 256 + threadIdx.x;  // 4096
  int hsel = iu >> 11;
  int i = iu & 2047;
  const float* W = hsel ? Wb : Wa;
  u32* P = hsel ? Pb : Pa;
  int q = i & 3, lane = (i >> 2) & 63, f = i >> 8;
  int ks = f >> 2, ot = f & 3;
  int o = ot * 16 + (lane & 15);
  int k = ks * 32 + (lane >> 4) * 8 + q * 2;
  P[i] = (u32)f2bf(W[o * 64 + k] * sc[k]) | ((u32)f2bf(W[o * 64 + k + 1] * sc[k + 1]) << 16);
}

// ---------------------------------------------------------------------------
// MFMA GEMM: Y[m,o] = sum_k A[m,k]*W[o,k]
//   AF32: A is f32 (row-clamped to n-1), else bf16 [NP,K]
//   GRU : 0 plain store, 1 GRU h'=(1-z)n, 2 full GRU reading G2B + Hv
//   CS  : fused per-column sum/sumsq atomics (KO==64 paths only)
// ---------------------------------------------------------------------------
template<int K, int KO, int AF32, int GRU, int CS, int OUTBF>
__global__ __launch_bounds__(256) void gemm_mfma(
    const void* __restrict__ Av, const u32* __restrict__ Wpk, void* __restrict__ Yv,
    const float* __restrict__ bih, const float* __restrict__ bhh,
    const u16* __restrict__ G2B, const u16* __restrict__ Hv,
    float* __restrict__ csum, int n) {
  constexpr int KOT = KO / 16, KS = K / 32;
  const int lane = threadIdx.x & 63, w = threadIdx.x >> 6;
  const int rr = lane & 15, kg = lane >> 4;
  const long mbase = (long)blockIdx.x * 128 + w * 32;
  const u16* Abf = (const u16*)Av;
  const float* Af = (const float*)Av;
  __shared__ float cs[128];
  f32x4 acc[2][KOT] = {};
  for (int ks = 0; ks < KS; ++ks) {
    bf16x8 af0, af1;
    if (AF32) {
      long r0 = mbase + rr;      if (r0 > n - 1) r0 = n - 1;
      long r1 = mbase + 16 + rr; if (r1 > n - 1) r1 = n - 1;
      const float* p0 = Af + r0 * K + ks * 32 + kg * 8;
      const float* p1 = Af + r1 * K + ks * 32 + kg * 8;
#pragma unroll
      for (int j = 0; j < 8; ++j) {
        af0[j] = __builtin_bit_cast(__bf16, f2bf(p0[j]));
        af1[j] = __builtin_bit_cast(__bf16, f2bf(p1[j]));
      }
    } else {
      af0 = *reinterpret_cast<const bf16x8*>(Abf + (mbase + rr) * K + ks * 32 + kg * 8);
      af1 = *reinterpret_cast<const bf16x8*>(Abf + (mbase + 16 + rr) * K + ks * 32 + kg * 8);
    }
#pragma unroll
    for (int o = 0; o < KOT; ++o) {
      bf16x8 bfr = *reinterpret_cast<const bf16x8*>(Wpk + ((long)(ks * KOT + o) * 64 + lane) * 4);
      acc[0][o] = __builtin_amdgcn_mfma_f32_16x16x32_bf16(af0, bfr, acc[0][o], 0, 0, 0);
      acc[1][o] = __builtin_amdgcn_mfma_f32_16x16x32_bf16(af1, bfr, acc[1][o], 0, 0, 0);
    }
  }

  if (GRU == 0) {
    float s[4] = {0.f, 0.f, 0.f, 0.f}, ss[4] = {0.f, 0.f, 0.f, 0.f};
#pragma unroll
    for (int tl = 0; tl < 2; ++tl)
#pragma unroll
      for (int o = 0; o < KOT; ++o)
#pragma unroll
        for (int q = 0; q < 4; ++q) {
          long row = mbase + tl * 16 + kg * 4 + q;
          float vv = acc[tl][o][q];
          if (row < n) {
            long off = row * KO + o * 16 + rr;
            if (OUTBF) ((u16*)Yv)[off] = f2bf(vv);
            else       ((float*)Yv)[off] = vv;
            if (CS) { s[o & 3] += vv; ss[o & 3] += vv * vv; }
          }
        }
    if (CS) {
      for (int i = threadIdx.x; i < 128; i += 256) cs[i] = 0.f;
      __syncthreads();
#pragma unroll
      for (int o = 0; o < 4 && o < KOT; ++o) {
        int c = o * 16 + rr;
        atomicAdd(&cs[c], s[o]);
        atomicAdd(&cs[64 + c], ss[o]);
      }
      __syncthreads();
      if (threadIdx.x < 128) atomicAdd(&csum[threadIdx.x], cs[threadIdx.x]);
    }
  } else {
    // GRU epilogue: gates (r,z,n) live in o-tiles {o, o+4, o+8} for h-col c=o*16+rr
    float bi[12], bh_[12];
#pragma unroll
    for (int g = 0; g < 3; ++g)
#pragma unroll
      for (int o = 0; o < 4; ++o) {
        bi[g * 4 + o] = bih[g * 64 + o * 16 + rr];
        bh_[g * 4 + o] = bhh[g * 64 + o * 16 + rr];
      }
#pragma unroll
    for (int tl = 0; tl < 2; ++tl)
#pragma unroll
      for (int o = 0; o < 4; ++o) {
        int c = o * 16 + rr;
#pragma unroll
        for (int q = 0; q < 4; ++q) {
          long row = mbase + tl * 16 + kg * 4 + q;
          float ir = acc[tl][o][q] + bi[o];
          float iz = acc[tl][o + 4][q] + bi[4 + o];
          float in_ = acc[tl][o + 8][q] + bi[8 + o];
          float hr = bh_[o], hz = bh_[4 + o], hn = bh_[8 + o], hv = 0.f;
          if (GRU == 2) {
            const u16* g2 = G2B + row * 192;
            hr += bf2f(g2[c]); hz += bf2f(g2[64 + c]); hn += bf2f(g2[128 + c]);
            hv = bf2f(Hv[row * 64 + c]);
          }
          float rg = 1.f / (1.f + __expf(-(ir + hr)));
          float zg = 1.f / (1.f + __expf(-(iz + hz)));
          float ng = tanhf(in_ + rg * hn);
          float h = (1.f - zg) * ng + (GRU == 2 ? zg * hv : 0.f);
          if (row < n) ((u16*)Yv)[row * 64 + c] = f2bf(h);
        }
      }
  }
}

// ---------------- BN helpers ----------------
__global__ void bn_finalize(const float* __restrict__ acc, const float* __restrict__ gamma,
                            const float* __restrict__ beta, float* __restrict__ scsh,
                            float inv_n) {
  int t = threadIdx.x;  // 64
  float mean = acc[t] * inv_n;
  float var = acc[64 + t] * inv_n - mean * mean;
  float sc = gamma[t] * rsqrtf(var + EPSV);
  scsh[t] = sc;
  scsh[64 + t] = beta[t] - mean * sc;
}

__global__ __launch_bounds__(256) void bn_apply_bf(const float* __restrict__ X,
                                                   u16* __restrict__ Y,
                                                   const float* __restrict__ scsh, int relu) {
  long i = (long)blockIdx.x * 256 + threadIdx.x;  // NN*16 float4s
  float4 v = reinterpret_cast<const float4*>(X)[i];
  int c = (int)((i * 4) & 63);
  v.x = fmaf(v.x, scsh[c],     scsh[64 + c]);
  v.y = fmaf(v.y, scsh[c + 1], scsh[65 + c]);
  v.z = fmaf(v.z, scsh[c + 2], scsh[66 + c]);
  v.w = fmaf(v.w, scsh[c + 3], scsh[67 + c]);
  if (relu) {
    v.x = fmaxf(v.x, 0.f); v.y = fmaxf(v.y, 0.f);
    v.z = fmaxf(v.z, 0.f); v.w = fmaxf(v.w, 0.f);
  }
  reinterpret_cast<ushort4*>(Y)[i] = make_ushort4(f2bf(v.x), f2bf(v.y), f2bf(v.z), f2bf(v.w));
}

// column stats over bf16 matrix (for ker BN)
__global__ __launch_bounds__(256) void colsum_bf(const u16* __restrict__ X,
                                                 float* __restrict__ acc, int n) {
  const int t = threadIdx.x, c = t & 63, w = t >> 6;
  float s = 0.f, ss = 0.f;
  for (int r = blockIdx.x * 4 + w; r < n; r += gridDim.x * 4) {
    float v = bf2f(X[(long)r * 64 + c]);
    s += v; ss += v * v;
  }
  __shared__ float sh[8][64];
  sh[w][c] = s; sh[4 + w][c] = ss;
  __syncthreads();
  if (t < 64) {
    float a = sh[0][t] + sh[1][t] + sh[2][t] + sh[3][t];
    float b = sh[4][t] + sh[5][t] + sh[6][t] + sh[7][t];
    atomicAdd(&acc[t], a);
    atomicAdd(&acc[64 + t], b);
  }
}

// ---------------- edge buckets ----------------
__global__ __launch_bounds__(256) void bucket_scatter(const int4* __restrict__ src4,
                                                      const int4* __restrict__ dst4,
                                                      const int4* __restrict__ rt4,
                                                      const float4* __restrict__ nrm4,
                                                      int* __restrict__ cur,
                                                      u64* __restrict__ buck) {
  int t = blockIdx.x * 256 + threadIdx.x;
  if (t >= NE / 4) return;
  int4 s = src4[t], d = dst4[t], r = rt4[t];
  float4 nm = nrm4[t];
#define PUT(SS, DD, RR, NM2)                                                    \
  { int pos = atomicAdd(&cur[DD], 1);                                           \
    if (pos < 64) {                                                             \
      u32 srp = (u32)(SS) | ((u32)(RR) << 20);                                  \
      buck[(long)(DD) * 64 + pos] = (u64)srp | ((u64)__float_as_uint(NM2) << 32); } }
  PUT(s.x, d.x, r.x, nm.x)
  PUT(s.y, d.y, r.y, nm.y)
  PUT(s.z, d.z, r.z, nm.z)
  PUT(s.w, d.w, r.w, nm.w)
#undef PUT
}

// one wave per node; scalar (readlane) edge walk, unroll 4 for MLP
__global__ __launch_bounds__(256) void bucket_gather(const int* __restrict__ cur,
                                                     const u64* __restrict__ buck,
                                                     const u16* __restrict__ Xbf,
                                                     u16* __restrict__ ACCbf) {
  int wv = blockIdx.x * 4 + (threadIdx.x >> 6);
  int lane = threadIdx.x & 63;
  if (wv >= NN) return;
  int deg = cur[wv]; deg = deg > 64 ? 64 : deg;
  u32 lo = 0, hi = 0;
  if (lane < deg) {
    u64 r = buck[(long)wv * 64 + lane];
    lo = (u32)r; hi = (u32)(r >> 32);
  }
  float a0 = 0.f, a1 = 0.f, a2 = 0.f;
#define GSTEP(JJ)                                                               \
  { u32 srp = (u32)__builtin_amdgcn_readlane((int)lo, (JJ));                    \
    float nm = __uint_as_float((u32)__builtin_amdgcn_readlane((int)hi, (JJ)));  \
    int r = (int)(srp >> 20);                                                   \
    float xv = bf2f(Xbf[(size_t)(srp & 0xFFFFFu) * 64 + lane]);                 \
    float n0 = (r == 0) ? nm : 0.f;                                             \
    float n1 = (r == 1) ? nm : 0.f;                                             \
    float n2 = (r == 2) ? nm : 0.f;                                             \
    a0 = fmaf(xv, n0, a0); a1 = fmaf(xv, n1, a1); a2 = fmaf(xv, n2, a2); }
  int j = 0;
  for (; j + 4 <= deg; j += 4) { GSTEP(j) GSTEP(j + 1) GSTEP(j + 2) GSTEP(j + 3) }
  for (; j < deg; ++j) { GSTEP(j) }
#undef GSTEP
  long o = (long)wv * 192 + lane;
  ACCbf[o] = f2bf(a0);
  ACCbf[o + 64] = f2bf(a1);
  ACCbf[o + 128] = f2bf(a2);
}

// ---------------- final head: BN+ReLU from f32 pre-acts, then tiny GEMM -------
template<int KO>
__global__ __launch_bounds__(256) void headfin_bn(const float* __restrict__ Z,
                                                  const float* __restrict__ scsh,
                                                  const float* __restrict__ W2,
                                                  const float* __restrict__ b2,
                                                  float* __restrict__ out, int n) {
  __shared__ float ws[KO * 64];
  for (int i = threadIdx.x; i < KO * 64; i += 256) ws[i] = W2[i];
  __syncthreads();
  long node = (long)blockIdx.x * 256 + threadIdx.x;
  if (node >= n) return;
  float x[64];
#pragma unroll
  for (int i = 0; i < 16; ++i) {
    float4 z4 = reinterpret_cast<const float4*>(Z + node * 64)[i];
    int c = i * 4;
    x[c]     = fmaxf(fmaf(z4.x, scsh[c],     scsh[64 + c]), 0.f);
    x[c + 1] = fmaxf(fmaf(z4.y, scsh[c + 1], scsh[65 + c]), 0.f);
    x[c + 2] = fmaxf(fmaf(z4.z, scsh[c + 2], scsh[66 + c]), 0.f);
    x[c + 3] = fmaxf(fmaf(z4.w, scsh[c + 3], scsh[67 + c]), 0.f);
  }
#pragma unroll
  for (int o = 0; o < KO; ++o) {
    float a = b2[o];
#pragma unroll
    for (int d = 0; d < 64; ++d) a = fmaf(x[d], ws[o * 64 + d], a);
    out[node * KO + o] = a;
  }
}

extern "C" void kernel_launch(void* const* d_in, const int* in_sizes, int n_in,
                              void* d_out, int out_size, void* d_ws, size_t ws_size,
                              hipStream_t stream) {
  const float* v     = (const float*)d_in[0];
  const int*   src   = (const int*)d_in[1];
  const int*   dst   = (const int*)d_in[2];
  const int*   rt    = (const int*)d_in[3];
  const float* norm  = (const float*)d_in[4];
  const float* emb_W = (const float*)d_in[5];
  // emb_b (d_in[6]) cancels in BN
  const float* emb_g  = (const float*)d_in[7];
  const float* emb_be = (const float*)d_in[8];
  const float* rel_w  = (const float*)d_in[9];
  const float* Wih    = (const float*)d_in[10];
  const float* Whh    = (const float*)d_in[11];
  const float* bih    = (const float*)d_in[12];
  const float* bhh    = (const float*)d_in[13];
  const float* ker_g  = (const float*)d_in[14];
  const float* ker_be = (const float*)d_in[15];
  const float* aW1    = (const float*)d_in[16];
  // a_b1 cancels in BN
  const float* a_g  = (const float*)d_in[18];
  const float* a_be = (const float*)d_in[19];
  const float* aW2  = (const float*)d_in[20];
  const float* ab2  = (const float*)d_in[21];
  const float* bW1  = (const float*)d_in[22];
  // b_b1 cancels in BN
  const float* b_g  = (const float*)d_in[24];
  const float* b_be = (const float*)d_in[25];
  const float* bW2  = (const float*)d_in[26];
  const float* bb2  = (const float*)d_in[27];
  float* out = (float*)d_out;

  // ---- workspace carve-up ----
  char* p = (char*)d_ws;
  auto nxt = [&](size_t bytes) -> char* {
    char* r = p; p += (bytes + 255) & ~(size_t)255; return r;
  };
  float* Z    = (float*)nxt((size_t)NP * 64 * 4);   // f32 pre-BN scratch
  u16*   X1   = (u16*)nxt((size_t)NP * 64 * 2);     // h (bf16)
  u16*   X2   = (u16*)nxt((size_t)NP * 64 * 2);     // h0 (bf16)
  u16*   ACCB = (u16*)nxt((size_t)NP * 192 * 2);    // gathered rel-sums
  u16*   G2B  = (u16*)nxt((size_t)NP * 192 * 2);    // h @ Whh^T
  u64*   BUCK = (u64*)nxt((size_t)NN * 64 * 8);
  int*   CUR  = (int*)nxt((size_t)NN * 4);
  u32*   PWf  = (u32*)nxt(18432 * 4);
  u32*   PWem = (u32*)nxt(2048 * 4);
  u32*   PWhh = (u32*)nxt(6144 * 4);
  u32*   PWa  = (u32*)nxt(2048 * 4);
  u32*   PWb  = (u32*)nxt(2048 * 4);
  float* WROW = (float*)nxt(147456);
  float* ACCs = (float*)nxt(512 * 4);
  float* SC   = (float*)nxt(512 * 4);

  hipMemsetAsync(CUR, 0, (size_t)NN * 4, stream);
  hipMemsetAsync(ACCs, 0, 512 * 4, stream);

  // setup
  wfuse<<<144, 256, 0, stream>>>(rel_w, Wih, WROW);
  pack_w<<<72, 256, 0, stream>>>(WROW, PWf, 192, 12);
  pack_w<<<8, 256, 0, stream>>>(emb_W, PWem, 64, 4);
  pack_w<<<24, 256, 0, stream>>>(Whh, PWhh, 64, 12);
  bucket_scatter<<<1563, 256, 0, stream>>>((const int4*)src, (const int4*)dst,
                                           (const int4*)rt, (const float4*)norm, CUR, BUCK);

  // embedding: Z = v @ emb_W^T (f32 A, fused colsum); X2 = bf16(relu(BN(Z)))
  gemm_mfma<64, 64, 1, 0, 1, 0><<<782, 256, 0, stream>>>(v, PWem, Z, nullptr, nullptr,
                                                         nullptr, nullptr, ACCs + 0, NN);
  bn_finalize<<<1, 64, 0, stream>>>(ACCs + 0, emb_g, emb_be, SC + 0, 1.f / NN);
  bn_apply_bf<<<6250, 256, 0, stream>>>(Z, X2, SC + 0, 1);

  // layer 1 (h==0): gather -> fused GEMM+GRU -> X1 = h1
  bucket_gather<<<25000, 256, 0, stream>>>(CUR, BUCK, X2, ACCB);
  gemm_mfma<192, 192, 0, 1, 0, 1><<<782, 256, 0, stream>>>(ACCB, PWf, X1, bih, bhh,
                                                           nullptr, nullptr, nullptr, NN);

  // layer 2: gather(h1) -> G2 = h1 @ Whh^T -> fused GEMM+GRU -> X1 = h2
  bucket_gather<<<25000, 256, 0, stream>>>(CUR, BUCK, X1, ACCB);
  gemm_mfma<64, 192, 0, 0, 0, 1><<<782, 256, 0, stream>>>(X1, PWhh, G2B, nullptr, nullptr,
                                                          nullptr, nullptr, nullptr, NN);
  gemm_mfma<192, 192, 0, 2, 0, 1><<<782, 256, 0, stream>>>(ACCB, PWf, X1, bih, bhh,
                                                           G2B, X1, nullptr, NN);

  // ker BN stats on h2; fold scale into head weights (shift cancels in head BN)
  colsum_bf<<<416, 256, 0, stream>>>(X1, ACCs + 128, NN);
  bn_finalize<<<1, 64, 0, stream>>>(ACCs + 128, ker_g, ker_be, SC + 128, 1.f / NN);
  fold_pack<<<16, 256, 0, stream>>>(aW1, bW1, SC + 128, PWa, PWb);

  // head A
  gemm_mfma<64, 64, 0, 0, 1, 0><<<782, 256, 0, stream>>>(X1, PWa, Z, nullptr, nullptr,
                                                         nullptr, nullptr, ACCs + 256, NN);
  bn_finalize<<<1, 64, 0, stream>>>(ACCs + 256, a_g, a_be, SC + 256, 1.f / NN);
  headfin_bn<2><<<391, 256, 0, stream>>>(Z, SC + 256, aW2, ab2, out, NN);

  // head B
  gemm_mfma<64, 64, 0, 0, 1, 0><<<782, 256, 0, stream>>>(X1, PWb, Z, nullptr, nullptr,
                                                         nullptr, nullptr, ACCs + 384, NN);
  bn_finalize<<<1, 64, 0, stream>>>(ACCs + 384, b_g, b_be, SC + 384, 1.f / NN);
  headfin_bn<21><<<391, 256, 0, stream>>>(Z, SC + 384, bW2, bb2, out + (long)NN * 2, NN);
}

// Round 4
// 533.990 us; speedup vs baseline: 4.7414x; 1.0710x over previous
//
#include <hip/hip_runtime.h>

#define NN 100000
#define NE 1600000
#define NP 100096   // 782 * 128 rows, GEMM tile padding
#define EPSV 1e-5f

typedef unsigned int u32;
typedef unsigned short u16;
typedef unsigned long long u64;
typedef __bf16 bf16x8 __attribute__((ext_vector_type(8)));
typedef float f32x4 __attribute__((ext_vector_type(4)));

__device__ __forceinline__ u16 f2bf(float f) {
  u32 x = __float_as_uint(f);
  return (u16)((x + 0x7FFFu + ((x >> 16) & 1u)) >> 16);  // RNE
}
__device__ __forceinline__ float bf2f(u16 h) { return __uint_as_float(((u32)h) << 16); }

// ---------------- setup A: wfuse (blocks 0..143) | pack emb (144..151) | pack Whh (152..175)
// wfuse: Wrow[kg*192+j] = sum_k relw[r,ds,k]*Wih[kg,k], j=(r*64+ds)
// pack layout: frag(ks,ot): lane l elem j holds W[o=ot*16+(l&15)][k=ks*32+(l>>4)*8+j]
__device__ __forceinline__ void pack_one(const float* W, u32* out, int K, int KOT, int i) {
  int q = i & 3, lane = (i >> 2) & 63, f = i >> 8;
  int ks = f / KOT, ot = f - ks * KOT;
  int o = ot * 16 + (lane & 15);
  int k = ks * 32 + (lane >> 4) * 8 + q * 2;
  out[i] = (u32)f2bf(W[o * K + k]) | ((u32)f2bf(W[o * K + k + 1]) << 16);
}

__global__ void setupA(const float* __restrict__ relw, const float* __restrict__ Wih,
                       const float* __restrict__ embW, const float* __restrict__ Whh,
                       float* __restrict__ Wrow, u32* __restrict__ PWem, u32* __restrict__ PWhh) {
  int b = blockIdx.x;
  if (b < 144) {
    int t = b * 256 + threadIdx.x;
    if (t >= 192 * 192) return;
    int kg = t / 192, j = t % 192;
    const float* a = relw + (j >> 6) * 4096 + (j & 63) * 64;
    const float* w = Wih + kg * 64;
    float s = 0.f;
#pragma unroll
    for (int k = 0; k < 64; ++k) s += a[k] * w[k];
    Wrow[kg * 192 + j] = s;
  } else if (b < 152) {
    pack_one(embW, PWem, 64, 4, (b - 144) * 256 + threadIdx.x);
  } else {
    pack_one(Whh, PWhh, 64, 12, (b - 152) * 256 + threadIdx.x);
  }
}

__global__ void pack_wf(const float* __restrict__ Wrow, u32* __restrict__ PWf) {
  pack_one(Wrow, PWf, 192, 12, blockIdx.x * 256 + threadIdx.x);  // 72 blocks
}

// pack head weights folded with ker-BN scale
__global__ void fold_pack(const float* __restrict__ Wa, const float* __restrict__ Wb,
                          const float* __restrict__ sc, u32* __restrict__ Pa,
                          u32* __restrict__ Pb) {
  int iu = blockIdx.x * 256 + threadIdx.x;  // 4096
  int hsel = iu >> 11;
  int i = iu & 2047;
  const float* W = hsel ? Wb : Wa;
  u32* P = hsel ? Pb : Pa;
  int q = i & 3, lane = (i >> 2) & 63, f = i >> 8;
  int ks = f >> 2, ot = f & 3;
  int o = ot * 16 + (lane & 15);
  int k = ks * 32 + (lane >> 4) * 8 + q * 2;
  P[i] = (u32)f2bf(W[o * 64 + k] * sc[k]) | ((u32)f2bf(W[o * 64 + k + 1] * sc[k + 1]) << 16);
}

// ---------------- CSR build ----------------
__global__ __launch_bounds__(256) void edge_count(const int* __restrict__ dst,
                                                  int* __restrict__ cnt,
                                                  int* __restrict__ epos) {
  int e = blockIdx.x * 256 + threadIdx.x;
  if (e >= NE) return;
  epos[e] = atomicAdd(&cnt[dst[e]], 1);
}

__global__ __launch_bounds__(256) void scanA(const int* __restrict__ cnt,
                                             int* __restrict__ lps, int* __restrict__ bsum) {
  int t = threadIdx.x;
  int i = blockIdx.x * 256 + t;
  int v = (i < NN) ? cnt[i] : 0;
  __shared__ int sh[256];
  sh[t] = v;
  __syncthreads();
#pragma unroll
  for (int off = 1; off < 256; off <<= 1) {
    int u = (t >= off) ? sh[t - off] : 0;
    __syncthreads();
    sh[t] += u;
    __syncthreads();
  }
  lps[i] = sh[t] - v;  // exclusive
  if (t == 255) bsum[blockIdx.x] = sh[255];
}

__global__ __launch_bounds__(512) void scanB(int* __restrict__ bsum) {  // 391 entries
  int t = threadIdx.x;
  int v = (t < 391) ? bsum[t] : 0;
  __shared__ int sh[512];
  sh[t] = v;
  __syncthreads();
#pragma unroll
  for (int off = 1; off < 512; off <<= 1) {
    int u = (t >= off) ? sh[t - off] : 0;
    __syncthreads();
    sh[t] += u;
    __syncthreads();
  }
  if (t < 391) bsum[t] = sh[t] - v;  // exclusive block offsets
}

__global__ __launch_bounds__(256) void scanC(const int* __restrict__ lps,
                                             const int* __restrict__ bsum,
                                             int* __restrict__ rowptr) {
  int i = blockIdx.x * 256 + threadIdx.x;
  if (i > NN) return;
  rowptr[i] = lps[i] + bsum[i >> 8];
}

__global__ __launch_bounds__(256) void edge_place(const int* __restrict__ src,
                                                  const int* __restrict__ dst,
                                                  const int* __restrict__ rt,
                                                  const float* __restrict__ nrm,
                                                  const int* __restrict__ epos,
                                                  const int* __restrict__ rowptr,
                                                  u64* __restrict__ csr) {
  int e = blockIdx.x * 256 + threadIdx.x;
  if (e >= NE) return;
  int pos = rowptr[dst[e]] + epos[e];
  u32 srp = (u32)src[e] | ((u32)rt[e] << 20);
  csr[pos] = (u64)srp | ((u64)__float_as_uint(nrm[e]) << 32);
}

// ---------------- CSR gather: one wave per node, scalar edge walk -------------
__global__ __launch_bounds__(256) void csr_gather(const int* __restrict__ rowptr,
                                                  const u64* __restrict__ csr,
                                                  const u16* __restrict__ Xbf,
                                                  u16* __restrict__ ACCbf) {
  int wv = blockIdx.x * 4 + (threadIdx.x >> 6);
  int lane = threadIdx.x & 63;
  if (wv >= NN) return;
  int base = rowptr[wv], end = rowptr[wv + 1];
  float a0 = 0.f, a1 = 0.f, a2 = 0.f;
#define GSTEP(JJ)                                                               \
  { u32 srp = (u32)__builtin_amdgcn_readlane((int)lo, (JJ));                    \
    float nm = __uint_as_float((u32)__builtin_amdgcn_readlane((int)hi, (JJ)));  \
    int r = (int)(srp >> 20);                                                   \
    float xv = bf2f(Xbf[(size_t)(srp & 0xFFFFFu) * 64 + lane]);                 \
    float n0 = (r == 0) ? nm : 0.f;                                             \
    float n1 = (r == 1) ? nm : 0.f;                                             \
    float n2 = (r == 2) ? nm : 0.f;                                             \
    a0 = fmaf(xv, n0, a0); a1 = fmaf(xv, n1, a1); a2 = fmaf(xv, n2, a2); }
  for (int c = base; c < end; c += 64) {
    int m = end - c; m = m > 64 ? 64 : m;
    u32 lo = 0, hi = 0;
    if (lane < m) {
      u64 r = csr[(size_t)c + lane];
      lo = (u32)r; hi = (u32)(r >> 32);
    }
    int j = 0;
    for (; j + 8 <= m; j += 8) {
      GSTEP(j) GSTEP(j + 1) GSTEP(j + 2) GSTEP(j + 3)
      GSTEP(j + 4) GSTEP(j + 5) GSTEP(j + 6) GSTEP(j + 7)
    }
    for (; j < m; ++j) { GSTEP(j) }
  }
#undef GSTEP
  long o = (long)wv * 192 + lane;
  ACCbf[o] = f2bf(a0);
  ACCbf[o + 64] = f2bf(a1);
  ACCbf[o + 128] = f2bf(a2);
}

// ---------------------------------------------------------------------------
// MFMA GEMM: Y[m,o] = sum_k A[m,k]*W[o,k]
//   AF32: A is f32 (row-clamped), else bf16; GRU: 0 store, 1 h'=(1-z)n, 2 full
//   CS: fused column sum/sumsq atomics (KO==64 only)
// ---------------------------------------------------------------------------
template<int K, int KO, int AF32, int GRU, int CS, int OUTBF>
__global__ __launch_bounds__(256) void gemm_mfma(
    const void* __restrict__ Av, const u32* __restrict__ Wpk, void* __restrict__ Yv,
    const float* __restrict__ bih, const float* __restrict__ bhh,
    const u16* __restrict__ G2B, const u16* __restrict__ Hv,
    float* __restrict__ csum, int n) {
  constexpr int KOT = KO / 16, KS = K / 32;
  const int lane = threadIdx.x & 63, w = threadIdx.x >> 6;
  const int rr = lane & 15, kg = lane >> 4;
  const long mbase = (long)blockIdx.x * 128 + w * 32;
  const u16* Abf = (const u16*)Av;
  const float* Af = (const float*)Av;
  __shared__ float cs[128];
  f32x4 acc[2][KOT] = {};
  for (int ks = 0; ks < KS; ++ks) {
    bf16x8 af0, af1;
    if (AF32) {
      long r0 = mbase + rr;      if (r0 > n - 1) r0 = n - 1;
      long r1 = mbase + 16 + rr; if (r1 > n - 1) r1 = n - 1;
      const float* p0 = Af + r0 * K + ks * 32 + kg * 8;
      const float* p1 = Af + r1 * K + ks * 32 + kg * 8;
#pragma unroll
      for (int j = 0; j < 8; ++j) {
        af0[j] = __builtin_bit_cast(__bf16, f2bf(p0[j]));
        af1[j] = __builtin_bit_cast(__bf16, f2bf(p1[j]));
      }
    } else {
      af0 = *reinterpret_cast<const bf16x8*>(Abf + (mbase + rr) * K + ks * 32 + kg * 8);
      af1 = *reinterpret_cast<const bf16x8*>(Abf + (mbase + 16 + rr) * K + ks * 32 + kg * 8);
    }
#pragma unroll
    for (int o = 0; o < KOT; ++o) {
      bf16x8 bfr = *reinterpret_cast<const bf16x8*>(Wpk + ((long)(ks * KOT + o) * 64 + lane) * 4);
      acc[0][o] = __builtin_amdgcn_mfma_f32_16x16x32_bf16(af0, bfr, acc[0][o], 0, 0, 0);
      acc[1][o] = __builtin_amdgcn_mfma_f32_16x16x32_bf16(af1, bfr, acc[1][o], 0, 0, 0);
    }
  }

  if (GRU == 0) {
    float s[4] = {0.f, 0.f, 0.f, 0.f}, ss[4] = {0.f, 0.f, 0.f, 0.f};
#pragma unroll
    for (int tl = 0; tl < 2; ++tl)
#pragma unroll
      for (int o = 0; o < KOT; ++o)
#pragma unroll
        for (int q = 0; q < 4; ++q) {
          long row = mbase + tl * 16 + kg * 4 + q;
          float vv = acc[tl][o][q];
          if (row < n) {
            long off = row * KO + o * 16 + rr;
            if (OUTBF) ((u16*)Yv)[off] = f2bf(vv);
            else       ((float*)Yv)[off] = vv;
            if (CS) { s[o & 3] += vv; ss[o & 3] += vv * vv; }
          }
        }
    if (CS) {
      for (int i = threadIdx.x; i < 128; i += 256) cs[i] = 0.f;
      __syncthreads();
#pragma unroll
      for (int o = 0; o < 4 && o < KOT; ++o) {
        int c = o * 16 + rr;
        atomicAdd(&cs[c], s[o]);
        atomicAdd(&cs[64 + c], ss[o]);
      }
      __syncthreads();
      if (threadIdx.x < 128) atomicAdd(&csum[threadIdx.x], cs[threadIdx.x]);
    }
  } else {
    float bi[12], bh_[12];
#pragma unroll
    for (int g = 0; g < 3; ++g)
#pragma unroll
      for (int o = 0; o < 4; ++o) {
        bi[g * 4 + o] = bih[g * 64 + o * 16 + rr];
        bh_[g * 4 + o] = bhh[g * 64 + o * 16 + rr];
      }
#pragma unroll
    for (int tl = 0; tl < 2; ++tl)
#pragma unroll
      for (int o = 0; o < 4; ++o) {
        int c = o * 16 + rr;
#pragma unroll
        for (int q = 0; q < 4; ++q) {
          long row = mbase + tl * 16 + kg * 4 + q;
          float ir = acc[tl][o][q] + bi[o];
          float iz = acc[tl][o + 4][q] + bi[4 + o];
          float in_ = acc[tl][o + 8][q] + bi[8 + o];
          float hr = bh_[o], hz = bh_[4 + o], hn = bh_[8 + o], hv = 0.f;
          if (GRU == 2) {
            const u16* g2 = G2B + row * 192;
            hr += bf2f(g2[c]); hz += bf2f(g2[64 + c]); hn += bf2f(g2[128 + c]);
            hv = bf2f(Hv[row * 64 + c]);
          }
          float rg = 1.f / (1.f + __expf(-(ir + hr)));
          float zg = 1.f / (1.f + __expf(-(iz + hz)));
          float ng = tanhf(in_ + rg * hn);
          float h = (1.f - zg) * ng + (GRU == 2 ? zg * hv : 0.f);
          if (row < n) ((u16*)Yv)[row * 64 + c] = f2bf(h);
        }
      }
  }
}

// ---------------- BN helpers ----------------
__global__ void bn_finalize(const float* __restrict__ acc, const float* __restrict__ gamma,
                            const float* __restrict__ beta, float* __restrict__ scsh,
                            float inv_n) {
  int t = threadIdx.x;  // 64
  float mean = acc[t] * inv_n;
  float var = acc[64 + t] * inv_n - mean * mean;
  float sc = gamma[t] * rsqrtf(var + EPSV);
  scsh[t] = sc;
  scsh[64 + t] = beta[t] - mean * sc;
}

__global__ __launch_bounds__(256) void bn_apply_bf(const float* __restrict__ X,
                                                   u16* __restrict__ Y,
                                                   const float* __restrict__ scsh, int relu) {
  long i = (long)blockIdx.x * 256 + threadIdx.x;  // NN*16 float4s
  float4 v = reinterpret_cast<const float4*>(X)[i];
  int c = (int)((i * 4) & 63);
  v.x = fmaf(v.x, scsh[c],     scsh[64 + c]);
  v.y = fmaf(v.y, scsh[c + 1], scsh[65 + c]);
  v.z = fmaf(v.z, scsh[c + 2], scsh[66 + c]);
  v.w = fmaf(v.w, scsh[c + 3], scsh[67 + c]);
  if (relu) {
    v.x = fmaxf(v.x, 0.f); v.y = fmaxf(v.y, 0.f);
    v.z = fmaxf(v.z, 0.f); v.w = fmaxf(v.w, 0.f);
  }
  reinterpret_cast<ushort4*>(Y)[i] = make_ushort4(f2bf(v.x), f2bf(v.y), f2bf(v.z), f2bf(v.w));
}

__global__ __launch_bounds__(256) void colsum_bf(const u16* __restrict__ X,
                                                 float* __restrict__ acc, int n) {
  const int t = threadIdx.x, c = t & 63, w = t >> 6;
  float s = 0.f, ss = 0.f;
  for (int r = blockIdx.x * 4 + w; r < n; r += gridDim.x * 4) {
    float v = bf2f(X[(long)r * 64 + c]);
    s += v; ss += v * v;
  }
  __shared__ float sh[8][64];
  sh[w][c] = s; sh[4 + w][c] = ss;
  __syncthreads();
  if (t < 64) {
    float a = sh[0][t] + sh[1][t] + sh[2][t] + sh[3][t];
    float b = sh[4][t] + sh[5][t] + sh[6][t] + sh[7][t];
    atomicAdd(&acc[t], a);
    atomicAdd(&acc[64 + t], b);
  }
}

// ---------------- final head: BN+ReLU from f32 pre-acts, tiny GEMM -----------
template<int KO>
__global__ __launch_bounds__(256) void headfin_bn(const float* __restrict__ Z,
                                                  const float* __restrict__ scsh,
                                                  const float* __restrict__ W2,
                                                  const float* __restrict__ b2,
                                                  float* __restrict__ out, int n) {
  __shared__ float ws[KO * 64];
  for (int i = threadIdx.x; i < KO * 64; i += 256) ws[i] = W2[i];
  __syncthreads();
  long node = (long)blockIdx.x * 256 + threadIdx.x;
  if (node >= n) return;
  float x[64];
#pragma unroll
  for (int i = 0; i < 16; ++i) {
    float4 z4 = reinterpret_cast<const float4*>(Z + node * 64)[i];
    int c = i * 4;
    x[c]     = fmaxf(fmaf(z4.x, scsh[c],     scsh[64 + c]), 0.f);
    x[c + 1] = fmaxf(fmaf(z4.y, scsh[c + 1], scsh[65 + c]), 0.f);
    x[c + 2] = fmaxf(fmaf(z4.z, scsh[c + 2], scsh[66 + c]), 0.f);
    x[c + 3] = fmaxf(fmaf(z4.w, scsh[c + 3], scsh[67 + c]), 0.f);
  }
#pragma unroll
  for (int o = 0; o < KO; ++o) {
    float a = b2[o];
#pragma unroll
    for (int d = 0; d < 64; ++d) a = fmaf(x[d], ws[o * 64 + d], a);
    out[node * KO + o] = a;
  }
}

extern "C" void kernel_launch(void* const* d_in, const int* in_sizes, int n_in,
                              void* d_out, int out_size, void* d_ws, size_t ws_size,
                              hipStream_t stream) {
  const float* v     = (const float*)d_in[0];
  const int*   src   = (const int*)d_in[1];
  const int*   dst   = (const int*)d_in[2];
  const int*   rt    = (const int*)d_in[3];
  const float* norm  = (const float*)d_in[4];
  const float* emb_W = (const float*)d_in[5];
  const float* emb_g  = (const float*)d_in[7];
  const float* emb_be = (const float*)d_in[8];
  const float* rel_w  = (const float*)d_in[9];
  const float* Wih    = (const float*)d_in[10];
  const float* Whh    = (const float*)d_in[11];
  const float* bih    = (const float*)d_in[12];
  const float* bhh    = (const float*)d_in[13];
  const float* ker_g  = (const float*)d_in[14];
  const float* ker_be = (const float*)d_in[15];
  const float* aW1    = (const float*)d_in[16];
  const float* a_g  = (const float*)d_in[18];
  const float* a_be = (const float*)d_in[19];
  const float* aW2  = (const float*)d_in[20];
  const float* ab2  = (const float*)d_in[21];
  const float* bW1  = (const float*)d_in[22];
  const float* b_g  = (const float*)d_in[24];
  const float* b_be = (const float*)d_in[25];
  const float* bW2  = (const float*)d_in[26];
  const float* bb2  = (const float*)d_in[27];
  float* out = (float*)d_out;

  // ---- workspace carve-up ----
  char* p = (char*)d_ws;
  auto nxt = [&](size_t bytes) -> char* {
    char* r = p; p += (bytes + 255) & ~(size_t)255; return r;
  };
  int*   CNT  = (int*)nxt((size_t)NP * 4);          // counts (memset w/ ACCs)
  float* ACCs = (float*)nxt(512 * 4);               // BN stat accumulators
  float* Z    = (float*)nxt((size_t)NP * 64 * 4);   // f32 pre-BN scratch
  u16*   X1   = (u16*)nxt((size_t)NP * 64 * 2);     // h (bf16)
  u16*   X2   = (u16*)nxt((size_t)NP * 64 * 2);     // h0 (bf16)
  u16*   ACCB = (u16*)nxt((size_t)NP * 192 * 2);    // gathered rel-sums
  u16*   G2B  = (u16*)nxt((size_t)NP * 192 * 2);    // h @ Whh^T
  u64*   CSR  = (u64*)nxt((size_t)NE * 8);          // edge records (dst-sorted)
  int*   EPOS = (int*)nxt((size_t)NE * 4);          // within-row rank
  int*   LPS  = (int*)nxt((size_t)NP * 4);
  int*   BSUM = (int*)nxt(512 * 4);
  int*   ROWP = (int*)nxt((size_t)(NN + 256) * 4);
  u32*   PWf  = (u32*)nxt(18432 * 4);
  u32*   PWem = (u32*)nxt(2048 * 4);
  u32*   PWhh = (u32*)nxt(6144 * 4);
  u32*   PWa  = (u32*)nxt(2048 * 4);
  u32*   PWb  = (u32*)nxt(2048 * 4);
  float* WROW = (float*)nxt(147456);
  float* SC   = (float*)nxt(512 * 4);

  hipMemsetAsync(CNT, 0, (size_t)(NP + 512) * 4, stream);  // CNT + ACCs contiguous

  // setup + CSR build
  setupA<<<176, 256, 0, stream>>>(rel_w, Wih, emb_W, Whh, WROW, PWem, PWhh);
  edge_count<<<6250, 256, 0, stream>>>(dst, CNT, EPOS);
  scanA<<<391, 256, 0, stream>>>(CNT, LPS, BSUM);
  scanB<<<1, 512, 0, stream>>>(BSUM);
  scanC<<<392, 256, 0, stream>>>(LPS, BSUM, ROWP);
  edge_place<<<6250, 256, 0, stream>>>(src, dst, rt, norm, EPOS, ROWP, CSR);
  pack_wf<<<72, 256, 0, stream>>>(WROW, PWf);

  // embedding: Z = v @ emb_W^T (fused colsum); X2 = bf16(relu(BN(Z)))
  gemm_mfma<64, 64, 1, 0, 1, 0><<<782, 256, 0, stream>>>(v, PWem, Z, nullptr, nullptr,
                                                         nullptr, nullptr, ACCs + 0, NN);
  bn_finalize<<<1, 64, 0, stream>>>(ACCs + 0, emb_g, emb_be, SC + 0, 1.f / NN);
  bn_apply_bf<<<6250, 256, 0, stream>>>(Z, X2, SC + 0, 1);

  // layer 1 (h==0): gather -> fused GEMM+GRU -> X1 = h1
  csr_gather<<<25000, 256, 0, stream>>>(ROWP, CSR, X2, ACCB);
  gemm_mfma<192, 192, 0, 1, 0, 1><<<782, 256, 0, stream>>>(ACCB, PWf, X1, bih, bhh,
                                                           nullptr, nullptr, nullptr, NN);

  // layer 2: gather(h1) -> G2 = h1 @ Whh^T -> fused GEMM+GRU -> X1 = h2
  csr_gather<<<25000, 256, 0, stream>>>(ROWP, CSR, X1, ACCB);
  gemm_mfma<64, 192, 0, 0, 0, 1><<<782, 256, 0, stream>>>(X1, PWhh, G2B, nullptr, nullptr,
                                                          nullptr, nullptr, nullptr, NN);
  gemm_mfma<192, 192, 0, 2, 0, 1><<<782, 256, 0, stream>>>(ACCB, PWf, X1, bih, bhh,
                                                           G2B, X1, nullptr, NN);

  // ker BN stats on h2; fold scale into head weights (shift cancels in head BN)
  colsum_bf<<<416, 256, 0, stream>>>(X1, ACCs + 128, NN);
  bn_finalize<<<1, 64, 0, stream>>>(ACCs + 128, ker_g, ker_be, SC + 128, 1.f / NN);
  fold_pack<<<16, 256, 0, stream>>>(aW1, bW1, SC + 128, PWa, PWb);

  // head A
  gemm_mfma<64, 64, 0, 0, 1, 0><<<782, 256, 0, stream>>>(X1, PWa, Z, nullptr, nullptr,
                                                         nullptr, nullptr, ACCs + 256, NN);
  bn_finalize<<<1, 64, 0, stream>>>(ACCs + 256, a_g, a_be, SC + 256, 1.f / NN);
  headfin_bn<2><<<391, 256, 0, stream>>>(Z, SC + 256, aW2, ab2, out, NN);

  // head B
  gemm_mfma<64, 64, 0, 0, 1, 0><<<782, 256, 0, stream>>>(X1, PWb, Z, nullptr, nullptr,
                                                         nullptr, nullptr, ACCs + 384, NN);
  bn_finalize<<<1, 64, 0, stream>>>(ACCs + 384, b_g, b_be, SC + 384, 1.f / NN);
  headfin_bn<21><<<391, 256, 0, stream>>>(Z, SC + 384, bW2, bb2, out + (long)NN * 2, NN);
}

// Round 5
// 470.085 us; speedup vs baseline: 5.3860x; 1.1359x over previous
//
#include <hip/hip_runtime.h>

#define NN 100000
#define NE 1600000
#define NP 100096   // 782 * 128 rows, GEMM tile padding
#define EPSV 1e-5f

typedef unsigned int u32;
typedef unsigned short u16;
typedef unsigned long long u64;
typedef __bf16 bf16x8 __attribute__((ext_vector_type(8)));
typedef float f32x4 __attribute__((ext_vector_type(4)));

#define GLBP(x) ((const __attribute__((address_space(1))) u32*)(x))
#define LDSP(x) ((__attribute__((address_space(3))) u32*)(x))

__device__ __forceinline__ u16 f2bf(float f) {
  u32 x = __float_as_uint(f);
  return (u16)((x + 0x7FFFu + ((x >> 16) & 1u)) >> 16);  // RNE
}
__device__ __forceinline__ float bf2f(u16 h) { return __uint_as_float(((u32)h) << 16); }

// ---------------- setup A: wfuse (blocks 0..143) | pack emb (144..151) | pack Whh (152..175)
__device__ __forceinline__ void pack_one(const float* W, u32* out, int K, int KOT, int i) {
  int q = i & 3, lane = (i >> 2) & 63, f = i >> 8;
  int ks = f / KOT, ot = f - ks * KOT;
  int o = ot * 16 + (lane & 15);
  int k = ks * 32 + (lane >> 4) * 8 + q * 2;
  out[i] = (u32)f2bf(W[o * K + k]) | ((u32)f2bf(W[o * K + k + 1]) << 16);
}

__global__ void setupA(const float* __restrict__ relw, const float* __restrict__ Wih,
                       const float* __restrict__ embW, const float* __restrict__ Whh,
                       float* __restrict__ Wrow, u32* __restrict__ PWem, u32* __restrict__ PWhh) {
  int b = blockIdx.x;
  if (b < 144) {
    int t = b * 256 + threadIdx.x;
    if (t >= 192 * 192) return;
    int kg = t / 192, j = t % 192;
    const float* a = relw + (j >> 6) * 4096 + (j & 63) * 64;
    const float* w = Wih + kg * 64;
    float s = 0.f;
#pragma unroll
    for (int k = 0; k < 64; ++k) s += a[k] * w[k];
    Wrow[kg * 192 + j] = s;
  } else if (b < 152) {
    pack_one(embW, PWem, 64, 4, (b - 144) * 256 + threadIdx.x);
  } else {
    pack_one(Whh, PWhh, 64, 12, (b - 152) * 256 + threadIdx.x);
  }
}

__global__ void pack_wf(const float* __restrict__ Wrow, u32* __restrict__ PWf) {
  pack_one(Wrow, PWf, 192, 12, blockIdx.x * 256 + threadIdx.x);  // 72 blocks
}

// pack head weights folded with ker-BN scale
__global__ void fold_pack(const float* __restrict__ Wa, const float* __restrict__ Wb,
                          const float* __restrict__ sc, u32* __restrict__ Pa,
                          u32* __restrict__ Pb) {
  int iu = blockIdx.x * 256 + threadIdx.x;  // 4096
  int hsel = iu >> 11;
  int i = iu & 2047;
  const float* W = hsel ? Wb : Wa;
  u32* P = hsel ? Pb : Pa;
  int q = i & 3, lane = (i >> 2) & 63, f = i >> 8;
  int ks = f >> 2, ot = f & 3;
  int o = ot * 16 + (lane & 15);
  int k = ks * 32 + (lane >> 4) * 8 + q * 2;
  P[i] = (u32)f2bf(W[o * 64 + k] * sc[k]) | ((u32)f2bf(W[o * 64 + k + 1] * sc[k + 1]) << 16);
}

// ---------------- CSR build ----------------
__global__ __launch_bounds__(256) void edge_count(const int* __restrict__ dst,
                                                  int* __restrict__ cnt,
                                                  int* __restrict__ epos) {
  int e = blockIdx.x * 256 + threadIdx.x;
  if (e >= NE) return;
  epos[e] = atomicAdd(&cnt[dst[e]], 1);
}

__global__ __launch_bounds__(256) void scanA(const int* __restrict__ cnt,
                                             int* __restrict__ lps, int* __restrict__ bsum) {
  int t = threadIdx.x;
  int i = blockIdx.x * 256 + t;
  int v = (i < NN) ? cnt[i] : 0;
  __shared__ int sh[256];
  sh[t] = v;
  __syncthreads();
#pragma unroll
  for (int off = 1; off < 256; off <<= 1) {
    int u = (t >= off) ? sh[t - off] : 0;
    __syncthreads();
    sh[t] += u;
    __syncthreads();
  }
  lps[i] = sh[t] - v;  // exclusive
  if (t == 255) bsum[blockIdx.x] = sh[255];
}

__global__ __launch_bounds__(512) void scanB(int* __restrict__ bsum) {  // 391 entries
  int t = threadIdx.x;
  int v = (t < 391) ? bsum[t] : 0;
  __shared__ int sh[512];
  sh[t] = v;
  __syncthreads();
#pragma unroll
  for (int off = 1; off < 512; off <<= 1) {
    int u = (t >= off) ? sh[t - off] : 0;
    __syncthreads();
    sh[t] += u;
    __syncthreads();
  }
  if (t < 391) bsum[t] = sh[t] - v;  // exclusive block offsets
}

__global__ __launch_bounds__(256) void scanC(const int* __restrict__ lps,
                                             const int* __restrict__ bsum,
                                             int* __restrict__ rowptr) {
  int i = blockIdx.x * 256 + threadIdx.x;
  if (i > NN) return;
  rowptr[i] = lps[i] + bsum[i >> 8];
}

__global__ __launch_bounds__(256) void edge_place(const int* __restrict__ src,
                                                  const int* __restrict__ dst,
                                                  const int* __restrict__ rt,
                                                  const float* __restrict__ nrm,
                                                  const int* __restrict__ epos,
                                                  const int* __restrict__ rowptr,
                                                  u64* __restrict__ csr) {
  int e = blockIdx.x * 256 + threadIdx.x;
  if (e >= NE) return;
  int pos = rowptr[dst[e]] + epos[e];
  u32 srp = (u32)src[e] | ((u32)rt[e] << 20);
  csr[pos] = (u64)srp | ((u64)__float_as_uint(nrm[e]) << 32);
}

// ---------------- CSR gather: one wave per node, scalar edge walk -------------
__global__ __launch_bounds__(256) void csr_gather(const int* __restrict__ rowptr,
                                                  const u64* __restrict__ csr,
                                                  const u16* __restrict__ Xbf,
                                                  u16* __restrict__ ACCbf) {
  int wv = blockIdx.x * 4 + (threadIdx.x >> 6);
  int lane = threadIdx.x & 63;
  if (wv >= NN) return;
  int base = rowptr[wv], end = rowptr[wv + 1];
  float a0 = 0.f, a1 = 0.f, a2 = 0.f;
#define GSTEP(JJ)                                                               \
  { u32 srp = (u32)__builtin_amdgcn_readlane((int)lo, (JJ));                    \
    float nm = __uint_as_float((u32)__builtin_amdgcn_readlane((int)hi, (JJ)));  \
    int r = (int)(srp >> 20);                                                   \
    float xv = bf2f(Xbf[(size_t)(srp & 0xFFFFFu) * 64 + lane]);                 \
    float n0 = (r == 0) ? nm : 0.f;                                             \
    float n1 = (r == 1) ? nm : 0.f;                                             \
    float n2 = (r == 2) ? nm : 0.f;                                             \
    a0 = fmaf(xv, n0, a0); a1 = fmaf(xv, n1, a1); a2 = fmaf(xv, n2, a2); }
  for (int c = base; c < end; c += 64) {
    int m = end - c; m = m > 64 ? 64 : m;
    u32 lo = 0, hi = 0;
    if (lane < m) {
      u64 r = csr[(size_t)c + lane];
      lo = (u32)r; hi = (u32)(r >> 32);
    }
    int j = 0;
    for (; j + 8 <= m; j += 8) {
      GSTEP(j) GSTEP(j + 1) GSTEP(j + 2) GSTEP(j + 3)
      GSTEP(j + 4) GSTEP(j + 5) GSTEP(j + 6) GSTEP(j + 7)
    }
    for (; j < m; ++j) { GSTEP(j) }
  }
#undef GSTEP
  long o = (long)wv * 192 + lane;
  ACCbf[o] = f2bf(a0);
  ACCbf[o + 64] = f2bf(a1);
  ACCbf[o + 128] = f2bf(a2);
}

// ---------------------------------------------------------------------------
// MFMA GEMM with LDS-staged (double-buffered) B panel + A-register prefetch.
//   AF32: A is f32 (row-clamped); GRU: 0 store, 1 h'=(1-z)n, 2 full
//   CS: fused column sum/sumsq atomics (KO==64 only)
// ---------------------------------------------------------------------------
template<int K, int KO, int AF32, int GRU, int CS, int OUTBF>
__global__ __launch_bounds__(256) void gemm_mfma(
    const void* __restrict__ Av, const u32* __restrict__ Wpk, void* __restrict__ Yv,
    const float* __restrict__ bih, const float* __restrict__ bhh,
    const u16* __restrict__ G2B, const u16* __restrict__ Hv,
    float* __restrict__ csum, int n) {
  constexpr int KOT = KO / 16, KS = K / 32;
  __shared__ u32 bsh[2][KOT * 256];
  __shared__ float cs[128];
  const int lane = threadIdx.x & 63, w = threadIdx.x >> 6;
  const int rr = lane & 15, kg = lane >> 4;
  const long mbase = (long)blockIdx.x * 128 + w * 32;
  const u16* Abf = (const u16*)Av;
  const float* Af = (const float*)Av;

  // async global->LDS stage of B chunk ks into buffer `buf`
  auto stage = [&](int ks, int buf) {
    constexpr int PASSES = KOT / 4;
#pragma unroll
    for (int i = 0; i < PASSES; ++i) {
      int c = i * 4 + w;  // chunk 0..KOT-1, one wave each
      const u32* srcp = Wpk + ((long)(ks * KOT + c) * 64 + lane) * 4;
      u32* dstp = &bsh[buf][c * 256];
      __builtin_amdgcn_global_load_lds(GLBP(srcp), LDSP(dstp), 16, 0, 0);
    }
  };

  // A fragment load (+ f32->bf16 convert for AF32)
  auto loadAbf = [&](int ks, int half) -> bf16x8 {
    if (AF32) {
      long r = mbase + half * 16 + rr;
      if (r > n - 1) r = n - 1;
      const float* pp = Af + r * K + ks * 32 + kg * 8;
      float4 u0 = *(const float4*)pp;
      float4 u1 = *(const float4*)(pp + 4);
      bf16x8 o_;
      o_[0] = __builtin_bit_cast(__bf16, f2bf(u0.x));
      o_[1] = __builtin_bit_cast(__bf16, f2bf(u0.y));
      o_[2] = __builtin_bit_cast(__bf16, f2bf(u0.z));
      o_[3] = __builtin_bit_cast(__bf16, f2bf(u0.w));
      o_[4] = __builtin_bit_cast(__bf16, f2bf(u1.x));
      o_[5] = __builtin_bit_cast(__bf16, f2bf(u1.y));
      o_[6] = __builtin_bit_cast(__bf16, f2bf(u1.z));
      o_[7] = __builtin_bit_cast(__bf16, f2bf(u1.w));
      return o_;
    }
    return *reinterpret_cast<const bf16x8*>(Abf + (mbase + half * 16 + rr) * K + ks * 32 + kg * 8);
  };

  f32x4 acc[2][KOT] = {};
  stage(0, 0);
  bf16x8 a0 = loadAbf(0, 0);
  bf16x8 a1 = loadAbf(0, 1);
  __syncthreads();  // drains stage(0) (implicit vmcnt(0))

  int buf = 0;
  for (int ks = 0; ks < KS; ++ks) {
    bf16x8 n0 = a0, n1 = a1;
    if (ks + 1 < KS) {
      stage(ks + 1, buf ^ 1);     // async; drained by end-of-iter barrier
      n0 = loadAbf(ks + 1, 0);    // reg prefetch, overlaps MFMA below
      n1 = loadAbf(ks + 1, 1);
    }
#pragma unroll
    for (int o = 0; o < KOT; ++o) {
      bf16x8 bfr = *reinterpret_cast<const bf16x8*>(&bsh[buf][(o * 64 + lane) * 4]);
      acc[0][o] = __builtin_amdgcn_mfma_f32_16x16x32_bf16(a0, bfr, acc[0][o], 0, 0, 0);
      acc[1][o] = __builtin_amdgcn_mfma_f32_16x16x32_bf16(a1, bfr, acc[1][o], 0, 0, 0);
    }
    __syncthreads();
    a0 = n0; a1 = n1;
    buf ^= 1;
  }

  if (GRU == 0) {
    float s[4] = {0.f, 0.f, 0.f, 0.f}, ss[4] = {0.f, 0.f, 0.f, 0.f};
#pragma unroll
    for (int tl = 0; tl < 2; ++tl)
#pragma unroll
      for (int o = 0; o < KOT; ++o)
#pragma unroll
        for (int q = 0; q < 4; ++q) {
          long row = mbase + tl * 16 + kg * 4 + q;
          float vv = acc[tl][o][q];
          if (row < n) {
            long off = row * KO + o * 16 + rr;
            if (OUTBF) ((u16*)Yv)[off] = f2bf(vv);
            else       ((float*)Yv)[off] = vv;
            if (CS) { s[o & 3] += vv; ss[o & 3] += vv * vv; }
          }
        }
    if (CS) {
      for (int i = threadIdx.x; i < 128; i += 256) cs[i] = 0.f;
      __syncthreads();
#pragma unroll
      for (int o = 0; o < 4 && o < KOT; ++o) {
        int c = o * 16 + rr;
        atomicAdd(&cs[c], s[o]);
        atomicAdd(&cs[64 + c], ss[o]);
      }
      __syncthreads();
      if (threadIdx.x < 128) atomicAdd(&csum[threadIdx.x], cs[threadIdx.x]);
    }
  } else {
    float bi[12], bh_[12];
#pragma unroll
    for (int g = 0; g < 3; ++g)
#pragma unroll
      for (int o = 0; o < 4; ++o) {
        bi[g * 4 + o] = bih[g * 64 + o * 16 + rr];
        bh_[g * 4 + o] = bhh[g * 64 + o * 16 + rr];
      }
#pragma unroll
    for (int tl = 0; tl < 2; ++tl)
#pragma unroll
      for (int o = 0; o < 4; ++o) {
        int c = o * 16 + rr;
#pragma unroll
        for (int q = 0; q < 4; ++q) {
          long row = mbase + tl * 16 + kg * 4 + q;
          float ir = acc[tl][o][q] + bi[o];
          float iz = acc[tl][o + 4][q] + bi[4 + o];
          float in_ = acc[tl][o + 8][q] + bi[8 + o];
          float hr = bh_[o], hz = bh_[4 + o], hn = bh_[8 + o], hv = 0.f;
          if (GRU == 2) {
            const u16* g2 = G2B + row * 192;
            hr += bf2f(g2[c]); hz += bf2f(g2[64 + c]); hn += bf2f(g2[128 + c]);
            hv = bf2f(Hv[row * 64 + c]);
          }
          float rg = 1.f / (1.f + __expf(-(ir + hr)));
          float zg = 1.f / (1.f + __expf(-(iz + hz)));
          float ng = tanhf(in_ + rg * hn);
          float h = (1.f - zg) * ng + (GRU == 2 ? zg * hv : 0.f);
          if (row < n) ((u16*)Yv)[row * 64 + c] = f2bf(h);
        }
      }
  }
}

// ---------------- BN helpers ----------------
__global__ void bn_finalize(const float* __restrict__ acc, const float* __restrict__ gamma,
                            const float* __restrict__ beta, float* __restrict__ scsh,
                            float inv_n) {
  int t = threadIdx.x;  // 64
  float mean = acc[t] * inv_n;
  float var = acc[64 + t] * inv_n - mean * mean;
  float sc = gamma[t] * rsqrtf(var + EPSV);
  scsh[t] = sc;
  scsh[64 + t] = beta[t] - mean * sc;
}

__global__ __launch_bounds__(256) void bn_apply_bf(const float* __restrict__ X,
                                                   u16* __restrict__ Y,
                                                   const float* __restrict__ scsh, int relu) {
  long i = (long)blockIdx.x * 256 + threadIdx.x;  // NN*16 float4s
  float4 v = reinterpret_cast<const float4*>(X)[i];
  int c = (int)((i * 4) & 63);
  v.x = fmaf(v.x, scsh[c],     scsh[64 + c]);
  v.y = fmaf(v.y, scsh[c + 1], scsh[65 + c]);
  v.z = fmaf(v.z, scsh[c + 2], scsh[66 + c]);
  v.w = fmaf(v.w, scsh[c + 3], scsh[67 + c]);
  if (relu) {
    v.x = fmaxf(v.x, 0.f); v.y = fmaxf(v.y, 0.f);
    v.z = fmaxf(v.z, 0.f); v.w = fmaxf(v.w, 0.f);
  }
  reinterpret_cast<ushort4*>(Y)[i] = make_ushort4(f2bf(v.x), f2bf(v.y), f2bf(v.z), f2bf(v.w));
}

__global__ __launch_bounds__(256) void colsum_bf(const u16* __restrict__ X,
                                                 float* __restrict__ acc, int n) {
  const int t = threadIdx.x, c = t & 63, w = t >> 6;
  float s = 0.f, ss = 0.f;
  for (int r = blockIdx.x * 4 + w; r < n; r += gridDim.x * 4) {
    float v = bf2f(X[(long)r * 64 + c]);
    s += v; ss += v * v;
  }
  __shared__ float sh[8][64];
  sh[w][c] = s; sh[4 + w][c] = ss;
  __syncthreads();
  if (t < 64) {
    float a = sh[0][t] + sh[1][t] + sh[2][t] + sh[3][t];
    float b = sh[4][t] + sh[5][t] + sh[6][t] + sh[7][t];
    atomicAdd(&acc[t], a);
    atomicAdd(&acc[64 + t], b);
  }
}

// ---------------- final head: BN+ReLU from f32 pre-acts, tiny GEMM -----------
template<int KO>
__global__ __launch_bounds__(256) void headfin_bn(const float* __restrict__ Z,
                                                  const float* __restrict__ scsh,
                                                  const float* __restrict__ W2,
                                                  const float* __restrict__ b2,
                                                  float* __restrict__ out, int n) {
  __shared__ float ws[KO * 64];
  for (int i = threadIdx.x; i < KO * 64; i += 256) ws[i] = W2[i];
  __syncthreads();
  long node = (long)blockIdx.x * 256 + threadIdx.x;
  if (node >= n) return;
  float x[64];
#pragma unroll
  for (int i = 0; i < 16; ++i) {
    float4 z4 = reinterpret_cast<const float4*>(Z + node * 64)[i];
    int c = i * 4;
    x[c]     = fmaxf(fmaf(z4.x, scsh[c],     scsh[64 + c]), 0.f);
    x[c + 1] = fmaxf(fmaf(z4.y, scsh[c + 1], scsh[65 + c]), 0.f);
    x[c + 2] = fmaxf(fmaf(z4.z, scsh[c + 2], scsh[66 + c]), 0.f);
    x[c + 3] = fmaxf(fmaf(z4.w, scsh[c + 3], scsh[67 + c]), 0.f);
  }
#pragma unroll
  for (int o = 0; o < KO; ++o) {
    float a = b2[o];
#pragma unroll
    for (int d = 0; d < 64; ++d) a = fmaf(x[d], ws[o * 64 + d], a);
    out[node * KO + o] = a;
  }
}

extern "C" void kernel_launch(void* const* d_in, const int* in_sizes, int n_in,
                              void* d_out, int out_size, void* d_ws, size_t ws_size,
                              hipStream_t stream) {
  const float* v     = (const float*)d_in[0];
  const int*   src   = (const int*)d_in[1];
  const int*   dst   = (const int*)d_in[2];
  const int*   rt    = (const int*)d_in[3];
  const float* norm  = (const float*)d_in[4];
  const float* emb_W = (const float*)d_in[5];
  const float* emb_g  = (const float*)d_in[7];
  const float* emb_be = (const float*)d_in[8];
  const float* rel_w  = (const float*)d_in[9];
  const float* Wih    = (const float*)d_in[10];
  const float* Whh    = (const float*)d_in[11];
  const float* bih    = (const float*)d_in[12];
  const float* bhh    = (const float*)d_in[13];
  const float* ker_g  = (const float*)d_in[14];
  const float* ker_be = (const float*)d_in[15];
  const float* aW1    = (const float*)d_in[16];
  const float* a_g  = (const float*)d_in[18];
  const float* a_be = (const float*)d_in[19];
  const float* aW2  = (const float*)d_in[20];
  const float* ab2  = (const float*)d_in[21];
  const float* bW1  = (const float*)d_in[22];
  const float* b_g  = (const float*)d_in[24];
  const float* b_be = (const float*)d_in[25];
  const float* bW2  = (const float*)d_in[26];
  const float* bb2  = (const float*)d_in[27];
  float* out = (float*)d_out;

  // ---- workspace carve-up ----
  char* p = (char*)d_ws;
  auto nxt = [&](size_t bytes) -> char* {
    char* r = p; p += (bytes + 255) & ~(size_t)255; return r;
  };
  int*   CNT  = (int*)nxt((size_t)NP * 4);          // counts (memset w/ ACCs)
  float* ACCs = (float*)nxt(512 * 4);               // BN stat accumulators
  float* Z    = (float*)nxt((size_t)NP * 64 * 4);   // f32 pre-BN scratch
  u16*   X1   = (u16*)nxt((size_t)NP * 64 * 2);     // h (bf16)
  u16*   X2   = (u16*)nxt((size_t)NP * 64 * 2);     // h0 (bf16)
  u16*   ACCB = (u16*)nxt((size_t)NP * 192 * 2);    // gathered rel-sums
  u16*   G2B  = (u16*)nxt((size_t)NP * 192 * 2);    // h @ Whh^T
  u64*   CSR  = (u64*)nxt((size_t)NE * 8);          // edge records (dst-sorted)
  int*   EPOS = (int*)nxt((size_t)NE * 4);          // within-row rank
  int*   LPS  = (int*)nxt((size_t)NP * 4);
  int*   BSUM = (int*)nxt(512 * 4);
  int*   ROWP = (int*)nxt((size_t)(NN + 256) * 4);
  u32*   PWf  = (u32*)nxt(18432 * 4);
  u32*   PWem = (u32*)nxt(2048 * 4);
  u32*   PWhh = (u32*)nxt(6144 * 4);
  u32*   PWa  = (u32*)nxt(2048 * 4);
  u32*   PWb  = (u32*)nxt(2048 * 4);
  float* WROW = (float*)nxt(147456);
  float* SC   = (float*)nxt(512 * 4);

  hipMemsetAsync(CNT, 0, (size_t)(NP + 512) * 4, stream);  // CNT + ACCs contiguous

  // setup + CSR build
  setupA<<<176, 256, 0, stream>>>(rel_w, Wih, emb_W, Whh, WROW, PWem, PWhh);
  edge_count<<<6250, 256, 0, stream>>>(dst, CNT, EPOS);
  scanA<<<391, 256, 0, stream>>>(CNT, LPS, BSUM);
  scanB<<<1, 512, 0, stream>>>(BSUM);
  scanC<<<392, 256, 0, stream>>>(LPS, BSUM, ROWP);
  edge_place<<<6250, 256, 0, stream>>>(src, dst, rt, norm, EPOS, ROWP, CSR);
  pack_wf<<<72, 256, 0, stream>>>(WROW, PWf);

  // embedding: Z = v @ emb_W^T (fused colsum); X2 = bf16(relu(BN(Z)))
  gemm_mfma<64, 64, 1, 0, 1, 0><<<782, 256, 0, stream>>>(v, PWem, Z, nullptr, nullptr,
                                                         nullptr, nullptr, ACCs + 0, NN);
  bn_finalize<<<1, 64, 0, stream>>>(ACCs + 0, emb_g, emb_be, SC + 0, 1.f / NN);
  bn_apply_bf<<<6250, 256, 0, stream>>>(Z, X2, SC + 0, 1);

  // layer 1 (h==0): gather -> fused GEMM+GRU -> X1 = h1
  csr_gather<<<25000, 256, 0, stream>>>(ROWP, CSR, X2, ACCB);
  gemm_mfma<192, 192, 0, 1, 0, 1><<<782, 256, 0, stream>>>(ACCB, PWf, X1, bih, bhh,
                                                           nullptr, nullptr, nullptr, NN);

  // layer 2: gather(h1) -> G2 = h1 @ Whh^T -> fused GEMM+GRU -> X1 = h2
  csr_gather<<<25000, 256, 0, stream>>>(ROWP, CSR, X1, ACCB);
  gemm_mfma<64, 192, 0, 0, 0, 1><<<782, 256, 0, stream>>>(X1, PWhh, G2B, nullptr, nullptr,
                                                          nullptr, nullptr, nullptr, NN);
  gemm_mfma<192, 192, 0, 2, 0, 1><<<782, 256, 0, stream>>>(ACCB, PWf, X1, bih, bhh,
                                                           G2B, X1, nullptr, NN);

  // ker BN stats on h2; fold scale into head weights (shift cancels in head BN)
  colsum_bf<<<416, 256, 0, stream>>>(X1, ACCs + 128, NN);
  bn_finalize<<<1, 64, 0, stream>>>(ACCs + 128, ker_g, ker_be, SC + 128, 1.f / NN);
  fold_pack<<<16, 256, 0, stream>>>(aW1, bW1, SC + 128, PWa, PWb);

  // head A
  gemm_mfma<64, 64, 0, 0, 1, 0><<<782, 256, 0, stream>>>(X1, PWa, Z, nullptr, nullptr,
                                                         nullptr, nullptr, ACCs + 256, NN);
  bn_finalize<<<1, 64, 0, stream>>>(ACCs + 256, a_g, a_be, SC + 256, 1.f / NN);
  headfin_bn<2><<<391, 256, 0, stream>>>(Z, SC + 256, aW2, ab2, out, NN);

  // head B
  gemm_mfma<64, 64, 0, 0, 1, 0><<<782, 256, 0, stream>>>(X1, PWb, Z, nullptr, nullptr,
                                                         nullptr, nullptr, ACCs + 384, NN);
  bn_finalize<<<1, 64, 0, stream>>>(ACCs + 384, b_g, b_be, SC + 384, 1.f / NN);
  headfin_bn<21><<<391, 256, 0, stream>>>(Z, SC + 384, bW2, bb2, out + (long)NN * 2, NN);
}

// Round 6
// 427.247 us; speedup vs baseline: 5.9260x; 1.1003x over previous
//
#include <hip/hip_runtime.h>

#define NN 100000
#define NE 1600000
#define NP 100096   // 782 * 128 rows, GEMM tile padding
#define NBKT 391    // ceil(NN/256) coarse buckets
#define CAP 6144    // padded region capacity per bucket (mean 4096, +32 sigma)
#define EPSV 1e-5f

typedef unsigned int u32;
typedef unsigned short u16;
typedef unsigned long long u64;
typedef __bf16 bf16x8 __attribute__((ext_vector_type(8)));
typedef float f32x4 __attribute__((ext_vector_type(4)));

#define GLBP(x) ((const __attribute__((address_space(1))) u32*)(x))
#define LDSP(x) ((__attribute__((address_space(3))) u32*)(x))

__device__ __forceinline__ u16 f2bf(float f) {
  u32 x = __float_as_uint(f);
  return (u16)((x + 0x7FFFu + ((x >> 16) & 1u)) >> 16);  // RNE
}
__device__ __forceinline__ float bf2f(u16 h) { return __uint_as_float(((u32)h) << 16); }

// ---------------- setup A: wfuse (blocks 0..143) | pack emb (144..151) | pack Whh (152..175)
__device__ __forceinline__ void pack_one(const float* W, u32* out, int K, int KOT, int i) {
  int q = i & 3, lane = (i >> 2) & 63, f = i >> 8;
  int ks = f / KOT, ot = f - ks * KOT;
  int o = ot * 16 + (lane & 15);
  int k = ks * 32 + (lane >> 4) * 8 + q * 2;
  out[i] = (u32)f2bf(W[o * K + k]) | ((u32)f2bf(W[o * K + k + 1]) << 16);
}

__global__ void setupA(const float* __restrict__ relw, const float* __restrict__ Wih,
                       const float* __restrict__ embW, const float* __restrict__ Whh,
                       float* __restrict__ Wrow, u32* __restrict__ PWem, u32* __restrict__ PWhh) {
  int b = blockIdx.x;
  if (b < 144) {
    int t = b * 256 + threadIdx.x;
    if (t >= 192 * 192) return;
    int kg = t / 192, j = t % 192;
    const float* a = relw + (j >> 6) * 4096 + (j & 63) * 64;
    const float* w = Wih + kg * 64;
    float s = 0.f;
#pragma unroll
    for (int k = 0; k < 64; ++k) s += a[k] * w[k];
    Wrow[kg * 192 + j] = s;
  } else if (b < 152) {
    pack_one(embW, PWem, 64, 4, (b - 144) * 256 + threadIdx.x);
  } else {
    pack_one(Whh, PWhh, 64, 12, (b - 152) * 256 + threadIdx.x);
  }
}

__global__ void pack_wf(const float* __restrict__ Wrow, u32* __restrict__ PWf) {
  pack_one(Wrow, PWf, 192, 12, blockIdx.x * 256 + threadIdx.x);  // 72 blocks
}

// pack head weights folded with ker-BN scale
__global__ void fold_pack(const float* __restrict__ Wa, const float* __restrict__ Wb,
                          const float* __restrict__ sc, u32* __restrict__ Pa,
                          u32* __restrict__ Pb) {
  int iu = blockIdx.x * 256 + threadIdx.x;  // 4096
  int hsel = iu >> 11;
  int i = iu & 2047;
  const float* W = hsel ? Wb : Wa;
  u32* P = hsel ? Pb : Pa;
  int q = i & 3, lane = (i >> 2) & 63, f = i >> 8;
  int ks = f >> 2, ot = f & 3;
  int o = ot * 16 + (lane & 15);
  int k = ks * 32 + (lane >> 4) * 8 + q * 2;
  P[i] = (u32)f2bf(W[o * 64 + k] * sc[k]) | ((u32)f2bf(W[o * 64 + k + 1] * sc[k + 1]) << 16);
}

// ---------------------------------------------------------------------------
// Hierarchical CSR build.
// record: low u32 = src(0..16) | rel(20..21) | dst&255(22..29); high u32 = norm bits
// ---------------------------------------------------------------------------
__global__ __launch_bounds__(256) void countplace(const int* __restrict__ src,
                                                  const int* __restrict__ dst,
                                                  const int* __restrict__ rt,
                                                  const float* __restrict__ nrm,
                                                  int* __restrict__ gcnt,
                                                  u64* __restrict__ region) {
  __shared__ u32 hist[NBKT], gbase[NBKT];
  const int t = threadIdx.x;
  for (int i = t; i < NBKT; i += 256) hist[i] = 0;
  __syncthreads();
  const int e0 = blockIdx.x * 2048 + t;
  u32 rlo[8], rhi[8], lrank[8];
  int bkt[8];
#pragma unroll
  for (int i = 0; i < 8; ++i) {
    int e = e0 + i * 256;
    bkt[i] = -1;
    if (e < NE) {
      int d = dst[e];
      int b = d >> 8;
      bkt[i] = b;
      lrank[i] = atomicAdd(&hist[b], 1u);
      rlo[i] = (u32)src[e] | ((u32)rt[e] << 20) | ((u32)(d & 255) << 22);
      rhi[i] = __float_as_uint(nrm[e]);
    }
  }
  __syncthreads();
  for (int i = t; i < NBKT; i += 256) {
    u32 h = hist[i];
    gbase[i] = h ? (u32)atomicAdd(&gcnt[i], (int)h) : 0u;
  }
  __syncthreads();
#pragma unroll
  for (int i = 0; i < 8; ++i) {
    if (bkt[i] >= 0) {
      u32 pos = gbase[bkt[i]] + lrank[i];
      if (pos < CAP)
        region[(size_t)bkt[i] * CAP + pos] = (u64)rlo[i] | ((u64)rhi[i] << 32);
    }
  }
}

__global__ __launch_bounds__(512) void bucketscan(const int* __restrict__ gcnt,
                                                  int* __restrict__ bbase,
                                                  int* __restrict__ rowp) {
  int t = threadIdx.x;
  int v = (t < NBKT) ? gcnt[t] : 0;
  __shared__ int sh[512];
  sh[t] = v;
  __syncthreads();
#pragma unroll
  for (int off = 1; off < 512; off <<= 1) {
    int u = (t >= off) ? sh[t - off] : 0;
    __syncthreads();
    sh[t] += u;
    __syncthreads();
  }
  if (t < NBKT) bbase[t] = sh[t] - v;  // exclusive
  if (t == 0) rowp[NN] = NE;
}

__global__ __launch_bounds__(256) void localsort(const int* __restrict__ gcnt,
                                                 const int* __restrict__ bbase,
                                                 const u64* __restrict__ region,
                                                 u64* __restrict__ csr,
                                                 int* __restrict__ rowp) {
  const int b = blockIdx.x, t = threadIdx.x;
  int n = gcnt[b];
  if (n > CAP) n = CAP;
  const int base = bbase[b];
  __shared__ u32 hist[256], sc[256];
  hist[t] = 0;
  __syncthreads();
  for (int i = t; i < n; i += 256)
    atomicAdd(&hist[((u32)region[(size_t)b * CAP + i] >> 22) & 255], 1u);
  __syncthreads();
  u32 v = hist[t];
  sc[t] = v;
  __syncthreads();
#pragma unroll
  for (int off = 1; off < 256; off <<= 1) {
    u32 u = (t >= off) ? sc[t - off] : 0;
    __syncthreads();
    sc[t] += u;
    __syncthreads();
  }
  u32 excl = sc[t] - v;
  int node = b * 256 + t;
  if (node < NN) rowp[node] = base + (int)excl;
  __syncthreads();
  hist[t] = excl;  // reuse as cursor
  __syncthreads();
  for (int i = t; i < n; i += 256) {
    u64 rec = region[(size_t)b * CAP + i];
    u32 pos = atomicAdd(&hist[((u32)rec >> 22) & 255], 1u);
    csr[(size_t)base + pos] = rec;
  }
}

// ---------------- CSR gather: one wave per node, 2 edges per step -------------
__global__ __launch_bounds__(256) void csr_gather(const int* __restrict__ rowp,
                                                  const u64* __restrict__ csr,
                                                  const u16* __restrict__ Xbf,
                                                  u16* __restrict__ ACCbf) {
  int wv = blockIdx.x * 4 + (threadIdx.x >> 6);
  int lane = threadIdx.x & 63;
  if (wv >= NN) return;
  const int half = lane >> 5, c2 = lane & 31;
  int base = rowp[wv], end = rowp[wv + 1];
  float a0x = 0.f, a0y = 0.f, a1x = 0.f, a1y = 0.f, a2x = 0.f, a2y = 0.f;
#define GP(JJ)                                                                   \
  { u32 sA = (u32)__builtin_amdgcn_readlane((int)lo, (JJ));                      \
    u32 sB = (u32)__builtin_amdgcn_readlane((int)lo, (JJ) + 1);                  \
    u32 nA = (u32)__builtin_amdgcn_readlane((int)hi, (JJ));                      \
    u32 nB = (u32)__builtin_amdgcn_readlane((int)hi, (JJ) + 1);                  \
    u32 srp = half ? sB : sA;                                                    \
    float nm = __uint_as_float(half ? nB : nA);                                  \
    u32 xw = *(const u32*)(Xbf + (size_t)(srp & 0xFFFFFu) * 64 + 2 * c2);        \
    float x0 = bf2f((u16)xw), x1 = bf2f((u16)(xw >> 16));                        \
    int r = (int)((srp >> 20) & 3);                                              \
    float n0 = (r == 0) ? nm : 0.f;                                              \
    float n1 = (r == 1) ? nm : 0.f;                                              \
    float n2 = (r == 2) ? nm : 0.f;                                              \
    a0x = fmaf(x0, n0, a0x); a0y = fmaf(x1, n0, a0y);                            \
    a1x = fmaf(x0, n1, a1x); a1y = fmaf(x1, n1, a1y);                            \
    a2x = fmaf(x0, n2, a2x); a2y = fmaf(x1, n2, a2y); }
  for (int c = base; c < end; c += 64) {
    int m = end - c; m = m > 64 ? 64 : m;
    u32 lo = 0, hi = 0;
    if (lane < m) {
      u64 r = csr[(size_t)c + lane];
      lo = (u32)r; hi = (u32)(r >> 32);
    }
    int j = 0;
    for (; j + 16 <= m; j += 16) {
      GP(j) GP(j + 2) GP(j + 4) GP(j + 6)
      GP(j + 8) GP(j + 10) GP(j + 12) GP(j + 14)
    }
    for (; j < m; j += 2) { GP(j) }
  }
#undef GP
  a0x += __shfl_xor(a0x, 32); a0y += __shfl_xor(a0y, 32);
  a1x += __shfl_xor(a1x, 32); a1y += __shfl_xor(a1y, 32);
  a2x += __shfl_xor(a2x, 32); a2y += __shfl_xor(a2y, 32);
  if (half == 0) {
    u32* orow = (u32*)(ACCbf + (size_t)wv * 192);
    orow[c2]      = (u32)f2bf(a0x) | ((u32)f2bf(a0y) << 16);
    orow[32 + c2] = (u32)f2bf(a1x) | ((u32)f2bf(a1y) << 16);
    orow[64 + c2] = (u32)f2bf(a2x) | ((u32)f2bf(a2y) << 16);
  }
}

// ---------------------------------------------------------------------------
// MFMA GEMM with LDS-staged (double-buffered) B panel + A-register prefetch.
//   AF32: A is f32 (row-clamped); GRU: 0 store, 1 h'=(1-z)n, 2 full
//   CS: fused column sum/sumsq atomics (KO==64 output paths)
// ---------------------------------------------------------------------------
template<int K, int KO, int AF32, int GRU, int CS, int OUTBF>
__global__ __launch_bounds__(256) void gemm_mfma(
    const void* __restrict__ Av, const u32* __restrict__ Wpk, void* __restrict__ Yv,
    const float* __restrict__ bih, const float* __restrict__ bhh,
    const u16* __restrict__ G2B, const u16* __restrict__ Hv,
    float* __restrict__ csum, int n) {
  constexpr int KOT = KO / 16, KS = K / 32;
  __shared__ u32 bsh[2][KOT * 256];
  __shared__ float cs[128];
  const int lane = threadIdx.x & 63, w = threadIdx.x >> 6;
  const int rr = lane & 15, kg = lane >> 4;
  const long mbase = (long)blockIdx.x * 128 + w * 32;
  const u16* Abf = (const u16*)Av;
  const float* Af = (const float*)Av;

  auto stage = [&](int ks, int buf) {
    constexpr int PASSES = KOT / 4;
#pragma unroll
    for (int i = 0; i < PASSES; ++i) {
      int c = i * 4 + w;
      const u32* srcp = Wpk + ((long)(ks * KOT + c) * 64 + lane) * 4;
      u32* dstp = &bsh[buf][c * 256];
      __builtin_amdgcn_global_load_lds(GLBP(srcp), LDSP(dstp), 16, 0, 0);
    }
  };

  auto loadAbf = [&](int ks, int halfsel) -> bf16x8 {
    if (AF32) {
      long r = mbase + halfsel * 16 + rr;
      if (r > n - 1) r = n - 1;
      const float* pp = Af + r * K + ks * 32 + kg * 8;
      float4 u0 = *(const float4*)pp;
      float4 u1 = *(const float4*)(pp + 4);
      bf16x8 o_;
      o_[0] = __builtin_bit_cast(__bf16, f2bf(u0.x));
      o_[1] = __builtin_bit_cast(__bf16, f2bf(u0.y));
      o_[2] = __builtin_bit_cast(__bf16, f2bf(u0.z));
      o_[3] = __builtin_bit_cast(__bf16, f2bf(u0.w));
      o_[4] = __builtin_bit_cast(__bf16, f2bf(u1.x));
      o_[5] = __builtin_bit_cast(__bf16, f2bf(u1.y));
      o_[6] = __builtin_bit_cast(__bf16, f2bf(u1.z));
      o_[7] = __builtin_bit_cast(__bf16, f2bf(u1.w));
      return o_;
    }
    return *reinterpret_cast<const bf16x8*>(Abf + (mbase + halfsel * 16 + rr) * K + ks * 32 + kg * 8);
  };

  f32x4 acc[2][KOT] = {};
  stage(0, 0);
  bf16x8 a0 = loadAbf(0, 0);
  bf16x8 a1 = loadAbf(0, 1);
  __syncthreads();

  int buf = 0;
  for (int ks = 0; ks < KS; ++ks) {
    bf16x8 n0 = a0, n1 = a1;
    if (ks + 1 < KS) {
      stage(ks + 1, buf ^ 1);
      n0 = loadAbf(ks + 1, 0);
      n1 = loadAbf(ks + 1, 1);
    }
#pragma unroll
    for (int o = 0; o < KOT; ++o) {
      bf16x8 bfr = *reinterpret_cast<const bf16x8*>(&bsh[buf][(o * 64 + lane) * 4]);
      acc[0][o] = __builtin_amdgcn_mfma_f32_16x16x32_bf16(a0, bfr, acc[0][o], 0, 0, 0);
      acc[1][o] = __builtin_amdgcn_mfma_f32_16x16x32_bf16(a1, bfr, acc[1][o], 0, 0, 0);
    }
    __syncthreads();
    a0 = n0; a1 = n1;
    buf ^= 1;
  }

  float s[4] = {0.f, 0.f, 0.f, 0.f}, ss[4] = {0.f, 0.f, 0.f, 0.f};
  if (GRU == 0) {
#pragma unroll
    for (int tl = 0; tl < 2; ++tl)
#pragma unroll
      for (int o = 0; o < KOT; ++o)
#pragma unroll
        for (int q = 0; q < 4; ++q) {
          long row = mbase + tl * 16 + kg * 4 + q;
          float vv = acc[tl][o][q];
          if (row < n) {
            long off = row * KO + o * 16 + rr;
            if (OUTBF) ((u16*)Yv)[off] = f2bf(vv);
            else       ((float*)Yv)[off] = vv;
            if (CS) { s[o & 3] += vv; ss[o & 3] += vv * vv; }
          }
        }
  } else {
    float bi[12], bh_[12];
#pragma unroll
    for (int g = 0; g < 3; ++g)
#pragma unroll
      for (int o = 0; o < 4; ++o) {
        bi[g * 4 + o] = bih[g * 64 + o * 16 + rr];
        bh_[g * 4 + o] = bhh[g * 64 + o * 16 + rr];
      }
#pragma unroll
    for (int tl = 0; tl < 2; ++tl)
#pragma unroll
      for (int o = 0; o < 4; ++o) {
        int c = o * 16 + rr;
#pragma unroll
        for (int q = 0; q < 4; ++q) {
          long row = mbase + tl * 16 + kg * 4 + q;
          float ir = acc[tl][o][q] + bi[o];
          float iz = acc[tl][o + 4][q] + bi[4 + o];
          float in_ = acc[tl][o + 8][q] + bi[8 + o];
          float hr = bh_[o], hz = bh_[4 + o], hn = bh_[8 + o], hv = 0.f;
          if (GRU == 2) {
            const u16* g2 = G2B + row * 192;
            hr += bf2f(g2[c]); hz += bf2f(g2[64 + c]); hn += bf2f(g2[128 + c]);
            hv = bf2f(Hv[row * 64 + c]);
          }
          float rg = 1.f / (1.f + __expf(-(ir + hr)));
          float zg = 1.f / (1.f + __expf(-(iz + hz)));
          float ng = tanhf(in_ + rg * hn);
          float h = (1.f - zg) * ng + (GRU == 2 ? zg * hv : 0.f);
          if (row < n) {
            ((u16*)Yv)[row * 64 + c] = f2bf(h);
            if (CS) { s[o] += h; ss[o] += h * h; }
          }
        }
      }
  }
  if (CS) {
    for (int i = threadIdx.x; i < 128; i += 256) cs[i] = 0.f;
    __syncthreads();
#pragma unroll
    for (int o = 0; o < 4; ++o) {
      int c = o * 16 + rr;
      atomicAdd(&cs[c], s[o]);
      atomicAdd(&cs[64 + c], ss[o]);
    }
    __syncthreads();
    if (threadIdx.x < 128) atomicAdd(&csum[threadIdx.x], cs[threadIdx.x]);
  }
}

// ---------------- BN helpers ----------------
__global__ void bn_finalize(const float* __restrict__ acc, const float* __restrict__ gamma,
                            const float* __restrict__ beta, float* __restrict__ scsh,
                            float inv_n) {
  int t = threadIdx.x;  // 64
  float mean = acc[t] * inv_n;
  float var = acc[64 + t] * inv_n - mean * mean;
  float sc = gamma[t] * rsqrtf(var + EPSV);
  scsh[t] = sc;
  scsh[64 + t] = beta[t] - mean * sc;
}

__global__ __launch_bounds__(256) void bn_apply_bf(const float* __restrict__ X,
                                                   u16* __restrict__ Y,
                                                   const float* __restrict__ scsh, int relu) {
  long i = (long)blockIdx.x * 256 + threadIdx.x;  // NN*16 float4s
  float4 v = reinterpret_cast<const float4*>(X)[i];
  int c = (int)((i * 4) & 63);
  v.x = fmaf(v.x, scsh[c],     scsh[64 + c]);
  v.y = fmaf(v.y, scsh[c + 1], scsh[65 + c]);
  v.z = fmaf(v.z, scsh[c + 2], scsh[66 + c]);
  v.w = fmaf(v.w, scsh[c + 3], scsh[67 + c]);
  if (relu) {
    v.x = fmaxf(v.x, 0.f); v.y = fmaxf(v.y, 0.f);
    v.z = fmaxf(v.z, 0.f); v.w = fmaxf(v.w, 0.f);
  }
  reinterpret_cast<ushort4*>(Y)[i] = make_ushort4(f2bf(v.x), f2bf(v.y), f2bf(v.z), f2bf(v.w));
}

// ---------------- final head: BN+ReLU from f32 pre-acts, tiny GEMM -----------
template<int KO>
__global__ __launch_bounds__(256) void headfin_bn(const float* __restrict__ Z,
                                                  const float* __restrict__ scsh,
                                                  const float* __restrict__ W2,
                                                  const float* __restrict__ b2,
                                                  float* __restrict__ out, int n) {
  __shared__ float ws[KO * 64];
  for (int i = threadIdx.x; i < KO * 64; i += 256) ws[i] = W2[i];
  __syncthreads();
  long node = (long)blockIdx.x * 256 + threadIdx.x;
  if (node >= n) return;
  float x[64];
#pragma unroll
  for (int i = 0; i < 16; ++i) {
    float4 z4 = reinterpret_cast<const float4*>(Z + node * 64)[i];
    int c = i * 4;
    x[c]     = fmaxf(fmaf(z4.x, scsh[c],     scsh[64 + c]), 0.f);
    x[c + 1] = fmaxf(fmaf(z4.y, scsh[c + 1], scsh[65 + c]), 0.f);
    x[c + 2] = fmaxf(fmaf(z4.z, scsh[c + 2], scsh[66 + c]), 0.f);
    x[c + 3] = fmaxf(fmaf(z4.w, scsh[c + 3], scsh[67 + c]), 0.f);
  }
#pragma unroll
  for (int o = 0; o < KO; ++o) {
    float a = b2[o];
#pragma unroll
    for (int d = 0; d < 64; ++d) a = fmaf(x[d], ws[o * 64 + d], a);
    out[node * KO + o] = a;
  }
}

extern "C" void kernel_launch(void* const* d_in, const int* in_sizes, int n_in,
                              void* d_out, int out_size, void* d_ws, size_t ws_size,
                              hipStream_t stream) {
  const float* v     = (const float*)d_in[0];
  const int*   src   = (const int*)d_in[1];
  const int*   dst   = (const int*)d_in[2];
  const int*   rt    = (const int*)d_in[3];
  const float* norm  = (const float*)d_in[4];
  const float* emb_W = (const float*)d_in[5];
  const float* emb_g  = (const float*)d_in[7];
  const float* emb_be = (const float*)d_in[8];
  const float* rel_w  = (const float*)d_in[9];
  const float* Wih    = (const float*)d_in[10];
  const float* Whh    = (const float*)d_in[11];
  const float* bih    = (const float*)d_in[12];
  const float* bhh    = (const float*)d_in[13];
  const float* ker_g  = (const float*)d_in[14];
  const float* ker_be = (const float*)d_in[15];
  const float* aW1    = (const float*)d_in[16];
  const float* a_g  = (const float*)d_in[18];
  const float* a_be = (const float*)d_in[19];
  const float* aW2  = (const float*)d_in[20];
  const float* ab2  = (const float*)d_in[21];
  const float* bW1  = (const float*)d_in[22];
  const float* b_g  = (const float*)d_in[24];
  const float* b_be = (const float*)d_in[25];
  const float* bW2  = (const float*)d_in[26];
  const float* bb2  = (const float*)d_in[27];
  float* out = (float*)d_out;

  // ---- workspace carve-up ----
  char* p = (char*)d_ws;
  auto nxt = [&](size_t bytes) -> char* {
    char* r = p; p += (bytes + 255) & ~(size_t)255; return r;
  };
  int*   GCNT = (int*)nxt(512 * 4);                 // bucket counts (memset w/ ACCs)
  float* ACCs = (float*)nxt(512 * 4);               // BN stat accumulators
  float* Z    = (float*)nxt((size_t)NP * 64 * 4);   // f32 pre-BN scratch
  u16*   X1   = (u16*)nxt((size_t)NP * 64 * 2);     // h (bf16)
  u16*   X2   = (u16*)nxt((size_t)NP * 64 * 2);     // h0 (bf16)
  u16*   ACCB = (u16*)nxt((size_t)NP * 192 * 2);    // gathered rel-sums
  u16*   G2B  = (u16*)nxt((size_t)NP * 192 * 2);    // h @ Whh^T
  u64*   REG  = (u64*)nxt((size_t)NBKT * CAP * 8);  // padded bucket regions
  u64*   CSR  = (u64*)nxt((size_t)NE * 8);          // compact dst-sorted records
  int*   BBAS = (int*)nxt(512 * 4);
  int*   ROWP = (int*)nxt((size_t)(NN + 8) * 4);
  u32*   PWf  = (u32*)nxt(18432 * 4);
  u32*   PWem = (u32*)nxt(2048 * 4);
  u32*   PWhh = (u32*)nxt(6144 * 4);
  u32*   PWa  = (u32*)nxt(2048 * 4);
  u32*   PWb  = (u32*)nxt(2048 * 4);
  float* WROW = (float*)nxt(147456);
  float* SC   = (float*)nxt(512 * 4);

  hipMemsetAsync(GCNT, 0, 1024 * 4, stream);  // GCNT + ACCs contiguous

  // setup + hierarchical CSR build
  setupA<<<176, 256, 0, stream>>>(rel_w, Wih, emb_W, Whh, WROW, PWem, PWhh);
  countplace<<<782, 256, 0, stream>>>(src, dst, rt, norm, GCNT, REG);
  bucketscan<<<1, 512, 0, stream>>>(GCNT, BBAS, ROWP);
  localsort<<<NBKT, 256, 0, stream>>>(GCNT, BBAS, REG, CSR, ROWP);
  pack_wf<<<72, 256, 0, stream>>>(WROW, PWf);

  // embedding: Z = v @ emb_W^T (fused colsum); X2 = bf16(relu(BN(Z)))
  gemm_mfma<64, 64, 1, 0, 1, 0><<<782, 256, 0, stream>>>(v, PWem, Z, nullptr, nullptr,
                                                         nullptr, nullptr, ACCs + 0, NN);
  bn_finalize<<<1, 64, 0, stream>>>(ACCs + 0, emb_g, emb_be, SC + 0, 1.f / NN);
  bn_apply_bf<<<6250, 256, 0, stream>>>(Z, X2, SC + 0, 1);

  // layer 1 (h==0): gather -> fused GEMM+GRU -> X1 = h1
  csr_gather<<<25000, 256, 0, stream>>>(ROWP, CSR, X2, ACCB);
  gemm_mfma<192, 192, 0, 1, 0, 1><<<782, 256, 0, stream>>>(ACCB, PWf, X1, bih, bhh,
                                                           nullptr, nullptr, nullptr, NN);

  // layer 2: gather(h1) -> G2 = h1 @ Whh^T -> fused GEMM+GRU (+ker BN stats) -> X1 = h2
  csr_gather<<<25000, 256, 0, stream>>>(ROWP, CSR, X1, ACCB);
  gemm_mfma<64, 192, 0, 0, 0, 1><<<782, 256, 0, stream>>>(X1, PWhh, G2B, nullptr, nullptr,
                                                          nullptr, nullptr, nullptr, NN);
  gemm_mfma<192, 192, 0, 2, 1, 1><<<782, 256, 0, stream>>>(ACCB, PWf, X1, bih, bhh,
                                                           G2B, X1, ACCs + 128, NN);

  // ker BN finalize; fold scale into head weights (shift cancels in head BN)
  bn_finalize<<<1, 64, 0, stream>>>(ACCs + 128, ker_g, ker_be, SC + 128, 1.f / NN);
  fold_pack<<<16, 256, 0, stream>>>(aW1, bW1, SC + 128, PWa, PWb);

  // head A
  gemm_mfma<64, 64, 0, 0, 1, 0><<<782, 256, 0, stream>>>(X1, PWa, Z, nullptr, nullptr,
                                                         nullptr, nullptr, ACCs + 256, NN);
  bn_finalize<<<1, 64, 0, stream>>>(ACCs + 256, a_g, a_be, SC + 256, 1.f / NN);
  headfin_bn<2><<<391, 256, 0, stream>>>(Z, SC + 256, aW2, ab2, out, NN);

  // head B
  gemm_mfma<64, 64, 0, 0, 1, 0><<<782, 256, 0, stream>>>(X1, PWb, Z, nullptr, nullptr,
                                                         nullptr, nullptr, ACCs + 384, NN);
  bn_finalize<<<1, 64, 0, stream>>>(ACCs + 384, b_g, b_be, SC + 384, 1.f / NN);
  headfin_bn<21><<<391, 256, 0, stream>>>(Z, SC + 384, bW2, bb2, out + (long)NN * 2, NN);
}

// Round 7
// 419.132 us; speedup vs baseline: 6.0407x; 1.0194x over previous
//
#include <hip/hip_runtime.h>

#define NN 100000
#define NE 1600000
#define NP 100096   // 782 * 128 rows, GEMM tile padding
#define NBKT 391    // ceil(NN/256) coarse buckets
#define CAP 6144    // padded region capacity per bucket
#define EPSV 1e-5f

typedef unsigned int u32;
typedef unsigned short u16;
typedef unsigned long long u64;
typedef __bf16 bf16x8 __attribute__((ext_vector_type(8)));
typedef float f32x4 __attribute__((ext_vector_type(4)));

#define GLBP(x) ((const __attribute__((address_space(1))) u32*)(x))
#define LDSP(x) ((__attribute__((address_space(3))) u32*)(x))

__device__ __forceinline__ u16 f2bf(float f) {
  u32 x = __float_as_uint(f);
  return (u16)((x + 0x7FFFu + ((x >> 16) & 1u)) >> 16);  // RNE
}
__device__ __forceinline__ float bf2f(u16 h) { return __uint_as_float(((u32)h) << 16); }

// ---------------- setup A: wfuse (blocks 0..143) | pack emb (144..151) | pack Whh (152..175)
__device__ __forceinline__ void pack_one(const float* W, u32* out, int K, int KOT, int i) {
  int q = i & 3, lane = (i >> 2) & 63, f = i >> 8;
  int ks = f / KOT, ot = f - ks * KOT;
  int o = ot * 16 + (lane & 15);
  int k = ks * 32 + (lane >> 4) * 8 + q * 2;
  out[i] = (u32)f2bf(W[o * K + k]) | ((u32)f2bf(W[o * K + k + 1]) << 16);
}

__global__ void setupA(const float* __restrict__ relw, const float* __restrict__ Wih,
                       const float* __restrict__ embW, const float* __restrict__ Whh,
                       float* __restrict__ Wrow, u32* __restrict__ PWem, u32* __restrict__ PWhh) {
  int b = blockIdx.x;
  if (b < 144) {
    int t = b * 256 + threadIdx.x;
    if (t >= 192 * 192) return;
    int kg = t / 192, j = t % 192;
    const float* a = relw + (j >> 6) * 4096 + (j & 63) * 64;
    const float* w = Wih + kg * 64;
    float s = 0.f;
#pragma unroll
    for (int k = 0; k < 64; ++k) s += a[k] * w[k];
    Wrow[kg * 192 + j] = s;
  } else if (b < 152) {
    pack_one(embW, PWem, 64, 4, (b - 144) * 256 + threadIdx.x);
  } else {
    pack_one(Whh, PWhh, 64, 12, (b - 152) * 256 + threadIdx.x);
  }
}

__global__ void pack_wf(const float* __restrict__ Wrow, u32* __restrict__ PWf) {
  pack_one(Wrow, PWf, 192, 12, blockIdx.x * 256 + threadIdx.x);  // 72 blocks
}

// pack head weights folded with ker-BN scale
__global__ void fold_pack(const float* __restrict__ Wa, const float* __restrict__ Wb,
                          const float* __restrict__ sc, u32* __restrict__ Pa,
                          u32* __restrict__ Pb) {
  int iu = blockIdx.x * 256 + threadIdx.x;  // 4096
  int hsel = iu >> 11;
  int i = iu & 2047;
  const float* W = hsel ? Wb : Wa;
  u32* P = hsel ? Pb : Pa;
  int q = i & 3, lane = (i >> 2) & 63, f = i >> 8;
  int ks = f >> 2, ot = f & 3;
  int o = ot * 16 + (lane & 15);
  int k = ks * 32 + (lane >> 4) * 8 + q * 2;
  P[i] = (u32)f2bf(W[o * 64 + k] * sc[k]) | ((u32)f2bf(W[o * 64 + k + 1] * sc[k + 1]) << 16);
}

// ---------------------------------------------------------------------------
// Hierarchical CSR build.
// record: low u32 = src(0..16) | rel(20..21) | dst&255(22..29); high u32 = norm bits
// ---------------------------------------------------------------------------
__global__ __launch_bounds__(256) void countplace(const int* __restrict__ src,
                                                  const int* __restrict__ dst,
                                                  const int* __restrict__ rt,
                                                  const float* __restrict__ nrm,
                                                  int* __restrict__ gcnt,
                                                  u64* __restrict__ region) {
  __shared__ u32 hist[NBKT], gbase[NBKT];
  const int t = threadIdx.x;
  for (int i = t; i < NBKT; i += 256) hist[i] = 0;
  __syncthreads();
  const int e0 = blockIdx.x * 2048 + t;
  u32 rlo[8], rhi[8], lrank[8];
  int bkt[8];
#pragma unroll
  for (int i = 0; i < 8; ++i) {
    int e = e0 + i * 256;
    bkt[i] = -1;
    if (e < NE) {
      int d = dst[e];
      int b = d >> 8;
      bkt[i] = b;
      lrank[i] = atomicAdd(&hist[b], 1u);
      rlo[i] = (u32)src[e] | ((u32)rt[e] << 20) | ((u32)(d & 255) << 22);
      rhi[i] = __float_as_uint(nrm[e]);
    }
  }
  __syncthreads();
  for (int i = t; i < NBKT; i += 256) {
    u32 h = hist[i];
    gbase[i] = h ? (u32)atomicAdd(&gcnt[i], (int)h) : 0u;
  }
  __syncthreads();
#pragma unroll
  for (int i = 0; i < 8; ++i) {
    if (bkt[i] >= 0) {
      u32 pos = gbase[bkt[i]] + lrank[i];
      if (pos < CAP)
        region[(size_t)bkt[i] * CAP + pos] = (u64)rlo[i] | ((u64)rhi[i] << 32);
    }
  }
}

__global__ __launch_bounds__(512) void bucketscan(const int* __restrict__ gcnt,
                                                  int* __restrict__ bbase,
                                                  int* __restrict__ rowp) {
  int t = threadIdx.x;
  int v = (t < NBKT) ? gcnt[t] : 0;
  __shared__ int sh[512];
  sh[t] = v;
  __syncthreads();
#pragma unroll
  for (int off = 1; off < 512; off <<= 1) {
    int u = (t >= off) ? sh[t - off] : 0;
    __syncthreads();
    sh[t] += u;
    __syncthreads();
  }
  if (t < NBKT) bbase[t] = sh[t] - v;  // exclusive
  if (t == 0) rowp[NN] = NE;
}

__global__ __launch_bounds__(256) void localsort(const int* __restrict__ gcnt,
                                                 const int* __restrict__ bbase,
                                                 const u64* __restrict__ region,
                                                 u64* __restrict__ csr,
                                                 int* __restrict__ rowp) {
  const int b = blockIdx.x, t = threadIdx.x;
  int n = gcnt[b];
  if (n > CAP) n = CAP;
  const int base = bbase[b];
  __shared__ u32 hist[256], sc[256];
  hist[t] = 0;
  __syncthreads();
  for (int i = t; i < n; i += 256)
    atomicAdd(&hist[((u32)region[(size_t)b * CAP + i] >> 22) & 255], 1u);
  __syncthreads();
  u32 v = hist[t];
  sc[t] = v;
  __syncthreads();
#pragma unroll
  for (int off = 1; off < 256; off <<= 1) {
    u32 u = (t >= off) ? sc[t - off] : 0;
    __syncthreads();
    sc[t] += u;
    __syncthreads();
  }
  u32 excl = sc[t] - v;
  int node = b * 256 + t;
  if (node < NN) rowp[node] = base + (int)excl;
  __syncthreads();
  hist[t] = excl;  // reuse as cursor
  __syncthreads();
  for (int i = t; i < n; i += 256) {
    u64 rec = region[(size_t)b * CAP + i];
    u32 pos = atomicAdd(&hist[((u32)rec >> 22) & 255], 1u);
    csr[(size_t)base + pos] = rec;
  }
}

// ---------------- CSR gather: one wave per node, 2 edges per step -------------
__global__ __launch_bounds__(256) void csr_gather(const int* __restrict__ rowp,
                                                  const u64* __restrict__ csr,
                                                  const u16* __restrict__ Xbf,
                                                  u16* __restrict__ ACCbf) {
  int wv = blockIdx.x * 4 + (threadIdx.x >> 6);
  int lane = threadIdx.x & 63;
  if (wv >= NN) return;
  const int half = lane >> 5, c2 = lane & 31;
  int base = rowp[wv], end = rowp[wv + 1];
  float a0x = 0.f, a0y = 0.f, a1x = 0.f, a1y = 0.f, a2x = 0.f, a2y = 0.f;
#define GP(JJ)                                                                   \
  { u32 sA = (u32)__builtin_amdgcn_readlane((int)lo, (JJ));                      \
    u32 sB = (u32)__builtin_amdgcn_readlane((int)lo, (JJ) + 1);                  \
    u32 nA = (u32)__builtin_amdgcn_readlane((int)hi, (JJ));                      \
    u32 nB = (u32)__builtin_amdgcn_readlane((int)hi, (JJ) + 1);                  \
    u32 srp = half ? sB : sA;                                                    \
    float nm = __uint_as_float(half ? nB : nA);                                  \
    u32 xw = *(const u32*)(Xbf + (size_t)(srp & 0xFFFFFu) * 64 + 2 * c2);        \
    float x0 = bf2f((u16)xw), x1 = bf2f((u16)(xw >> 16));                        \
    int r = (int)((srp >> 20) & 3);                                              \
    float n0 = (r == 0) ? nm : 0.f;                                              \
    float n1 = (r == 1) ? nm : 0.f;                                              \
    float n2 = (r == 2) ? nm : 0.f;                                              \
    a0x = fmaf(x0, n0, a0x); a0y = fmaf(x1, n0, a0y);                            \
    a1x = fmaf(x0, n1, a1x); a1y = fmaf(x1, n1, a1y);                            \
    a2x = fmaf(x0, n2, a2x); a2y = fmaf(x1, n2, a2y); }
  for (int c = base; c < end; c += 64) {
    int m = end - c; m = m > 64 ? 64 : m;
    u32 lo = 0, hi = 0;
    if (lane < m) {
      u64 r = csr[(size_t)c + lane];
      lo = (u32)r; hi = (u32)(r >> 32);
    }
    int j = 0;
    for (; j + 16 <= m; j += 16) {
      GP(j) GP(j + 2) GP(j + 4) GP(j + 6)
      GP(j + 8) GP(j + 10) GP(j + 12) GP(j + 14)
    }
    for (; j < m; j += 2) { GP(j) }
  }
#undef GP
  a0x += __shfl_xor(a0x, 32); a0y += __shfl_xor(a0y, 32);
  a1x += __shfl_xor(a1x, 32); a1y += __shfl_xor(a1y, 32);
  a2x += __shfl_xor(a2x, 32); a2y += __shfl_xor(a2y, 32);
  if (half == 0) {
    u32* orow = (u32*)(ACCbf + (size_t)wv * 192);
    orow[c2]      = (u32)f2bf(a0x) | ((u32)f2bf(a0y) << 16);
    orow[32 + c2] = (u32)f2bf(a1x) | ((u32)f2bf(a1y) << 16);
    orow[64 + c2] = (u32)f2bf(a2x) | ((u32)f2bf(a2y) << 16);
  }
}

// ---------------------------------------------------------------------------
// MFMA GEMM, whole-B-in-LDS: stage the full packed weight panel once (one
// barrier), then the K-loop is pure ds_read_b128 + MFMA with NO barriers and
// no vmcnt drains. A fragments stream from global, prefetched one K-step ahead.
//   AF32: A is f32 (row-clamped); GRU: 0 store, 1 h'=(1-z)n, 2 full
//   CS: fused column sum/sumsq atomics (KO==64 output paths)
// ---------------------------------------------------------------------------
template<int K, int KO, int AF32, int GRU, int CS, int OUTBF>
__global__ __launch_bounds__(256) void gemm_mfma(
    const void* __restrict__ Av, const u32* __restrict__ Wpk, void* __restrict__ Yv,
    const float* __restrict__ bih, const float* __restrict__ bhh,
    const u16* __restrict__ G2B, const u16* __restrict__ Hv,
    float* __restrict__ csum, int n) {
  constexpr int KOT = KO / 16, KS = K / 32;
  constexpr int NFRAG = KS * KOT;        // 16B fragments per lane
  __shared__ u32 bsh[NFRAG * 256];
  __shared__ float cs[128];
  const int lane = threadIdx.x & 63, w = threadIdx.x >> 6;
  const int rr = lane & 15, kg = lane >> 4;
  const long mbase = (long)blockIdx.x * 128 + w * 32;
  const u16* Abf = (const u16*)Av;
  const float* Af = (const float*)Av;

  auto loadAbf = [&](int ks, int halfsel) -> bf16x8 {
    if (AF32) {
      long r = mbase + halfsel * 16 + rr;
      if (r > n - 1) r = n - 1;
      const float* pp = Af + r * K + ks * 32 + kg * 8;
      float4 u0 = *(const float4*)pp;
      float4 u1 = *(const float4*)(pp + 4);
      bf16x8 o_;
      o_[0] = __builtin_bit_cast(__bf16, f2bf(u0.x));
      o_[1] = __builtin_bit_cast(__bf16, f2bf(u0.y));
      o_[2] = __builtin_bit_cast(__bf16, f2bf(u0.z));
      o_[3] = __builtin_bit_cast(__bf16, f2bf(u0.w));
      o_[4] = __builtin_bit_cast(__bf16, f2bf(u1.x));
      o_[5] = __builtin_bit_cast(__bf16, f2bf(u1.y));
      o_[6] = __builtin_bit_cast(__bf16, f2bf(u1.z));
      o_[7] = __builtin_bit_cast(__bf16, f2bf(u1.w));
      return o_;
    }
    return *reinterpret_cast<const bf16x8*>(Abf + (mbase + halfsel * 16 + rr) * K + ks * 32 + kg * 8);
  };

  // stage the entire packed B panel (NFRAG*64 16B chunks) via global_load_lds
  constexpr int PASSES = NFRAG / 4;  // 4 waves, one 16B chunk per lane per pass
#pragma unroll
  for (int i = 0; i < PASSES; ++i) {
    int c = i * 4 + w;
    __builtin_amdgcn_global_load_lds(GLBP(Wpk + (long)c * 256 + lane * 4),
                                     LDSP(&bsh[c * 256]), 16, 0, 0);
  }
  bf16x8 a0 = loadAbf(0, 0);
  bf16x8 a1 = loadAbf(0, 1);
  __syncthreads();  // single drain of the B stage

  f32x4 acc[2][KOT] = {};
#pragma unroll
  for (int ks = 0; ks < KS; ++ks) {
    bf16x8 c0 = a0, c1 = a1;
    if (ks + 1 < KS) {
      a0 = loadAbf(ks + 1, 0);  // overlaps the MFMAs below
      a1 = loadAbf(ks + 1, 1);
    }
#pragma unroll
    for (int o = 0; o < KOT; ++o) {
      bf16x8 bfr = *reinterpret_cast<const bf16x8*>(&bsh[((ks * KOT + o) * 64 + lane) * 4]);
      acc[0][o] = __builtin_amdgcn_mfma_f32_16x16x32_bf16(c0, bfr, acc[0][o], 0, 0, 0);
      acc[1][o] = __builtin_amdgcn_mfma_f32_16x16x32_bf16(c1, bfr, acc[1][o], 0, 0, 0);
    }
  }

  float s[4] = {0.f, 0.f, 0.f, 0.f}, ss[4] = {0.f, 0.f, 0.f, 0.f};
  if (GRU == 0) {
#pragma unroll
    for (int tl = 0; tl < 2; ++tl)
#pragma unroll
      for (int o = 0; o < KOT; ++o)
#pragma unroll
        for (int q = 0; q < 4; ++q) {
          long row = mbase + tl * 16 + kg * 4 + q;
          float vv = acc[tl][o][q];
          if (row < n) {
            long off = row * KO + o * 16 + rr;
            if (OUTBF) ((u16*)Yv)[off] = f2bf(vv);
            else       ((float*)Yv)[off] = vv;
            if (CS) { s[o & 3] += vv; ss[o & 3] += vv * vv; }
          }
        }
  } else {
    float bi[12], bh_[12];
#pragma unroll
    for (int g = 0; g < 3; ++g)
#pragma unroll
      for (int o = 0; o < 4; ++o) {
        bi[g * 4 + o] = bih[g * 64 + o * 16 + rr];
        bh_[g * 4 + o] = bhh[g * 64 + o * 16 + rr];
      }
#pragma unroll
    for (int tl = 0; tl < 2; ++tl)
#pragma unroll
      for (int o = 0; o < 4; ++o) {
        int c = o * 16 + rr;
#pragma unroll
        for (int q = 0; q < 4; ++q) {
          long row = mbase + tl * 16 + kg * 4 + q;
          float ir = acc[tl][o][q] + bi[o];
          float iz = acc[tl][o + 4][q] + bi[4 + o];
          float in_ = acc[tl][o + 8][q] + bi[8 + o];
          float hr = bh_[o], hz = bh_[4 + o], hn = bh_[8 + o], hv = 0.f;
          if (GRU == 2) {
            const u16* g2 = G2B + row * 192;
            hr += bf2f(g2[c]); hz += bf2f(g2[64 + c]); hn += bf2f(g2[128 + c]);
            hv = bf2f(Hv[row * 64 + c]);
          }
          float rg = 1.f / (1.f + __expf(-(ir + hr)));
          float zg = 1.f / (1.f + __expf(-(iz + hz)));
          float ng = tanhf(in_ + rg * hn);
          float h = (1.f - zg) * ng + (GRU == 2 ? zg * hv : 0.f);
          if (row < n) {
            ((u16*)Yv)[row * 64 + c] = f2bf(h);
            if (CS) { s[o] += h; ss[o] += h * h; }
          }
        }
      }
  }
  if (CS) {
    for (int i = threadIdx.x; i < 128; i += 256) cs[i] = 0.f;
    __syncthreads();
#pragma unroll
    for (int o = 0; o < 4; ++o) {
      int c = o * 16 + rr;
      atomicAdd(&cs[c], s[o]);
      atomicAdd(&cs[64 + c], ss[o]);
    }
    __syncthreads();
    if (threadIdx.x < 128) atomicAdd(&csum[threadIdx.x], cs[threadIdx.x]);
  }
}

// ---------------- BN helpers ----------------
__global__ void bn_finalize(const float* __restrict__ acc, const float* __restrict__ gamma,
                            const float* __restrict__ beta, float* __restrict__ scsh,
                            float inv_n) {
  int t = threadIdx.x;  // 64
  float mean = acc[t] * inv_n;
  float var = acc[64 + t] * inv_n - mean * mean;
  float sc = gamma[t] * rsqrtf(var + EPSV);
  scsh[t] = sc;
  scsh[64 + t] = beta[t] - mean * sc;
}

__global__ __launch_bounds__(256) void bn_apply_bf(const float* __restrict__ X,
                                                   u16* __restrict__ Y,
                                                   const float* __restrict__ scsh, int relu) {
  long i = (long)blockIdx.x * 256 + threadIdx.x;  // NN*16 float4s
  float4 v = reinterpret_cast<const float4*>(X)[i];
  int c = (int)((i * 4) & 63);
  v.x = fmaf(v.x, scsh[c],     scsh[64 + c]);
  v.y = fmaf(v.y, scsh[c + 1], scsh[65 + c]);
  v.z = fmaf(v.z, scsh[c + 2], scsh[66 + c]);
  v.w = fmaf(v.w, scsh[c + 3], scsh[67 + c]);
  if (relu) {
    v.x = fmaxf(v.x, 0.f); v.y = fmaxf(v.y, 0.f);
    v.z = fmaxf(v.z, 0.f); v.w = fmaxf(v.w, 0.f);
  }
  reinterpret_cast<ushort4*>(Y)[i] = make_ushort4(f2bf(v.x), f2bf(v.y), f2bf(v.z), f2bf(v.w));
}

// ---------------- final head: BN+ReLU from f32 pre-acts, tiny GEMM -----------
template<int KO>
__global__ __launch_bounds__(256) void headfin_bn(const float* __restrict__ Z,
                                                  const float* __restrict__ scsh,
                                                  const float* __restrict__ W2,
                                                  const float* __restrict__ b2,
                                                  float* __restrict__ out, int n) {
  __shared__ float ws[KO * 64];
  for (int i = threadIdx.x; i < KO * 64; i += 256) ws[i] = W2[i];
  __syncthreads();
  long node = (long)blockIdx.x * 256 + threadIdx.x;
  if (node >= n) return;
  float x[64];
#pragma unroll
  for (int i = 0; i < 16; ++i) {
    float4 z4 = reinterpret_cast<const float4*>(Z + node * 64)[i];
    int c = i * 4;
    x[c]     = fmaxf(fmaf(z4.x, scsh[c],     scsh[64 + c]), 0.f);
    x[c + 1] = fmaxf(fmaf(z4.y, scsh[c + 1], scsh[65 + c]), 0.f);
    x[c + 2] = fmaxf(fmaf(z4.z, scsh[c + 2], scsh[66 + c]), 0.f);
    x[c + 3] = fmaxf(fmaf(z4.w, scsh[c + 3], scsh[67 + c]), 0.f);
  }
#pragma unroll
  for (int o = 0; o < KO; ++o) {
    float a = b2[o];
#pragma unroll
    for (int d = 0; d < 64; ++d) a = fmaf(x[d], ws[o * 64 + d], a);
    out[node * KO + o] = a;
  }
}

extern "C" void kernel_launch(void* const* d_in, const int* in_sizes, int n_in,
                              void* d_out, int out_size, void* d_ws, size_t ws_size,
                              hipStream_t stream) {
  const float* v     = (const float*)d_in[0];
  const int*   src   = (const int*)d_in[1];
  const int*   dst   = (const int*)d_in[2];
  const int*   rt    = (const int*)d_in[3];
  const float* norm  = (const float*)d_in[4];
  const float* emb_W = (const float*)d_in[5];
  const float* emb_g  = (const float*)d_in[7];
  const float* emb_be = (const float*)d_in[8];
  const float* rel_w  = (const float*)d_in[9];
  const float* Wih    = (const float*)d_in[10];
  const float* Whh    = (const float*)d_in[11];
  const float* bih    = (const float*)d_in[12];
  const float* bhh    = (const float*)d_in[13];
  const float* ker_g  = (const float*)d_in[14];
  const float* ker_be = (const float*)d_in[15];
  const float* aW1    = (const float*)d_in[16];
  const float* a_g  = (const float*)d_in[18];
  const float* a_be = (const float*)d_in[19];
  const float* aW2  = (const float*)d_in[20];
  const float* ab2  = (const float*)d_in[21];
  const float* bW1  = (const float*)d_in[22];
  const float* b_g  = (const float*)d_in[24];
  const float* b_be = (const float*)d_in[25];
  const float* bW2  = (const float*)d_in[26];
  const float* bb2  = (const float*)d_in[27];
  float* out = (float*)d_out;

  // ---- workspace carve-up ----
  char* p = (char*)d_ws;
  auto nxt = [&](size_t bytes) -> char* {
    char* r = p; p += (bytes + 255) & ~(size_t)255; return r;
  };
  int*   GCNT = (int*)nxt(512 * 4);                 // bucket counts (memset w/ ACCs)
  float* ACCs = (float*)nxt(512 * 4);               // BN stat accumulators
  float* Z    = (float*)nxt((size_t)NP * 64 * 4);   // f32 pre-BN scratch
  u16*   X1   = (u16*)nxt((size_t)NP * 64 * 2);     // h (bf16)
  u16*   X2   = (u16*)nxt((size_t)NP * 64 * 2);     // h0 (bf16)
  u16*   ACCB = (u16*)nxt((size_t)NP * 192 * 2);    // gathered rel-sums
  u16*   G2B  = (u16*)nxt((size_t)NP * 192 * 2);    // h @ Whh^T
  u64*   REG  = (u64*)nxt((size_t)NBKT * CAP * 8);  // padded bucket regions
  u64*   CSR  = (u64*)nxt((size_t)NE * 8);          // compact dst-sorted records
  int*   BBAS = (int*)nxt(512 * 4);
  int*   ROWP = (int*)nxt((size_t)(NN + 8) * 4);
  u32*   PWf  = (u32*)nxt(18432 * 4);
  u32*   PWem = (u32*)nxt(2048 * 4);
  u32*   PWhh = (u32*)nxt(6144 * 4);
  u32*   PWa  = (u32*)nxt(2048 * 4);
  u32*   PWb  = (u32*)nxt(2048 * 4);
  float* WROW = (float*)nxt(147456);
  float* SC   = (float*)nxt(512 * 4);

  hipMemsetAsync(GCNT, 0, 1024 * 4, stream);  // GCNT + ACCs contiguous

  // setup + hierarchical CSR build
  setupA<<<176, 256, 0, stream>>>(rel_w, Wih, emb_W, Whh, WROW, PWem, PWhh);
  countplace<<<782, 256, 0, stream>>>(src, dst, rt, norm, GCNT, REG);
  bucketscan<<<1, 512, 0, stream>>>(GCNT, BBAS, ROWP);
  localsort<<<NBKT, 256, 0, stream>>>(GCNT, BBAS, REG, CSR, ROWP);
  pack_wf<<<72, 256, 0, stream>>>(WROW, PWf);

  // embedding: Z = v @ emb_W^T (fused colsum); X2 = bf16(relu(BN(Z)))
  gemm_mfma<64, 64, 1, 0, 1, 0><<<782, 256, 0, stream>>>(v, PWem, Z, nullptr, nullptr,
                                                         nullptr, nullptr, ACCs + 0, NN);
  bn_finalize<<<1, 64, 0, stream>>>(ACCs + 0, emb_g, emb_be, SC + 0, 1.f / NN);
  bn_apply_bf<<<6250, 256, 0, stream>>>(Z, X2, SC + 0, 1);

  // layer 1 (h==0): gather -> fused GEMM+GRU -> X1 = h1
  csr_gather<<<25000, 256, 0, stream>>>(ROWP, CSR, X2, ACCB);
  gemm_mfma<192, 192, 0, 1, 0, 1><<<782, 256, 0, stream>>>(ACCB, PWf, X1, bih, bhh,
                                                           nullptr, nullptr, nullptr, NN);

  // layer 2: gather(h1) -> G2 = h1 @ Whh^T -> fused GEMM+GRU (+ker BN stats) -> X1 = h2
  csr_gather<<<25000, 256, 0, stream>>>(ROWP, CSR, X1, ACCB);
  gemm_mfma<64, 192, 0, 0, 0, 1><<<782, 256, 0, stream>>>(X1, PWhh, G2B, nullptr, nullptr,
                                                          nullptr, nullptr, nullptr, NN);
  gemm_mfma<192, 192, 0, 2, 1, 1><<<782, 256, 0, stream>>>(ACCB, PWf, X1, bih, bhh,
                                                           G2B, X1, ACCs + 128, NN);

  // ker BN finalize; fold scale into head weights (shift cancels in head BN)
  bn_finalize<<<1, 64, 0, stream>>>(ACCs + 128, ker_g, ker_be, SC + 128, 1.f / NN);
  fold_pack<<<16, 256, 0, stream>>>(aW1, bW1, SC + 128, PWa, PWb);

  // head A
  gemm_mfma<64, 64, 0, 0, 1, 0><<<782, 256, 0, stream>>>(X1, PWa, Z, nullptr, nullptr,
                                                         nullptr, nullptr, ACCs + 256, NN);
  bn_finalize<<<1, 64, 0, stream>>>(ACCs + 256, a_g, a_be, SC + 256, 1.f / NN);
  headfin_bn<2><<<391, 256, 0, stream>>>(Z, SC + 256, aW2, ab2, out, NN);

  // head B
  gemm_mfma<64, 64, 0, 0, 1, 0><<<782, 256, 0, stream>>>(X1, PWb, Z, nullptr, nullptr,
                                                         nullptr, nullptr, ACCs + 384, NN);
  bn_finalize<<<1, 64, 0, stream>>>(ACCs + 384, b_g, b_be, SC + 384, 1.f / NN);
  headfin_bn<21><<<391, 256, 0, stream>>>(Z, SC + 384, bW2, bb2, out + (long)NN * 2, NN);
}

// Round 8
// 414.202 us; speedup vs baseline: 6.1126x; 1.0119x over previous
//
#include <hip/hip_runtime.h>

#define NN 100000
#define NE 1600000
#define NP 100096   // 782 * 128 rows, GEMM tile padding
#define NBKT 391    // ceil(NN/256) coarse buckets
#define CAP 6144    // padded region capacity per bucket
#define EPSV 1e-5f

typedef unsigned int u32;
typedef unsigned short u16;
typedef unsigned long long u64;
typedef __bf16 bf16x8 __attribute__((ext_vector_type(8)));
typedef float f32x4 __attribute__((ext_vector_type(4)));

#define GLBP(x) ((const __attribute__((address_space(1))) u32*)(x))
#define LDSP(x) ((__attribute__((address_space(3))) u32*)(x))

__device__ __forceinline__ u16 f2bf(float f) {
  u32 x = __float_as_uint(f);
  return (u16)((x + 0x7FFFu + ((x >> 16) & 1u)) >> 16);  // RNE
}
__device__ __forceinline__ float bf2f(u16 h) { return __uint_as_float(((u32)h) << 16); }

// ---------------- setup A: wfuse (blocks 0..143) | pack emb (144..151) | pack Whh (152..175)
__device__ __forceinline__ void pack_one(const float* W, u32* out, int K, int KOT, int i) {
  int q = i & 3, lane = (i >> 2) & 63, f = i >> 8;
  int ks = f / KOT, ot = f - ks * KOT;
  int o = ot * 16 + (lane & 15);
  int k = ks * 32 + (lane >> 4) * 8 + q * 2;
  out[i] = (u32)f2bf(W[o * K + k]) | ((u32)f2bf(W[o * K + k + 1]) << 16);
}

__global__ void setupA(const float* __restrict__ relw, const float* __restrict__ Wih,
                       const float* __restrict__ embW, const float* __restrict__ Whh,
                       float* __restrict__ Wrow, u32* __restrict__ PWem, u32* __restrict__ PWhh) {
  int b = blockIdx.x;
  if (b < 144) {
    int t = b * 256 + threadIdx.x;
    if (t >= 192 * 192) return;
    int kg = t / 192, j = t % 192;
    const float* a = relw + (j >> 6) * 4096 + (j & 63) * 64;
    const float* w = Wih + kg * 64;
    float s = 0.f;
#pragma unroll
    for (int k = 0; k < 64; ++k) s += a[k] * w[k];
    Wrow[kg * 192 + j] = s;
  } else if (b < 152) {
    pack_one(embW, PWem, 64, 4, (b - 144) * 256 + threadIdx.x);
  } else {
    pack_one(Whh, PWhh, 64, 12, (b - 152) * 256 + threadIdx.x);
  }
}

__global__ void pack_wf(const float* __restrict__ Wrow, u32* __restrict__ PWf) {
  pack_one(Wrow, PWf, 192, 12, blockIdx.x * 256 + threadIdx.x);  // 72 blocks
}

// pack BOTH head weights (128 rows) folded with inline ker-BN scale (from raw stats)
__global__ void fold_pack(const float* __restrict__ Wa, const float* __restrict__ Wb,
                          const float* __restrict__ kacc, const float* __restrict__ kg,
                          u32* __restrict__ P) {
  int i = blockIdx.x * 256 + threadIdx.x;  // 4096 = KS(2)*KOT(8)*256
  int q = i & 3, lane = (i >> 2) & 63, f = i >> 8;
  int ks = f >> 3, ot = f & 7;
  int o = ot * 16 + (lane & 15);            // 0..127
  int k = ks * 32 + (lane >> 4) * 8 + q * 2;
  const float* W = (o < 64) ? (Wa + o * 64) : (Wb + (o - 64) * 64);
  const float inv = 1.f / NN;
  float m0 = kacc[k] * inv;
  float s0 = kg[k] * rsqrtf(kacc[64 + k] * inv - m0 * m0 + EPSV);
  float m1 = kacc[k + 1] * inv;
  float s1 = kg[k + 1] * rsqrtf(kacc[64 + k + 1] * inv - m1 * m1 + EPSV);
  P[i] = (u32)f2bf(W[k] * s0) | ((u32)f2bf(W[k + 1] * s1) << 16);
}

// ---------------------------------------------------------------------------
// Hierarchical CSR build.
// record: low u32 = src(0..16) | rel(20..21) | dst&255(22..29); high u32 = norm
// ---------------------------------------------------------------------------
__global__ __launch_bounds__(256) void countplace(const int* __restrict__ src,
                                                  const int* __restrict__ dst,
                                                  const int* __restrict__ rt,
                                                  const float* __restrict__ nrm,
                                                  int* __restrict__ gcnt,
                                                  u64* __restrict__ region) {
  __shared__ u32 hist[NBKT], gbase[NBKT];
  const int t = threadIdx.x;
  for (int i = t; i < NBKT; i += 256) hist[i] = 0;
  __syncthreads();
  const int e0 = blockIdx.x * 2048 + t;
  u32 rlo[8], rhi[8], lrank[8];
  int bkt[8];
#pragma unroll
  for (int i = 0; i < 8; ++i) {
    int e = e0 + i * 256;
    bkt[i] = -1;
    if (e < NE) {
      int d = dst[e];
      int b = d >> 8;
      bkt[i] = b;
      lrank[i] = atomicAdd(&hist[b], 1u);
      rlo[i] = (u32)src[e] | ((u32)rt[e] << 20) | ((u32)(d & 255) << 22);
      rhi[i] = __float_as_uint(nrm[e]);
    }
  }
  __syncthreads();
  for (int i = t; i < NBKT; i += 256) {
    u32 h = hist[i];
    gbase[i] = h ? (u32)atomicAdd(&gcnt[i], (int)h) : 0u;
  }
  __syncthreads();
#pragma unroll
  for (int i = 0; i < 8; ++i) {
    if (bkt[i] >= 0) {
      u32 pos = gbase[bkt[i]] + lrank[i];
      if (pos < CAP)
        region[(size_t)bkt[i] * CAP + pos] = (u64)rlo[i] | ((u64)rhi[i] << 32);
    }
  }
}

__global__ __launch_bounds__(512) void bucketscan(const int* __restrict__ gcnt,
                                                  int* __restrict__ bbase) {
  int t = threadIdx.x;
  int v = (t < NBKT) ? gcnt[t] : 0;
  __shared__ int sh[512];
  sh[t] = v;
  __syncthreads();
#pragma unroll
  for (int off = 1; off < 512; off <<= 1) {
    int u = (t >= off) ? sh[t - off] : 0;
    __syncthreads();
    sh[t] += u;
    __syncthreads();
  }
  if (t < NBKT) bbase[t] = sh[t] - v;  // exclusive
}

// 1024-bin counting sort per bucket: key = (dst&255)*4 + rel -> rel-sorted CSR
// + per-(node,rel) boundaries rowpr[4*node + r] (entry 3 = node end).
__global__ __launch_bounds__(256) void localsort(const int* __restrict__ gcnt,
                                                 const int* __restrict__ bbase,
                                                 const u64* __restrict__ region,
                                                 u64* __restrict__ csr,
                                                 int* __restrict__ rowpr) {
  const int b = blockIdx.x, t = threadIdx.x;
  int n = gcnt[b];
  if (n > CAP) n = CAP;
  const int base = bbase[b];
  __shared__ u32 hist[1024], sc[256];
#pragma unroll
  for (int i = 0; i < 4; ++i) hist[t + 256 * i] = 0;
  __syncthreads();
  for (int i = t; i < n; i += 256)
    atomicAdd(&hist[(u32)(region[(size_t)b * CAP + i] >> 20) & 1023u], 1u);
  __syncthreads();
  u32 a0 = hist[4 * t], a1 = hist[4 * t + 1], a2 = hist[4 * t + 2], a3 = hist[4 * t + 3];
  u32 part = a0 + a1 + a2 + a3;
  sc[t] = part;
  __syncthreads();
#pragma unroll
  for (int off = 1; off < 256; off <<= 1) {
    u32 u = (t >= off) ? sc[t - off] : 0;
    __syncthreads();
    sc[t] += u;
    __syncthreads();
  }
  u32 ex = sc[t] - part;
  int node = b * 256 + t;
  rowpr[4 * node + 0] = base + (int)ex;
  rowpr[4 * node + 1] = base + (int)(ex + a0);
  rowpr[4 * node + 2] = base + (int)(ex + a0 + a1);
  rowpr[4 * node + 3] = base + (int)(ex + a0 + a1 + a2);
  __syncthreads();
  hist[4 * t] = ex; hist[4 * t + 1] = ex + a0;
  hist[4 * t + 2] = ex + a0 + a1; hist[4 * t + 3] = ex + a0 + a1 + a2;
  __syncthreads();
  for (int i = t; i < n; i += 256) {
    u64 rec = region[(size_t)b * CAP + i];
    u32 pos = atomicAdd(&hist[(u32)(rec >> 20) & 1023u], 1u);
    csr[(size_t)base + pos] = rec;
  }
}

// ---------------- CSR gather: wave per node, rel-sorted segments, 2 edges/step
__global__ __launch_bounds__(256) void csr_gather(const int* __restrict__ rowpr,
                                                  const u64* __restrict__ csr,
                                                  const u16* __restrict__ Xbf,
                                                  u16* __restrict__ ACCbf) {
  int wv = blockIdx.x * 4 + (threadIdx.x >> 6);
  int lane = threadIdx.x & 63;
  if (wv >= NN) return;
  const int half = lane >> 5, c2 = lane & 31;
  int4 rp = *reinterpret_cast<const int4*>(rowpr + 4 * wv);
  const int bnd[4] = {rp.x, rp.y, rp.z, rp.w};
  u32* orow = (u32*)(ACCbf + (size_t)wv * 192);
#define PAIRF(J)                                                                  \
  { u32 sA = (u32)__builtin_amdgcn_readlane((int)lo, (J));                        \
    u32 sB = (u32)__builtin_amdgcn_readlane((int)lo, (J) + 1);                    \
    u32 nA = (u32)__builtin_amdgcn_readlane((int)hi, (J));                        \
    u32 nB = (u32)__builtin_amdgcn_readlane((int)hi, (J) + 1);                    \
    u32 srp = half ? sB : sA;                                                     \
    float nm = __uint_as_float(half ? nB : nA);                                   \
    u32 xw = *(const u32*)(Xbf + (size_t)(srp & 0xFFFFFu) * 64 + 2 * c2);         \
    ax = fmaf(__uint_as_float(xw << 16), nm, ax);                                 \
    ay = fmaf(__uint_as_float(xw & 0xFFFF0000u), nm, ay); }
#pragma unroll
  for (int r = 0; r < 3; ++r) {
    int b0 = bnd[r], e0 = bnd[r + 1];
    float ax = 0.f, ay = 0.f;
    for (int c = b0; c < e0; c += 64) {
      int m = e0 - c; m = m > 64 ? 64 : m;
      u32 lo = 0, hi = 0;
      if (lane < m) {
        u64 rec = csr[(size_t)c + lane];
        lo = (u32)rec; hi = (u32)(rec >> 32);
      }
      int j = 0;
      for (; j + 4 <= m; j += 4) { PAIRF(j) PAIRF(j + 2) }
      for (; j + 2 <= m; j += 2) { PAIRF(j) }
      if (j < m) {  // single-edge tail: half 1 contributes 0
        u32 sA = (u32)__builtin_amdgcn_readlane((int)lo, j);
        u32 nA = (u32)__builtin_amdgcn_readlane((int)hi, j);
        float nm = __uint_as_float(half ? 0u : nA);
        u32 xw = *(const u32*)(Xbf + (size_t)(sA & 0xFFFFFu) * 64 + 2 * c2);
        ax = fmaf(__uint_as_float(xw << 16), nm, ax);
        ay = fmaf(__uint_as_float(xw & 0xFFFF0000u), nm, ay);
      }
    }
    ax += __shfl_xor(ax, 32);
    ay += __shfl_xor(ay, 32);
    if (half == 0) orow[r * 32 + c2] = (u32)f2bf(ax) | ((u32)f2bf(ay) << 16);
  }
#undef PAIRF
}

// ---------------------------------------------------------------------------
// MFMA GEMM, whole-B-in-LDS (one barrier), A streamed with 1-step prefetch.
//   AF32: A is f32 (row-clamped); GRU: 0 store, 1 h'=(1-z)n, 2 full
//   CS: fused column sum/sumsq atomics
// ---------------------------------------------------------------------------
template<int K, int KO, int AF32, int GRU, int CS, int OUTBF>
__global__ __launch_bounds__(256) void gemm_mfma(
    const void* __restrict__ Av, const u32* __restrict__ Wpk, void* __restrict__ Yv,
    const float* __restrict__ bih, const float* __restrict__ bhh,
    const u16* __restrict__ G2B, const u16* __restrict__ Hv,
    float* __restrict__ csum, int n) {
  constexpr int KOT = KO / 16, KS = K / 32;
  constexpr int NFRAG = KS * KOT;
  __shared__ u32 bsh[NFRAG * 256];
  __shared__ float cs[2 * KO];
  const int lane = threadIdx.x & 63, w = threadIdx.x >> 6;
  const int rr = lane & 15, kg = lane >> 4;
  const long mbase = (long)blockIdx.x * 128 + w * 32;
  const u16* Abf = (const u16*)Av;
  const float* Af = (const float*)Av;

  auto loadAbf = [&](int ks, int halfsel) -> bf16x8 {
    if (AF32) {
      long r = mbase + halfsel * 16 + rr;
      if (r > n - 1) r = n - 1;
      const float* pp = Af + r * K + ks * 32 + kg * 8;
      float4 u0 = *(const float4*)pp;
      float4 u1 = *(const float4*)(pp + 4);
      bf16x8 o_;
      o_[0] = __builtin_bit_cast(__bf16, f2bf(u0.x));
      o_[1] = __builtin_bit_cast(__bf16, f2bf(u0.y));
      o_[2] = __builtin_bit_cast(__bf16, f2bf(u0.z));
      o_[3] = __builtin_bit_cast(__bf16, f2bf(u0.w));
      o_[4] = __builtin_bit_cast(__bf16, f2bf(u1.x));
      o_[5] = __builtin_bit_cast(__bf16, f2bf(u1.y));
      o_[6] = __builtin_bit_cast(__bf16, f2bf(u1.z));
      o_[7] = __builtin_bit_cast(__bf16, f2bf(u1.w));
      return o_;
    }
    return *reinterpret_cast<const bf16x8*>(Abf + (mbase + halfsel * 16 + rr) * K + ks * 32 + kg * 8);
  };

  constexpr int PASSES = NFRAG / 4;
#pragma unroll
  for (int i = 0; i < PASSES; ++i) {
    int c = i * 4 + w;
    __builtin_amdgcn_global_load_lds(GLBP(Wpk + (long)c * 256 + lane * 4),
                                     LDSP(&bsh[c * 256]), 16, 0, 0);
  }
  bf16x8 a0 = loadAbf(0, 0);
  bf16x8 a1 = loadAbf(0, 1);
  __syncthreads();  // single drain of the B stage

  f32x4 acc[2][KOT] = {};
#pragma unroll
  for (int ks = 0; ks < KS; ++ks) {
    bf16x8 c0 = a0, c1 = a1;
    if (ks + 1 < KS) {
      a0 = loadAbf(ks + 1, 0);
      a1 = loadAbf(ks + 1, 1);
    }
#pragma unroll
    for (int o = 0; o < KOT; ++o) {
      bf16x8 bfr = *reinterpret_cast<const bf16x8*>(&bsh[((ks * KOT + o) * 64 + lane) * 4]);
      acc[0][o] = __builtin_amdgcn_mfma_f32_16x16x32_bf16(c0, bfr, acc[0][o], 0, 0, 0);
      acc[1][o] = __builtin_amdgcn_mfma_f32_16x16x32_bf16(c1, bfr, acc[1][o], 0, 0, 0);
    }
  }

  float s[KOT] = {}, ss[KOT] = {};
  if (GRU == 0) {
#pragma unroll
    for (int tl = 0; tl < 2; ++tl)
#pragma unroll
      for (int o = 0; o < KOT; ++o)
#pragma unroll
        for (int q = 0; q < 4; ++q) {
          long row = mbase + tl * 16 + kg * 4 + q;
          float vv = acc[tl][o][q];
          if (row < n) {
            long off = row * KO + o * 16 + rr;
            if (OUTBF) ((u16*)Yv)[off] = f2bf(vv);
            else       ((float*)Yv)[off] = vv;
            if (CS) { s[o] += vv; ss[o] += vv * vv; }
          }
        }
  } else {
    float bi[12], bh_[12];
#pragma unroll
    for (int g = 0; g < 3; ++g)
#pragma unroll
      for (int o = 0; o < 4; ++o) {
        bi[g * 4 + o] = bih[g * 64 + o * 16 + rr];
        bh_[g * 4 + o] = bhh[g * 64 + o * 16 + rr];
      }
#pragma unroll
    for (int tl = 0; tl < 2; ++tl)
#pragma unroll
      for (int o = 0; o < 4; ++o) {
        int c = o * 16 + rr;
#pragma unroll
        for (int q = 0; q < 4; ++q) {
          long row = mbase + tl * 16 + kg * 4 + q;
          float ir = acc[tl][o][q] + bi[o];
          float iz = acc[tl][o + 4][q] + bi[4 + o];
          float in_ = acc[tl][o + 8][q] + bi[8 + o];
          float hr = bh_[o], hz = bh_[4 + o], hn = bh_[8 + o], hv = 0.f;
          if (GRU == 2) {
            const u16* g2 = G2B + row * 192;
            hr += bf2f(g2[c]); hz += bf2f(g2[64 + c]); hn += bf2f(g2[128 + c]);
            hv = bf2f(Hv[row * 64 + c]);
          }
          float rg = 1.f / (1.f + __expf(-(ir + hr)));
          float zg = 1.f / (1.f + __expf(-(iz + hz)));
          float ng = tanhf(in_ + rg * hn);
          float h = (1.f - zg) * ng + (GRU == 2 ? zg * hv : 0.f);
          if (row < n) {
            ((u16*)Yv)[row * 64 + c] = f2bf(h);
            if (CS) { s[o] += h; ss[o] += h * h; }
          }
        }
      }
  }
  if (CS) {
    constexpr int LIM = (GRU == 0) ? 2 * KO : 128;
    constexpr int CKO = (GRU == 0) ? KO : 64;
    constexpr int OL = (GRU == 0) ? KOT : 4;
    for (int i = threadIdx.x; i < LIM; i += 256) cs[i] = 0.f;
    __syncthreads();
#pragma unroll
    for (int o = 0; o < OL; ++o) {
      int c = o * 16 + rr;
      atomicAdd(&cs[c], s[o]);
      atomicAdd(&cs[CKO + c], ss[o]);
    }
    __syncthreads();
    for (int i = threadIdx.x; i < LIM; i += 256) atomicAdd(&csum[i], cs[i]);
  }
}

// ---------------- BN apply with inline finalize (f32 in, bf16 out) ------------
__global__ __launch_bounds__(256) void bn_apply_bf(const float* __restrict__ X,
                                                   u16* __restrict__ Y,
                                                   const float* __restrict__ accs,
                                                   const float* __restrict__ gamma,
                                                   const float* __restrict__ beta, int relu) {
  __shared__ float scsh[128];
  int t = threadIdx.x;
  if (t < 64) {
    float mean = accs[t] * (1.f / NN);
    float var = accs[64 + t] * (1.f / NN) - mean * mean;
    float sc = gamma[t] * rsqrtf(var + EPSV);
    scsh[t] = sc;
    scsh[64 + t] = beta[t] - mean * sc;
  }
  __syncthreads();
  long i = (long)blockIdx.x * 256 + t;  // NN*16 float4s
  float4 v = reinterpret_cast<const float4*>(X)[i];
  int c = (int)((i * 4) & 63);
  v.x = fmaf(v.x, scsh[c],     scsh[64 + c]);
  v.y = fmaf(v.y, scsh[c + 1], scsh[65 + c]);
  v.z = fmaf(v.z, scsh[c + 2], scsh[66 + c]);
  v.w = fmaf(v.w, scsh[c + 3], scsh[67 + c]);
  if (relu) {
    v.x = fmaxf(v.x, 0.f); v.y = fmaxf(v.y, 0.f);
    v.z = fmaxf(v.z, 0.f); v.w = fmaxf(v.w, 0.f);
  }
  reinterpret_cast<ushort4*>(Y)[i] = make_ushort4(f2bf(v.x), f2bf(v.y), f2bf(v.z), f2bf(v.w));
}

// ---------------- final head: inline BN finalize + ReLU + tiny GEMM -----------
// Z: bf16 [n,128] rows, pre-offset to this head's 64-col slice.
template<int KO>
__global__ __launch_bounds__(256) void headfin_bn(const u16* __restrict__ Z,
                                                  const float* __restrict__ asum,
                                                  const float* __restrict__ asq,
                                                  const float* __restrict__ gamma,
                                                  const float* __restrict__ beta,
                                                  const float* __restrict__ W2,
                                                  const float* __restrict__ b2,
                                                  float* __restrict__ out, int n) {
  __shared__ float ws[KO * 64];
  __shared__ float scsh[128];
  int t = threadIdx.x;
  if (t < 64) {
    float mean = asum[t] * (1.f / NN);
    float var = asq[t] * (1.f / NN) - mean * mean;
    float sc = gamma[t] * rsqrtf(var + EPSV);
    scsh[t] = sc;
    scsh[64 + t] = beta[t] - mean * sc;
  }
  for (int i = t; i < KO * 64; i += 256) ws[i] = W2[i];
  __syncthreads();
  long node = (long)blockIdx.x * 256 + t;
  if (node >= n) return;
  const u16* zr = Z + node * 128;
  float x[64];
#pragma unroll
  for (int i = 0; i < 16; ++i) {
    ushort4 z4 = reinterpret_cast<const ushort4*>(zr)[i];
    int c = i * 4;
    x[c]     = fmaxf(fmaf(bf2f(z4.x), scsh[c],     scsh[64 + c]), 0.f);
    x[c + 1] = fmaxf(fmaf(bf2f(z4.y), scsh[c + 1], scsh[65 + c]), 0.f);
    x[c + 2] = fmaxf(fmaf(bf2f(z4.z), scsh[c + 2], scsh[66 + c]), 0.f);
    x[c + 3] = fmaxf(fmaf(bf2f(z4.w), scsh[c + 3], scsh[67 + c]), 0.f);
  }
#pragma unroll
  for (int o = 0; o < KO; ++o) {
    float a = b2[o];
#pragma unroll
    for (int d = 0; d < 64; ++d) a = fmaf(x[d], ws[o * 64 + d], a);
    out[node * KO + o] = a;
  }
}

extern "C" void kernel_launch(void* const* d_in, const int* in_sizes, int n_in,
                              void* d_out, int out_size, void* d_ws, size_t ws_size,
                              hipStream_t stream) {
  const float* v     = (const float*)d_in[0];
  const int*   src   = (const int*)d_in[1];
  const int*   dst   = (const int*)d_in[2];
  const int*   rt    = (const int*)d_in[3];
  const float* norm  = (const float*)d_in[4];
  const float* emb_W = (const float*)d_in[5];
  const float* emb_g  = (const float*)d_in[7];
  const float* emb_be = (const float*)d_in[8];
  const float* rel_w  = (const float*)d_in[9];
  const float* Wih    = (const float*)d_in[10];
  const float* Whh    = (const float*)d_in[11];
  const float* bih    = (const float*)d_in[12];
  const float* bhh    = (const float*)d_in[13];
  const float* ker_g  = (const float*)d_in[14];
  const float* aW1    = (const float*)d_in[16];
  const float* a_g  = (const float*)d_in[18];
  const float* a_be = (const float*)d_in[19];
  const float* aW2  = (const float*)d_in[20];
  const float* ab2  = (const float*)d_in[21];
  const float* bW1  = (const float*)d_in[22];
  const float* b_g  = (const float*)d_in[24];
  const float* b_be = (const float*)d_in[25];
  const float* bW2  = (const float*)d_in[26];
  const float* bb2  = (const float*)d_in[27];
  float* out = (float*)d_out;

  // ---- workspace carve-up ----
  char* p = (char*)d_ws;
  auto nxt = [&](size_t bytes) -> char* {
    char* r = p; p += (bytes + 255) & ~(size_t)255; return r;
  };
  int*   GCNT = (int*)nxt(512 * 4);                 // bucket counts (memset w/ ACCs)
  float* ACCs = (float*)nxt(512 * 4);               // raw BN stats: emb|ker|heads
  float* Z    = (float*)nxt((size_t)NP * 64 * 4);   // f32 emb pre-acts
  u16*   X1   = (u16*)nxt((size_t)NP * 64 * 2);     // h (bf16)
  u16*   X2   = (u16*)nxt((size_t)NP * 64 * 2);     // h0 (bf16)
  u16*   ACCB = (u16*)nxt((size_t)NP * 192 * 2);    // gathered rel-sums / head pre-acts
  u16*   G2B  = (u16*)nxt((size_t)NP * 192 * 2);    // h @ Whh^T
  u64*   REG  = (u64*)nxt((size_t)NBKT * CAP * 8);  // padded bucket regions
  u64*   CSR  = (u64*)nxt((size_t)NE * 8);          // rel+dst-sorted records
  int*   BBAS = (int*)nxt(512 * 4);
  int*   ROWPR = (int*)nxt((size_t)(NP + 8) * 4 * 4); // per-(node,rel) bounds
  u32*   PWf  = (u32*)nxt(18432 * 4);
  u32*   PWem = (u32*)nxt(2048 * 4);
  u32*   PWhh = (u32*)nxt(6144 * 4);
  u32*   PWab = (u32*)nxt(4096 * 4);
  float* WROW = (float*)nxt(147456);

  hipMemsetAsync(GCNT, 0, 1024 * 4, stream);  // GCNT + ACCs contiguous

  // setup + hierarchical rel-sorted CSR build
  setupA<<<176, 256, 0, stream>>>(rel_w, Wih, emb_W, Whh, WROW, PWem, PWhh);
  countplace<<<782, 256, 0, stream>>>(src, dst, rt, norm, GCNT, REG);
  bucketscan<<<1, 512, 0, stream>>>(GCNT, BBAS);
  localsort<<<NBKT, 256, 0, stream>>>(GCNT, BBAS, REG, CSR, ROWPR);
  pack_wf<<<72, 256, 0, stream>>>(WROW, PWf);

  // embedding: Z = v @ emb_W^T (fused colsum); X2 = bf16(relu(BN(Z)))
  gemm_mfma<64, 64, 1, 0, 1, 0><<<782, 256, 0, stream>>>(v, PWem, Z, nullptr, nullptr,
                                                         nullptr, nullptr, ACCs + 0, NN);
  bn_apply_bf<<<6250, 256, 0, stream>>>(Z, X2, ACCs + 0, emb_g, emb_be, 1);

  // layer 1 (h==0): gather -> fused GEMM+GRU -> X1 = h1
  csr_gather<<<25000, 256, 0, stream>>>(ROWPR, CSR, X2, ACCB);
  gemm_mfma<192, 192, 0, 1, 0, 1><<<782, 256, 0, stream>>>(ACCB, PWf, X1, bih, bhh,
                                                           nullptr, nullptr, nullptr, NN);

  // layer 2: gather(h1) -> G2 = h1 @ Whh^T -> fused GEMM+GRU (+ker stats) -> X1 = h2
  csr_gather<<<25000, 256, 0, stream>>>(ROWPR, CSR, X1, ACCB);
  gemm_mfma<64, 192, 0, 0, 0, 1><<<782, 256, 0, stream>>>(X1, PWhh, G2B, nullptr, nullptr,
                                                          nullptr, nullptr, nullptr, NN);
  gemm_mfma<192, 192, 0, 2, 1, 1><<<782, 256, 0, stream>>>(ACCB, PWf, X1, bih, bhh,
                                                           G2B, X1, ACCs + 128, NN);

  // heads: fold ker-BN scale into both W1s (shift cancels in head BN), one KO=128
  // GEMM into ACCB (bf16) with fused dual column stats, then per-head finish.
  fold_pack<<<16, 256, 0, stream>>>(aW1, bW1, ACCs + 128, ker_g, PWab);
  gemm_mfma<64, 128, 0, 0, 1, 1><<<782, 256, 0, stream>>>(X1, PWab, ACCB, nullptr, nullptr,
                                                          nullptr, nullptr, ACCs + 256, NN);
  headfin_bn<2><<<391, 256, 0, stream>>>((const u16*)ACCB, ACCs + 256, ACCs + 384,
                                         a_g, a_be, aW2, ab2, out, NN);
  headfin_bn<21><<<391, 256, 0, stream>>>((const u16*)ACCB + 64, ACCs + 320, ACCs + 448,
                                          b_g, b_be, bW2, bb2, out + (long)NN * 2, NN);
}

// Round 9
// 380.659 us; speedup vs baseline: 6.6512x; 1.0881x over previous
//
#include <hip/hip_runtime.h>

#define NN 100000
#define NE 1600000
#define NP 100096   // 782 * 128 rows, GEMM tile padding
#define NBKT 391    // ceil(NN/256) coarse buckets
#define CAP 6144    // padded region capacity per bucket
#define EPSV 1e-5f

typedef unsigned int u32;
typedef unsigned short u16;
typedef unsigned long long u64;
typedef __bf16 bf16x8 __attribute__((ext_vector_type(8)));
typedef float f32x4 __attribute__((ext_vector_type(4)));

#define GLBP(x) ((const __attribute__((address_space(1))) u32*)(x))
#define LDSP(x) ((__attribute__((address_space(3))) u32*)(x))

__device__ __forceinline__ u16 f2bf(float f) {
  u32 x = __float_as_uint(f);
  return (u16)((x + 0x7FFFu + ((x >> 16) & 1u)) >> 16);  // RNE
}
__device__ __forceinline__ float bf2f(u16 h) { return __uint_as_float(((u32)h) << 16); }

// ---------------- setup A: wfuse (blocks 0..143) | pack emb (144..151) | pack Whh (152..175)
__device__ __forceinline__ void pack_one(const float* W, u32* out, int K, int KOT, int i) {
  int q = i & 3, lane = (i >> 2) & 63, f = i >> 8;
  int ks = f / KOT, ot = f - ks * KOT;
  int o = ot * 16 + (lane & 15);
  int k = ks * 32 + (lane >> 4) * 8 + q * 2;
  out[i] = (u32)f2bf(W[o * K + k]) | ((u32)f2bf(W[o * K + k + 1]) << 16);
}

__global__ void setupA(const float* __restrict__ relw, const float* __restrict__ Wih,
                       const float* __restrict__ embW, const float* __restrict__ Whh,
                       float* __restrict__ Wrow, u32* __restrict__ PWem, u32* __restrict__ PWhh) {
  int b = blockIdx.x;
  if (b < 144) {
    int t = b * 256 + threadIdx.x;
    if (t >= 192 * 192) return;
    int kg = t / 192, j = t % 192;
    const float* a = relw + (j >> 6) * 4096 + (j & 63) * 64;
    const float* w = Wih + kg * 64;
    float s = 0.f;
#pragma unroll
    for (int k = 0; k < 64; ++k) s += a[k] * w[k];
    Wrow[kg * 192 + j] = s;
  } else if (b < 152) {
    pack_one(embW, PWem, 64, 4, (b - 144) * 256 + threadIdx.x);
  } else {
    pack_one(Whh, PWhh, 64, 12, (b - 152) * 256 + threadIdx.x);
  }
}

__global__ void pack_wf(const float* __restrict__ Wrow, u32* __restrict__ PWf) {
  pack_one(Wrow, PWf, 192, 12, blockIdx.x * 256 + threadIdx.x);  // 72 blocks
}

// pack BOTH head weights (128 rows) folded with inline ker-BN scale (from raw stats)
__global__ void fold_pack(const float* __restrict__ Wa, const float* __restrict__ Wb,
                          const float* __restrict__ kacc, const float* __restrict__ kg,
                          u32* __restrict__ P) {
  int i = blockIdx.x * 256 + threadIdx.x;  // 4096 = KS(2)*KOT(8)*256
  int q = i & 3, lane = (i >> 2) & 63, f = i >> 8;
  int ks = f >> 3, ot = f & 7;
  int o = ot * 16 + (lane & 15);            // 0..127
  int k = ks * 32 + (lane >> 4) * 8 + q * 2;
  const float* W = (o < 64) ? (Wa + o * 64) : (Wb + (o - 64) * 64);
  const float inv = 1.f / NN;
  float m0 = kacc[k] * inv;
  float s0 = kg[k] * rsqrtf(kacc[64 + k] * inv - m0 * m0 + EPSV);
  float m1 = kacc[k + 1] * inv;
  float s1 = kg[k + 1] * rsqrtf(kacc[64 + k + 1] * inv - m1 * m1 + EPSV);
  P[i] = (u32)f2bf(W[k] * s0) | ((u32)f2bf(W[k + 1] * s1) << 16);
}

// ---------------------------------------------------------------------------
// Hierarchical CSR build.
// record: low u32 = src(0..19) | rel(20..21) | dst&255(22..29); high u32 = norm
// ---------------------------------------------------------------------------
__global__ __launch_bounds__(256) void countplace(const int* __restrict__ src,
                                                  const int* __restrict__ dst,
                                                  const int* __restrict__ rt,
                                                  const float* __restrict__ nrm,
                                                  int* __restrict__ gcnt,
                                                  u64* __restrict__ region) {
  __shared__ u32 hist[NBKT], gbase[NBKT];
  const int t = threadIdx.x;
  for (int i = t; i < NBKT; i += 256) hist[i] = 0;
  __syncthreads();
  const int e0 = blockIdx.x * 2048 + t;
  u32 rlo[8], rhi[8], lrank[8];
  int bkt[8];
#pragma unroll
  for (int i = 0; i < 8; ++i) {
    int e = e0 + i * 256;
    bkt[i] = -1;
    if (e < NE) {
      int d = dst[e];
      int b = d >> 8;
      bkt[i] = b;
      lrank[i] = atomicAdd(&hist[b], 1u);
      rlo[i] = (u32)src[e] | ((u32)rt[e] << 20) | ((u32)(d & 255) << 22);
      rhi[i] = __float_as_uint(nrm[e]);
    }
  }
  __syncthreads();
  for (int i = t; i < NBKT; i += 256) {
    u32 h = hist[i];
    gbase[i] = h ? (u32)atomicAdd(&gcnt[i], (int)h) : 0u;
  }
  __syncthreads();
#pragma unroll
  for (int i = 0; i < 8; ++i) {
    if (bkt[i] >= 0) {
      u32 pos = gbase[bkt[i]] + lrank[i];
      if (pos < CAP)
        region[(size_t)bkt[i] * CAP + pos] = (u64)rlo[i] | ((u64)rhi[i] << 32);
    }
  }
}

// exclusive prefix over PADDED bucket sizes (gcnt + 768 slack for even-padding)
__global__ __launch_bounds__(512) void bucketscan(const int* __restrict__ gcnt,
                                                  int* __restrict__ bbase) {
  int t = threadIdx.x;
  int v = (t < NBKT) ? (gcnt[t] + 768) : 0;
  __shared__ int sh[512];
  sh[t] = v;
  __syncthreads();
#pragma unroll
  for (int off = 1; off < 512; off <<= 1) {
    int u = (t >= off) ? sh[t - off] : 0;
    __syncthreads();
    sh[t] += u;
    __syncthreads();
  }
  if (t < NBKT) bbase[t] = sh[t] - v;  // exclusive
}

// 1024-bin counting sort per bucket, with each (node,rel) segment padded to
// EVEN length via zero-norm dummy records. rowpr[4*node+r] = padded boundaries.
__global__ __launch_bounds__(256) void localsort(const int* __restrict__ gcnt,
                                                 const int* __restrict__ bbase,
                                                 const u64* __restrict__ region,
                                                 u64* __restrict__ csr,
                                                 int* __restrict__ rowpr) {
  const int b = blockIdx.x, t = threadIdx.x;
  int n = gcnt[b];
  if (n > CAP) n = CAP;
  const int base = bbase[b];
  __shared__ u32 hist[1024], sc[256];
#pragma unroll
  for (int i = 0; i < 4; ++i) hist[t + 256 * i] = 0;
  __syncthreads();
  for (int i = t; i < n; i += 256)
    atomicAdd(&hist[(u32)(region[(size_t)b * CAP + i] >> 20) & 1023u], 1u);
  __syncthreads();
  u32 a0 = hist[4 * t], a1 = hist[4 * t + 1], a2 = hist[4 * t + 2];
  u32 p0 = (a0 + 1) & ~1u, p1 = (a1 + 1) & ~1u, p2 = (a2 + 1) & ~1u;
  u32 part = p0 + p1 + p2;
  sc[t] = part;
  __syncthreads();
#pragma unroll
  for (int off = 1; off < 256; off <<= 1) {
    u32 u = (t >= off) ? sc[t - off] : 0;
    __syncthreads();
    sc[t] += u;
    __syncthreads();
  }
  u32 ex = sc[t] - part;
  int node = b * 256 + t;
  rowpr[4 * node + 0] = base + (int)ex;
  rowpr[4 * node + 1] = base + (int)(ex + p0);
  rowpr[4 * node + 2] = base + (int)(ex + p0 + p1);
  rowpr[4 * node + 3] = base + (int)(ex + p0 + p1 + p2);
  __syncthreads();
  hist[4 * t + 0] = ex;
  hist[4 * t + 1] = ex + p0;
  hist[4 * t + 2] = ex + p0 + p1;
  __syncthreads();
  for (int i = t; i < n; i += 256) {
    u64 rec = region[(size_t)b * CAP + i];
    u32 pos = atomicAdd(&hist[(u32)(rec >> 20) & 1023u], 1u);
    csr[(size_t)base + pos] = rec;
  }
  __syncthreads();
  // zero-norm dummies complete odd segments (norm bits = 0 -> fma contributes 0)
  if (a0 & 1) csr[(size_t)base + ex + a0] = 0ull;
  if (a1 & 1) csr[(size_t)base + ex + p0 + a1] = 0ull;
  if (a2 & 1) csr[(size_t)base + ex + p0 + p1 + a2] = 0ull;
}

// ---------------- CSR gather: wave per node, single chunk loop, positional rel
// segments even -> pairs are rel-homogeneous; 3 branch-free scalar sub-loops.
__global__ __launch_bounds__(256) void csr_gather(const int* __restrict__ rowpr,
                                                  const u64* __restrict__ csr,
                                                  const u16* __restrict__ Xbf,
                                                  u16* __restrict__ ACCbf) {
  int wv = blockIdx.x * 4 + (threadIdx.x >> 6);
  int lane = threadIdx.x & 63;
  if (wv >= NN) return;
  const int half = lane >> 5, c2 = lane & 31;
  int4 rp = *reinterpret_cast<const int4*>(rowpr + 4 * wv);
  const int b0 = __builtin_amdgcn_readfirstlane(rp.x);
  const int b1 = __builtin_amdgcn_readfirstlane(rp.y);
  const int b2 = __builtin_amdgcn_readfirstlane(rp.z);
  const int b3 = __builtin_amdgcn_readfirstlane(rp.w);
  const u32* X4 = (const u32*)Xbf;
  float a0x = 0.f, a0y = 0.f, a1x = 0.f, a1y = 0.f, a2x = 0.f, a2y = 0.f;
#define PAIRB(J, AX, AY)                                                        \
  { u32 sA = (u32)__builtin_amdgcn_readlane((int)lo, (J));                      \
    u32 sB = (u32)__builtin_amdgcn_readlane((int)lo, (J) + 1);                  \
    u32 nA = (u32)__builtin_amdgcn_readlane((int)hi, (J));                      \
    u32 nB = (u32)__builtin_amdgcn_readlane((int)hi, (J) + 1);                  \
    u32 srp = half ? sB : sA;                                                   \
    float nm = __uint_as_float(half ? nB : nA);                                 \
    u32 xw = X4[((srp & 0xFFFFFu) << 5) | (u32)c2];                             \
    AX = fmaf(__uint_as_float(xw << 16), nm, AX);                               \
    AY = fmaf(__uint_as_float(xw & 0xFFFF0000u), nm, AY); }
  for (int c = b0; c < b3; c += 64) {
    int m = b3 - c; m = m > 64 ? 64 : m;
    u32 lo = 0, hi = 0;
    if (lane < m) {
      u64 rec = csr[(size_t)c + lane];
      lo = (u32)rec; hi = (u32)(rec >> 32);
    }
    int j1 = b1 - c; j1 = j1 < 0 ? 0 : (j1 > m ? m : j1);
    int j2 = b2 - c; j2 = j2 < 0 ? 0 : (j2 > m ? m : j2);
    int j = 0;
    for (; j + 4 <= j1; j += 4) { PAIRB(j, a0x, a0y) PAIRB(j + 2, a0x, a0y) }
    if (j < j1) { PAIRB(j, a0x, a0y) j += 2; }
    for (; j + 4 <= j2; j += 4) { PAIRB(j, a1x, a1y) PAIRB(j + 2, a1x, a1y) }
    if (j < j2) { PAIRB(j, a1x, a1y) j += 2; }
    for (; j + 4 <= m; j += 4) { PAIRB(j, a2x, a2y) PAIRB(j + 2, a2x, a2y) }
    if (j < m) { PAIRB(j, a2x, a2y) j += 2; }
  }
#undef PAIRB
  a0x += __shfl_xor(a0x, 32); a0y += __shfl_xor(a0y, 32);
  a1x += __shfl_xor(a1x, 32); a1y += __shfl_xor(a1y, 32);
  a2x += __shfl_xor(a2x, 32); a2y += __shfl_xor(a2y, 32);
  if (half == 0) {
    u32* orow = (u32*)(ACCbf + (size_t)wv * 192);
    orow[c2]      = (u32)f2bf(a0x) | ((u32)f2bf(a0y) << 16);
    orow[32 + c2] = (u32)f2bf(a1x) | ((u32)f2bf(a1y) << 16);
    orow[64 + c2] = (u32)f2bf(a2x) | ((u32)f2bf(a2y) << 16);
  }
}

// ---------------------------------------------------------------------------
// MFMA GEMM, whole-B-in-LDS (one barrier), A streamed with 1-step prefetch.
//   AF32: A is f32 (row-clamped); GRU: 0 store, 1 h'=(1-z)n, 2 full
//   CS: fused column sum/sumsq atomics
// ---------------------------------------------------------------------------
template<int K, int KO, int AF32, int GRU, int CS, int OUTBF>
__global__ __launch_bounds__(256) void gemm_mfma(
    const void* __restrict__ Av, const u32* __restrict__ Wpk, void* __restrict__ Yv,
    const float* __restrict__ bih, const float* __restrict__ bhh,
    const u16* __restrict__ G2B, const u16* __restrict__ Hv,
    float* __restrict__ csum, int n) {
  constexpr int KOT = KO / 16, KS = K / 32;
  constexpr int NFRAG = KS * KOT;
  __shared__ u32 bsh[NFRAG * 256];
  __shared__ float cs[2 * KO];
  const int lane = threadIdx.x & 63, w = threadIdx.x >> 6;
  const int rr = lane & 15, kg = lane >> 4;
  const long mbase = (long)blockIdx.x * 128 + w * 32;
  const u16* Abf = (const u16*)Av;
  const float* Af = (const float*)Av;

  auto loadAbf = [&](int ks, int halfsel) -> bf16x8 {
    if (AF32) {
      long r = mbase + halfsel * 16 + rr;
      if (r > n - 1) r = n - 1;
      const float* pp = Af + r * K + ks * 32 + kg * 8;
      float4 u0 = *(const float4*)pp;
      float4 u1 = *(const float4*)(pp + 4);
      bf16x8 o_;
      o_[0] = __builtin_bit_cast(__bf16, f2bf(u0.x));
      o_[1] = __builtin_bit_cast(__bf16, f2bf(u0.y));
      o_[2] = __builtin_bit_cast(__bf16, f2bf(u0.z));
      o_[3] = __builtin_bit_cast(__bf16, f2bf(u0.w));
      o_[4] = __builtin_bit_cast(__bf16, f2bf(u1.x));
      o_[5] = __builtin_bit_cast(__bf16, f2bf(u1.y));
      o_[6] = __builtin_bit_cast(__bf16, f2bf(u1.z));
      o_[7] = __builtin_bit_cast(__bf16, f2bf(u1.w));
      return o_;
    }
    return *reinterpret_cast<const bf16x8*>(Abf + (mbase + halfsel * 16 + rr) * K + ks * 32 + kg * 8);
  };

  constexpr int PASSES = NFRAG / 4;
#pragma unroll
  for (int i = 0; i < PASSES; ++i) {
    int c = i * 4 + w;
    __builtin_amdgcn_global_load_lds(GLBP(Wpk + (long)c * 256 + lane * 4),
                                     LDSP(&bsh[c * 256]), 16, 0, 0);
  }
  bf16x8 a0 = loadAbf(0, 0);
  bf16x8 a1 = loadAbf(0, 1);
  __syncthreads();  // single drain of the B stage

  f32x4 acc[2][KOT] = {};
#pragma unroll
  for (int ks = 0; ks < KS; ++ks) {
    bf16x8 c0 = a0, c1 = a1;
    if (ks + 1 < KS) {
      a0 = loadAbf(ks + 1, 0);
      a1 = loadAbf(ks + 1, 1);
    }
#pragma unroll
    for (int o = 0; o < KOT; ++o) {
      bf16x8 bfr = *reinterpret_cast<const bf16x8*>(&bsh[((ks * KOT + o) * 64 + lane) * 4]);
      acc[0][o] = __builtin_amdgcn_mfma_f32_16x16x32_bf16(c0, bfr, acc[0][o], 0, 0, 0);
      acc[1][o] = __builtin_amdgcn_mfma_f32_16x16x32_bf16(c1, bfr, acc[1][o], 0, 0, 0);
    }
  }

  float s[KOT] = {}, ss[KOT] = {};
  if (GRU == 0) {
#pragma unroll
    for (int tl = 0; tl < 2; ++tl)
#pragma unroll
      for (int o = 0; o < KOT; ++o)
#pragma unroll
        for (int q = 0; q < 4; ++q) {
          long row = mbase + tl * 16 + kg * 4 + q;
          float vv = acc[tl][o][q];
          if (row < n) {
            long off = row * KO + o * 16 + rr;
            if (OUTBF) ((u16*)Yv)[off] = f2bf(vv);
            else       ((float*)Yv)[off] = vv;
            if (CS) { s[o] += vv; ss[o] += vv * vv; }
          }
        }
  } else {
    float bi[12], bh_[12];
#pragma unroll
    for (int g = 0; g < 3; ++g)
#pragma unroll
      for (int o = 0; o < 4; ++o) {
        bi[g * 4 + o] = bih[g * 64 + o * 16 + rr];
        bh_[g * 4 + o] = bhh[g * 64 + o * 16 + rr];
      }
#pragma unroll
    for (int tl = 0; tl < 2; ++tl)
#pragma unroll
      for (int o = 0; o < 4; ++o) {
        int c = o * 16 + rr;
#pragma unroll
        for (int q = 0; q < 4; ++q) {
          long row = mbase + tl * 16 + kg * 4 + q;
          float ir = acc[tl][o][q] + bi[o];
          float iz = acc[tl][o + 4][q] + bi[4 + o];
          float in_ = acc[tl][o + 8][q] + bi[8 + o];
          float hr = bh_[o], hz = bh_[4 + o], hn = bh_[8 + o], hv = 0.f;
          if (GRU == 2) {
            const u16* g2 = G2B + row * 192;
            hr += bf2f(g2[c]); hz += bf2f(g2[64 + c]); hn += bf2f(g2[128 + c]);
            hv = bf2f(Hv[row * 64 + c]);
          }
          float rg = 1.f / (1.f + __expf(-(ir + hr)));
          float zg = 1.f / (1.f + __expf(-(iz + hz)));
          float ng = tanhf(in_ + rg * hn);
          float h = (1.f - zg) * ng + (GRU == 2 ? zg * hv : 0.f);
          if (row < n) {
            ((u16*)Yv)[row * 64 + c] = f2bf(h);
            if (CS) { s[o] += h; ss[o] += h * h; }
          }
        }
      }
  }
  if (CS) {
    constexpr int LIM = (GRU == 0) ? 2 * KO : 128;
    constexpr int CKO = (GRU == 0) ? KO : 64;
    constexpr int OL = (GRU == 0) ? KOT : 4;
    for (int i = threadIdx.x; i < LIM; i += 256) cs[i] = 0.f;
    __syncthreads();
#pragma unroll
    for (int o = 0; o < OL; ++o) {
      int c = o * 16 + rr;
      atomicAdd(&cs[c], s[o]);
      atomicAdd(&cs[CKO + c], ss[o]);
    }
    __syncthreads();
    for (int i = threadIdx.x; i < LIM; i += 256) atomicAdd(&csum[i], cs[i]);
  }
}

// ---------------- BN apply with inline finalize (f32 in, bf16 out) ------------
__global__ __launch_bounds__(256) void bn_apply_bf(const float* __restrict__ X,
                                                   u16* __restrict__ Y,
                                                   const float* __restrict__ accs,
                                                   const float* __restrict__ gamma,
                                                   const float* __restrict__ beta, int relu) {
  __shared__ float scsh[128];
  int t = threadIdx.x;
  if (t < 64) {
    float mean = accs[t] * (1.f / NN);
    float var = accs[64 + t] * (1.f / NN) - mean * mean;
    float sc = gamma[t] * rsqrtf(var + EPSV);
    scsh[t] = sc;
    scsh[64 + t] = beta[t] - mean * sc;
  }
  __syncthreads();
  long i = (long)blockIdx.x * 256 + t;  // NN*16 float4s
  float4 v = reinterpret_cast<const float4*>(X)[i];
  int c = (int)((i * 4) & 63);
  v.x = fmaf(v.x, scsh[c],     scsh[64 + c]);
  v.y = fmaf(v.y, scsh[c + 1], scsh[65 + c]);
  v.z = fmaf(v.z, scsh[c + 2], scsh[66 + c]);
  v.w = fmaf(v.w, scsh[c + 3], scsh[67 + c]);
  if (relu) {
    v.x = fmaxf(v.x, 0.f); v.y = fmaxf(v.y, 0.f);
    v.z = fmaxf(v.z, 0.f); v.w = fmaxf(v.w, 0.f);
  }
  reinterpret_cast<ushort4*>(Y)[i] = make_ushort4(f2bf(v.x), f2bf(v.y), f2bf(v.z), f2bf(v.w));
}

// ---------------- final head: inline BN finalize + ReLU + tiny GEMM -----------
// Z: bf16 [n,128] rows, pre-offset to this head's 64-col slice.
template<int KO>
__global__ __launch_bounds__(256) void headfin_bn(const u16* __restrict__ Z,
                                                  const float* __restrict__ asum,
                                                  const float* __restrict__ asq,
                                                  const float* __restrict__ gamma,
                                                  const float* __restrict__ beta,
                                                  const float* __restrict__ W2,
                                                  const float* __restrict__ b2,
                                                  float* __restrict__ out, int n) {
  __shared__ float ws[KO * 64];
  __shared__ float scsh[128];
  int t = threadIdx.x;
  if (t < 64) {
    float mean = asum[t] * (1.f / NN);
    float var = asq[t] * (1.f / NN) - mean * mean;
    float sc = gamma[t] * rsqrtf(var + EPSV);
    scsh[t] = sc;
    scsh[64 + t] = beta[t] - mean * sc;
  }
  for (int i = t; i < KO * 64; i += 256) ws[i] = W2[i];
  __syncthreads();
  long node = (long)blockIdx.x * 256 + t;
  if (node >= n) return;
  const u16* zr = Z + node * 128;
  float x[64];
#pragma unroll
  for (int i = 0; i < 16; ++i) {
    ushort4 z4 = reinterpret_cast<const ushort4*>(zr)[i];
    int c = i * 4;
    x[c]     = fmaxf(fmaf(bf2f(z4.x), scsh[c],     scsh[64 + c]), 0.f);
    x[c + 1] = fmaxf(fmaf(bf2f(z4.y), scsh[c + 1], scsh[65 + c]), 0.f);
    x[c + 2] = fmaxf(fmaf(bf2f(z4.z), scsh[c + 2], scsh[66 + c]), 0.f);
    x[c + 3] = fmaxf(fmaf(bf2f(z4.w), scsh[c + 3], scsh[67 + c]), 0.f);
  }
#pragma unroll
  for (int o = 0; o < KO; ++o) {
    float a = b2[o];
#pragma unroll
    for (int d = 0; d < 64; ++d) a = fmaf(x[d], ws[o * 64 + d], a);
    out[node * KO + o] = a;
  }
}

extern "C" void kernel_launch(void* const* d_in, const int* in_sizes, int n_in,
                              void* d_out, int out_size, void* d_ws, size_t ws_size,
                              hipStream_t stream) {
  const float* v     = (const float*)d_in[0];
  const int*   src   = (const int*)d_in[1];
  const int*   dst   = (const int*)d_in[2];
  const int*   rt    = (const int*)d_in[3];
  const float* norm  = (const float*)d_in[4];
  const float* emb_W = (const float*)d_in[5];
  const float* emb_g  = (const float*)d_in[7];
  const float* emb_be = (const float*)d_in[8];
  const float* rel_w  = (const float*)d_in[9];
  const float* Wih    = (const float*)d_in[10];
  const float* Whh    = (const float*)d_in[11];
  const float* bih    = (const float*)d_in[12];
  const float* bhh    = (const float*)d_in[13];
  const float* ker_g  = (const float*)d_in[14];
  const float* aW1    = (const float*)d_in[16];
  const float* a_g  = (const float*)d_in[18];
  const float* a_be = (const float*)d_in[19];
  const float* aW2  = (const float*)d_in[20];
  const float* ab2  = (const float*)d_in[21];
  const float* bW1  = (const float*)d_in[22];
  const float* b_g  = (const float*)d_in[24];
  const float* b_be = (const float*)d_in[25];
  const float* bW2  = (const float*)d_in[26];
  const float* bb2  = (const float*)d_in[27];
  float* out = (float*)d_out;

  // ---- workspace carve-up ----
  char* p = (char*)d_ws;
  auto nxt = [&](size_t bytes) -> char* {
    char* r = p; p += (bytes + 255) & ~(size_t)255; return r;
  };
  int*   GCNT = (int*)nxt(512 * 4);                 // bucket counts (memset w/ ACCs)
  float* ACCs = (float*)nxt(512 * 4);               // raw BN stats: emb|ker|heads
  float* Z    = (float*)nxt((size_t)NP * 64 * 4);   // f32 emb pre-acts
  u16*   X1   = (u16*)nxt((size_t)NP * 64 * 2);     // h (bf16)
  u16*   X2   = (u16*)nxt((size_t)NP * 64 * 2);     // h0 (bf16)
  u16*   ACCB = (u16*)nxt((size_t)NP * 192 * 2);    // gathered rel-sums / head pre-acts
  u16*   G2B  = (u16*)nxt((size_t)NP * 192 * 2);    // h @ Whh^T
  u64*   REG  = (u64*)nxt((size_t)NBKT * CAP * 8);  // padded bucket regions
  u64*   CSR  = (u64*)nxt((size_t)(NE + NBKT * 768 + 64) * 8);  // even-padded CSR
  int*   BBAS = (int*)nxt(512 * 4);
  int*   ROWPR = (int*)nxt((size_t)(NP + 8) * 4 * 4); // per-(node,rel) padded bounds
  u32*   PWf  = (u32*)nxt(18432 * 4);
  u32*   PWem = (u32*)nxt(2048 * 4);
  u32*   PWhh = (u32*)nxt(6144 * 4);
  u32*   PWab = (u32*)nxt(4096 * 4);
  float* WROW = (float*)nxt(147456);

  hipMemsetAsync(GCNT, 0, 1024 * 4, stream);  // GCNT + ACCs contiguous

  // setup + hierarchical rel-sorted even-padded CSR build
  setupA<<<176, 256, 0, stream>>>(rel_w, Wih, emb_W, Whh, WROW, PWem, PWhh);
  countplace<<<782, 256, 0, stream>>>(src, dst, rt, norm, GCNT, REG);
  bucketscan<<<1, 512, 0, stream>>>(GCNT, BBAS);
  localsort<<<NBKT, 256, 0, stream>>>(GCNT, BBAS, REG, CSR, ROWPR);
  pack_wf<<<72, 256, 0, stream>>>(WROW, PWf);

  // embedding: Z = v @ emb_W^T (fused colsum); X2 = bf16(relu(BN(Z)))
  gemm_mfma<64, 64, 1, 0, 1, 0><<<782, 256, 0, stream>>>(v, PWem, Z, nullptr, nullptr,
                                                         nullptr, nullptr, ACCs + 0, NN);
  bn_apply_bf<<<6250, 256, 0, stream>>>(Z, X2, ACCs + 0, emb_g, emb_be, 1);

  // layer 1 (h==0): gather -> fused GEMM+GRU -> X1 = h1
  csr_gather<<<25000, 256, 0, stream>>>(ROWPR, CSR, X2, ACCB);
  gemm_mfma<192, 192, 0, 1, 0, 1><<<782, 256, 0, stream>>>(ACCB, PWf, X1, bih, bhh,
                                                           nullptr, nullptr, nullptr, NN);

  // layer 2: gather(h1) -> G2 = h1 @ Whh^T -> fused GEMM+GRU (+ker stats) -> X1 = h2
  csr_gather<<<25000, 256, 0, stream>>>(ROWPR, CSR, X1, ACCB);
  gemm_mfma<64, 192, 0, 0, 0, 1><<<782, 256, 0, stream>>>(X1, PWhh, G2B, nullptr, nullptr,
                                                          nullptr, nullptr, nullptr, NN);
  gemm_mfma<192, 192, 0, 2, 1, 1><<<782, 256, 0, stream>>>(ACCB, PWf, X1, bih, bhh,
                                                           G2B, X1, ACCs + 128, NN);

  // heads: fold ker-BN scale into both W1s, one KO=128 GEMM with fused dual
  // column stats, then per-head inline-BN finish.
  fold_pack<<<16, 256, 0, stream>>>(aW1, bW1, ACCs + 128, ker_g, PWab);
  gemm_mfma<64, 128, 0, 0, 1, 1><<<782, 256, 0, stream>>>(X1, PWab, ACCB, nullptr, nullptr,
                                                          nullptr, nullptr, ACCs + 256, NN);
  headfin_bn<2><<<391, 256, 0, stream>>>((const u16*)ACCB, ACCs + 256, ACCs + 384,
                                         a_g, a_be, aW2, ab2, out, NN);
  headfin_bn<21><<<391, 256, 0, stream>>>((const u16*)ACCB + 64, ACCs + 320, ACCs + 448,
                                          b_g, b_be, bW2, bb2, out + (long)NN * 2, NN);
}